// Round 8
// baseline (491.780 us; speedup 1.0000x reference)
//
#include <hip/hip_runtime.h>

// Problem constants: B=8192, D=768, C=512, H=256, N=65536, k=10.
// Outputs (flat): rec_layer_2 [8192*768], prob [8192*512], L1, L2.

typedef __attribute__((ext_vector_type(8))) short short8;
typedef __attribute__((ext_vector_type(4))) float f32x4;
typedef unsigned int u32;

__device__ __forceinline__ ushort f2bf(float f) {
    unsigned u = __builtin_bit_cast(unsigned, f);
    u += 0x7FFFu + ((u >> 16) & 1u);          // round-to-nearest-even
    return (ushort)(u >> 16);
}
__device__ __forceinline__ unsigned pack2(float lo, float hi) {
    return (unsigned)f2bf(lo) | ((unsigned)f2bf(hi) << 16);
}
// async global->LDS, 16B per lane; lds dest = wave-uniform base + lane*16
__device__ __forceinline__ void gll16(const void* g, void* l) {
    __builtin_amdgcn_global_load_lds((const __attribute__((address_space(1))) u32*)g,
                                     (__attribute__((address_space(3))) u32*)l, 16, 0, 0);
}

// ======================= shared small kernels =======================
__global__ void k_zero(float* p, int n) {
    int i = blockIdx.x * 256 + threadIdx.x;
    if (i < n) p[i] = 0.f;
}
__global__ void k_init(float* cn_sq, float* acc) {
    int t = threadIdx.x;
    cn_sq[t] = 0.f; cn_sq[t + 256] = 0.f;
    if (t < 8) acc[t] = 0.f;
}
__global__ void k_col_sumsq(const float* __restrict__ cpt, float* __restrict__ cn_sq) {
    int c = blockIdx.x * 256 + threadIdx.x;
    int d0 = blockIdx.y * 96;
    float s = 0.f;
    #pragma unroll 4
    for (int d = d0; d < d0 + 96; ++d) { float v = cpt[d * 512 + c]; s += v * v; }
    atomicAdd(&cn_sq[c], s);
}
__global__ void k_row_stats(const float* __restrict__ cpt, float* __restrict__ acc) {
    __shared__ float red[256];
    int t = threadIdx.x;
    int d = blockIdx.x * 16;
    float rowsq = 0.f, tot = 0.f;
    for (int r = 0; r < 16; ++r, ++d) {
        float v1 = cpt[d * 512 + t], v2 = cpt[d * 512 + 256 + t];
        tot += v1 * v1 + v2 * v2;
        red[t] = v1 + v2;
        __syncthreads();
        for (int st = 128; st > 0; st >>= 1) {
            if (t < st) red[t] += red[t + st];
            __syncthreads();
        }
        if (t == 0) rowsq += red[0] * red[0];
        __syncthreads();
    }
    red[t] = tot; __syncthreads();
    for (int st = 128; st > 0; st >>= 1) {
        if (t < st) red[t] += red[t + st];
        __syncthreads();
    }
    if (t == 0) { atomicAdd(&acc[1], rowsq); atomicAdd(&acc[2], red[0]); }
}

template <int NB>
__global__ __launch_bounds__(256) void k_knn_merge(const float2* __restrict__ cand,
                                                   float* __restrict__ acc) {
    __shared__ float2 buf[NB];
    __shared__ float2 l2[160];
    int c = blockIdx.x, t = threadIdx.x;
    const float FINF = __builtin_inff();
    const float2* src = &cand[(size_t)c * NB];
    for (int i = t; i < NB; i += 256) buf[i] = src[i];
    __syncthreads();
    if (t < 16) {
        float td[10], tv[10];
        #pragma unroll
        for (int i = 0; i < 10; ++i) { td[i] = FINF; tv[i] = 0.f; }
        const int per = NB / 16;
        for (int j = t * per; j < t * per + per; ++j) {
            float nd = buf[j].x;
            if (nd < td[9]) {
                td[9] = nd; tv[9] = buf[j].y;
                #pragma unroll
                for (int x = 9; x > 0; --x)
                    if (td[x] < td[x - 1]) {
                        float a = td[x]; td[x] = td[x - 1]; td[x - 1] = a;
                        float b = tv[x]; tv[x] = tv[x - 1]; tv[x - 1] = b;
                    }
            }
        }
        #pragma unroll
        for (int i = 0; i < 10; ++i) l2[t * 10 + i] = make_float2(td[i], tv[i]);
    }
    __syncthreads();
    if (t == 0) {
        float td[10], tv[10];
        #pragma unroll
        for (int i = 0; i < 10; ++i) { td[i] = FINF; tv[i] = 0.f; }
        for (int j = 0; j < 160; ++j) {
            float nd = l2[j].x;
            if (nd < td[9]) {
                td[9] = nd; tv[9] = l2[j].y;
                #pragma unroll
                for (int x = 9; x > 0; --x)
                    if (td[x] < td[x - 1]) {
                        float a = td[x]; td[x] = td[x - 1]; td[x - 1] = a;
                        float b = tv[x]; tv[x] = tv[x - 1]; tv[x - 1] = b;
                    }
            }
        }
        float s = 0.f;
        #pragma unroll
        for (int i = 0; i < 10; ++i) s += tv[i];
        atomicAdd(&acc[0], s);
    }
}
__global__ void k_finalize(const float* __restrict__ acc, float* __restrict__ out) {
    if (threadIdx.x == 0) {
        out[10485760] = acc[0] / 5120.0f;
        out[10485761] = (acc[1] - acc[2]) / 262144.0f;
    }
}

// ======================= FAST PATH =======================
template <int EN>
__global__ __launch_bounds__(256) void k_tc(const float* __restrict__ src,
                                            ushort* __restrict__ dst,
                                            float* __restrict__ en,
                                            int Ncols, int D) {
    __shared__ float tile[32][256];
    const int t = threadIdx.x;
    const int n0 = blockIdx.x * 256;
    const int d0 = blockIdx.y * 32;
    float s = 0.f;
    #pragma unroll 8
    for (int dd = 0; dd < 32; ++dd) {
        float v = src[(size_t)(d0 + dd) * Ncols + n0 + t];
        tile[dd][t] = v;
        if (EN) s += v * v;
    }
    if (EN) atomicAdd(&en[n0 + t], s);
    __syncthreads();
    ushort* drow = dst + (size_t)(n0 + t) * D + d0;
    #pragma unroll
    for (int q = 0; q < 4; ++q) {
        uint4 d4;
        d4.x = pack2(tile[q * 8 + 0][t], tile[q * 8 + 1][t]);
        d4.y = pack2(tile[q * 8 + 2][t], tile[q * 8 + 3][t]);
        d4.z = pack2(tile[q * 8 + 4][t], tile[q * 8 + 5][t]);
        d4.w = pack2(tile[q * 8 + 6][t], tile[q * 8 + 7][t]);
        *(uint4*)(drow + q * 8) = d4;
    }
}

__global__ void k_cvt_emb(const float* __restrict__ src, ushort* __restrict__ dst) {
    int i = (blockIdx.x * 256 + threadIdx.x) * 8;
    float4 a = *(const float4*)&src[i], b = *(const float4*)&src[i + 4];
    uint4 d4 = make_uint4(pack2(a.x, a.y), pack2(a.z, a.w), pack2(b.x, b.y), pack2(b.z, b.w));
    *(uint4*)&dst[i] = d4;
}

// C = A[MxK] @ B[NxK]^T, bf16 in, gload_lds staging, tile 64x128, BK=64 (R5 proven).
template <int WF32, int WB16, int RELU>
__global__ __launch_bounds__(256, 4) void gemm_bt(const ushort* __restrict__ A,
                                                  const ushort* __restrict__ B,
                                                  float* __restrict__ C,
                                                  ushort* __restrict__ Cb,
                                                  int M, int N, int K) {
    __shared__ __align__(16) char smem[24576];
    char* Ab = smem;              // [64 rows][128 B]
    char* Bb = smem + 8192;       // [128 rows][128 B]
    const int t = threadIdx.x;
    const int l = t & 63, w = t >> 6;
    const int wr = w >> 1, wc = w & 1;
    const int lg = l >> 4, lc = l & 15;
    const int m0 = blockIdx.x * 64, n0 = blockIdx.y * 128;
    const int sr8 = l >> 3, oct = l & 7;
    const int arw0 = 16 * w + sr8, arw1 = arw0 + 8;
    const ushort* ga0 = A + (size_t)(m0 + arw0) * K + (oct ^ (arw0 & 7)) * 8;
    const ushort* ga1 = A + (size_t)(m0 + arw1) * K + (oct ^ (arw1 & 7)) * 8;
    char* la0 = Ab + w * 2048;
    char* la1 = Ab + w * 2048 + 1024;
    const int brw0 = 32 * w + sr8, brw1 = brw0 + 8, brw2 = brw0 + 16, brw3 = brw0 + 24;
    const ushort* gb0 = B + (size_t)(n0 + brw0) * K + (oct ^ (brw0 & 7)) * 8;
    const ushort* gb1 = B + (size_t)(n0 + brw1) * K + (oct ^ (brw1 & 7)) * 8;
    const ushort* gb2 = B + (size_t)(n0 + brw2) * K + (oct ^ (brw2 & 7)) * 8;
    const ushort* gb3 = B + (size_t)(n0 + brw3) * K + (oct ^ (brw3 & 7)) * 8;
    char* lb0 = Bb + w * 4096;
    char* lb1 = Bb + w * 4096 + 1024;
    char* lb2 = Bb + w * 4096 + 2048;
    char* lb3 = Bb + w * 4096 + 3072;
    const int ar0 = wr * 32 + lc, ar1 = ar0 + 16;
    int aoff[2][2], boff[2][4];
    #pragma unroll
    for (int kk = 0; kk < 2; ++kk) {
        aoff[kk][0] = ar0 * 128 + (((kk * 4 + lg) ^ (ar0 & 7)) * 16);
        aoff[kk][1] = ar1 * 128 + (((kk * 4 + lg) ^ (ar1 & 7)) * 16);
        #pragma unroll
        for (int f = 0; f < 4; ++f) {
            int bc = wc * 64 + f * 16 + lc;
            boff[kk][f] = bc * 128 + (((kk * 4 + lg) ^ (bc & 7)) * 16);
        }
    }
    f32x4 acc[2][4];
    #pragma unroll
    for (int m = 0; m < 2; ++m)
        #pragma unroll
        for (int f = 0; f < 4; ++f) acc[m][f] = (f32x4){0.f, 0.f, 0.f, 0.f};

    #pragma unroll 1
    for (int k0 = 0; k0 < K; k0 += 64) {
        __syncthreads();
        gll16(ga0 + k0, la0); gll16(ga1 + k0, la1);
        gll16(gb0 + k0, lb0); gll16(gb1 + k0, lb1);
        gll16(gb2 + k0, lb2); gll16(gb3 + k0, lb3);
        __syncthreads();
        #pragma unroll
        for (int kk = 0; kk < 2; ++kk) {
            short8 a0 = *(const short8*)(Ab + aoff[kk][0]);
            short8 a1 = *(const short8*)(Ab + aoff[kk][1]);
            short8 bfr[4];
            #pragma unroll
            for (int f = 0; f < 4; ++f) bfr[f] = *(const short8*)(Bb + boff[kk][f]);
            #pragma unroll
            for (int f = 0; f < 4; ++f) {
                acc[0][f] = __builtin_amdgcn_mfma_f32_16x16x32_bf16(a0, bfr[f], acc[0][f], 0, 0, 0);
                acc[1][f] = __builtin_amdgcn_mfma_f32_16x16x32_bf16(a1, bfr[f], acc[1][f], 0, 0, 0);
            }
        }
    }
    #pragma unroll
    for (int m = 0; m < 2; ++m)
        #pragma unroll
        for (int f = 0; f < 4; ++f)
            #pragma unroll
            for (int i = 0; i < 4; ++i) {
                int row = m0 + wr * 32 + m * 16 + lg * 4 + i;
                int col = n0 + wc * 64 + f * 16 + lc;
                float v = acc[m][f][i];
                if (RELU) v = fmaxf(v, 0.f);
                if (WF32) C[(size_t)row * N + col] = v;
                if (WB16) Cb[(size_t)row * N + col] = f2bf(v);
            }
}

// prob epilogue with exact fp32 fixup for flagged entries
__global__ __launch_bounds__(256) void k_prob2(const float* __restrict__ emb,
                                               const float* __restrict__ cpt,
                                               const float* __restrict__ cn_sq,
                                               float* __restrict__ S,
                                               ushort* __restrict__ probb) {
    __shared__ float erow[768];
    __shared__ float sval[512];
    __shared__ int idxl[512];
    __shared__ int cnt;
    __shared__ float redw[4];
    const int b = blockIdx.x, t = threadIdx.x;
    const int l = t & 63, w = t >> 6;
    if (t == 0) cnt = 0;
    float s = 0.f;
    #pragma unroll
    for (int j = 0; j < 3; ++j) {
        float v = emb[(size_t)b * 768 + t + j * 256];
        erow[t + j * 256] = v; s += v * v;
    }
    #pragma unroll
    for (int o = 32; o > 0; o >>= 1) s += __shfl_down(s, o);
    if (l == 0) redw[w] = s;
    __syncthreads();
    const float rn = fmaxf(sqrtf(redw[0] + redw[1] + redw[2] + redw[3]), 1e-12f);
    #pragma unroll
    for (int j = 0; j < 2; ++j) {
        int c = t + j * 256;
        sval[c] = 0.f;
        float cn = fmaxf(sqrtf(cn_sq[c]), 1e-12f);
        float sn = S[(size_t)b * 512 + c] / (rn * cn);
        if (sn > 0.1f - 4e-3f) { int p = atomicAdd(&cnt, 1); idxl[p] = c; }
    }
    __syncthreads();
    const int nf = cnt;
    for (int q0 = 0; q0 < nf; q0 += 4) {
        int q = q0 + w;
        if (q < nf) {
            int c = idxl[q];
            float p = 0.f;
            #pragma unroll
            for (int ii = 0; ii < 12; ++ii) {
                int d = l + ii * 64;
                p += erow[d] * cpt[(size_t)d * 512 + c];
            }
            #pragma unroll
            for (int o = 32; o > 0; o >>= 1) p += __shfl_down(p, o);
            if (l == 0) {
                float cn = fmaxf(sqrtf(cn_sq[c]), 1e-12f);
                sval[c] = (p / (rn * cn) > 0.1f) ? p : 0.f;
            }
        }
    }
    __syncthreads();
    float s2 = sval[t] + sval[t + 256];
    #pragma unroll
    for (int o = 32; o > 0; o >>= 1) s2 += __shfl_down(s2, o);
    if (l == 0) redw[w] = s2;
    __syncthreads();
    const float denom = redw[0] + redw[1] + redw[2] + redw[3] + 0.001f;
    #pragma unroll
    for (int j = 0; j < 2; ++j) {
        int c = t + j * 256;
        float pr = sval[c] / denom;
        S[(size_t)b * 512 + c] = pr;
        probb[(size_t)b * 512 + c] = f2bf(pr);
    }
}

// cx GEMM, m97 geometry: 128x128 tile, 2x2 waves, acc[4][4]/wave, BK=32,
// single-buffered gload_lds, slot^=(row&3) swizzle. Fused top-10 (2 phases).
// grid (512 nb, 4 cgroups). cand[grow*512+nb] in out-region (write-once).
__global__ __launch_bounds__(256, 3) void k_cx_topk4(const ushort* __restrict__ cptb, // [512][768]
                                                     const ushort* __restrict__ XbT,  // [65536][768]
                                                     const float* __restrict__ cn_sq,
                                                     const float* __restrict__ en,
                                                     float2* __restrict__ cand) {
    __shared__ __align__(16) char smem[34048];
    char* Ab = smem;              // [128 rows][64 B] = 8 KB
    char* Bb = smem + 8192;       // [128 rows][64 B] = 8 KB
    float* Ct = (float*)smem;     // [64][133] f32 (34048 B) aliased
    float* ML = (float*)smem;     // [256][20] aliased

    const int t = threadIdx.x;
    const int l = t & 63, w = t >> 6;
    const int wr = w >> 1, wc = w & 1;
    const int lg = l >> 4, lc = l & 15;
    const int c0 = blockIdx.y * 128;
    const int n0 = blockIdx.x * 128;
    const float FINF = __builtin_inff();

    // staging: wave w covers rows 32w..32w+31 (2 gll16 calls of 16 rows)
    const int sr = l >> 2, slot = l & 3;            // row-within-16, 16B slot
    const int arw0 = 32 * w + sr, arw1 = arw0 + 16;
    const ushort* ga0 = cptb + (size_t)(c0 + arw0) * 768 + ((slot ^ (arw0 & 3)) * 8);
    const ushort* ga1 = cptb + (size_t)(c0 + arw1) * 768 + ((slot ^ (arw1 & 3)) * 8);
    const ushort* gb0 = XbT + (size_t)(n0 + arw0) * 768 + ((slot ^ (arw0 & 3)) * 8);
    const ushort* gb1 = XbT + (size_t)(n0 + arw1) * 768 + ((slot ^ (arw1 & 3)) * 8);
    char* la0 = Ab + w * 2048;
    char* la1 = Ab + w * 2048 + 1024;
    char* lb0 = Bb + w * 2048;
    char* lb1 = Bb + w * 2048 + 1024;

    // fragment read offsets: row a -> a*64 + ((lg ^ (a&3))*16)
    int aoff[4], boff[4];
    #pragma unroll
    for (int mi = 0; mi < 4; ++mi) {
        int a = wr * 64 + mi * 16 + lc;
        aoff[mi] = a * 64 + ((lg ^ (a & 3)) * 16);
    }
    #pragma unroll
    for (int f = 0; f < 4; ++f) {
        int b = wc * 64 + f * 16 + lc;
        boff[f] = b * 64 + ((lg ^ (b & 3)) * 16);
    }

    f32x4 acc[4][4];
    #pragma unroll
    for (int mi = 0; mi < 4; ++mi)
        #pragma unroll
        for (int f = 0; f < 4; ++f) acc[mi][f] = (f32x4){0.f, 0.f, 0.f, 0.f};

    #pragma unroll 1
    for (int k0 = 0; k0 < 768; k0 += 32) {
        __syncthreads();
        gll16(ga0 + k0, la0); gll16(ga1 + k0, la1);
        gll16(gb0 + k0, lb0); gll16(gb1 + k0, lb1);
        __syncthreads();
        short8 av[4], bv[4];
        #pragma unroll
        for (int mi = 0; mi < 4; ++mi) av[mi] = *(const short8*)(Ab + aoff[mi]);
        #pragma unroll
        for (int f = 0; f < 4; ++f) bv[f] = *(const short8*)(Bb + boff[f]);
        #pragma unroll
        for (int f = 0; f < 4; ++f)
            #pragma unroll
            for (int mi = 0; mi < 4; ++mi)
                acc[mi][f] = __builtin_amdgcn_mfma_f32_16x16x32_bf16(av[mi], bv[f], acc[mi][f], 0, 0, 0);
    }

    const int r = t >> 2, g = t & 3;
    // ---- 2 scan phases: waves with wr==p stage their 64x128 half ----
    #pragma unroll 1
    for (int p = 0; p < 2; ++p) {
        __syncthreads();
        if (wr == p) {
            #pragma unroll
            for (int mi = 0; mi < 4; ++mi)
                #pragma unroll
                for (int f = 0; f < 4; ++f)
                    #pragma unroll
                    for (int i = 0; i < 4; ++i)
                        Ct[(mi * 16 + lg * 4 + i) * 133 + wc * 64 + f * 16 + lc] = acc[mi][f][i];
        }
        __syncthreads();
        const int grow = c0 + p * 64 + r;
        const float cnr = cn_sq[grow];
        float topd[10], topv[10];
        #pragma unroll
        for (int i = 0; i < 10; ++i) { topd[i] = FINF; topv[i] = 0.f; }
        #pragma unroll 1
        for (int u = 0; u < 32; ++u) {
            int c = u * 4 + g;
            float val = Ct[r * 133 + c];
            float dist = cnr + en[n0 + c] - 2.f * val;
            if (dist < topd[9]) {
                topd[9] = dist; topv[9] = val;
                #pragma unroll
                for (int i = 9; i > 0; --i) {
                    if (topd[i] < topd[i - 1]) {
                        float td = topd[i]; topd[i] = topd[i - 1]; topd[i - 1] = td;
                        float tv = topv[i]; topv[i] = topv[i - 1]; topv[i - 1] = tv;
                    }
                }
            }
        }
        __syncthreads();   // Ct reads done before ML overwrite (alias)
        #pragma unroll
        for (int i = 0; i < 10; ++i) {
            ML[t * 20 + 2 * i] = topd[i];
            ML[t * 20 + 2 * i + 1] = topv[i];
        }
        __syncthreads();
        if (g == 0) {
            #pragma unroll 1
            for (int o = 1; o < 4; ++o) {
                const float* L = &ML[(t + o) * 20];
                #pragma unroll 1
                for (int i = 0; i < 10; ++i) {
                    float nd = L[2 * i];
                    if (nd >= topd[9]) break;
                    float nv = L[2 * i + 1];
                    topd[9] = nd; topv[9] = nv;
                    #pragma unroll
                    for (int x = 9; x > 0; --x) {
                        if (topd[x] < topd[x - 1]) {
                            float td = topd[x]; topd[x] = topd[x - 1]; topd[x - 1] = td;
                            float tv = topv[x]; topv[x] = topv[x - 1]; topv[x - 1] = tv;
                        }
                    }
                }
            }
            float2* dst = &cand[((size_t)grow * 512 + blockIdx.x) * 10];
            #pragma unroll
            for (int i = 0; i < 10; ++i) dst[i] = make_float2(topd[i], topv[i]);
        }
    }
}

// ======================= FALLBACK PATH (round-3, proven) =======================
template <int RELU>
__global__ __launch_bounds__(256) void k_gemm(const float* __restrict__ A,
                                              const float* __restrict__ Bm,
                                              float* __restrict__ Cm,
                                              int M, int N, int K) {
    __shared__ float As[16][68];
    __shared__ float Bs[16][128];
    const int t = threadIdx.x;
    const int m0 = blockIdx.x * 64, n0 = blockIdx.y * 128;
    const int tm = t >> 4, tn = t & 15;
    float acc[4][8] = {};
    #pragma unroll 1
    for (int k0 = 0; k0 < K; k0 += 16) {
        {
            int i = t >> 2, kk4 = (t & 3) * 4;
            float4 av = *(const float4*)&A[(size_t)(m0 + i) * K + k0 + kk4];
            As[kk4 + 0][i] = av.x; As[kk4 + 1][i] = av.y;
            As[kk4 + 2][i] = av.z; As[kk4 + 3][i] = av.w;
        }
        {
            int kk = t >> 5, c4 = (t & 31) * 4;
            *(float4*)&Bs[kk][c4] = *(const float4*)&Bm[(size_t)(k0 + kk) * N + n0 + c4];
            *(float4*)&Bs[kk + 8][c4] = *(const float4*)&Bm[(size_t)(k0 + kk + 8) * N + n0 + c4];
        }
        __syncthreads();
        #pragma unroll
        for (int k = 0; k < 16; ++k) {
            float4 a4 = *(const float4*)&As[k][tm * 4];
            float4 b0 = *(const float4*)&Bs[k][tn * 4];
            float4 b1 = *(const float4*)&Bs[k][64 + tn * 4];
            float av[4] = {a4.x, a4.y, a4.z, a4.w};
            float bv[8] = {b0.x, b0.y, b0.z, b0.w, b1.x, b1.y, b1.z, b1.w};
            #pragma unroll
            for (int i = 0; i < 4; ++i)
                #pragma unroll
                for (int j = 0; j < 8; ++j) acc[i][j] += av[i] * bv[j];
        }
        __syncthreads();
    }
    #pragma unroll
    for (int i = 0; i < 4; ++i) {
        int row = m0 + tm * 4 + i;
        float4 o0 = make_float4(acc[i][0], acc[i][1], acc[i][2], acc[i][3]);
        float4 o1 = make_float4(acc[i][4], acc[i][5], acc[i][6], acc[i][7]);
        if (RELU) {
            o0.x = fmaxf(o0.x, 0.f); o0.y = fmaxf(o0.y, 0.f);
            o0.z = fmaxf(o0.z, 0.f); o0.w = fmaxf(o0.w, 0.f);
            o1.x = fmaxf(o1.x, 0.f); o1.y = fmaxf(o1.y, 0.f);
            o1.z = fmaxf(o1.z, 0.f); o1.w = fmaxf(o1.w, 0.f);
        }
        *(float4*)&Cm[(size_t)row * N + n0 + tn * 4] = o0;
        *(float4*)&Cm[(size_t)row * N + n0 + 64 + tn * 4] = o1;
    }
}

template <int RELU>
__global__ __launch_bounds__(256) void k_gemm_bf(const float* __restrict__ A,
                                                 const float* __restrict__ Bm,
                                                 float* __restrict__ Cm,
                                                 int M, int N, int K) {
    __shared__ __align__(16) char smem[15360];
    char* Ab = smem;
    char* Bb = smem + 5120;
    const int t = threadIdx.x;
    const int l = t & 63, w = t >> 6;
    const int wr = w >> 1, wc = w & 1;
    const int lg = l >> 4, lc = l & 15;
    const int m0 = blockIdx.x * 64, n0 = blockIdx.y * 128;
    const int ar = t >> 2, ak = (t & 3) * 8;
    const int bc = t & 63, bw = t >> 6;
    f32x4 acc[2][4];
    #pragma unroll
    for (int m = 0; m < 2; ++m)
        #pragma unroll
        for (int f = 0; f < 4; ++f) acc[m][f] = (f32x4){0.f, 0.f, 0.f, 0.f};
    #pragma unroll 1
    for (int k0 = 0; k0 < K; k0 += 32) {
        __syncthreads();
        {
            const float* p = &A[(size_t)(m0 + ar) * K + k0 + ak];
            float4 a0 = *(const float4*)p;
            float4 a1 = *(const float4*)(p + 4);
            uint4 da = make_uint4(pack2(a0.x, a0.y), pack2(a0.z, a0.w),
                                  pack2(a1.x, a1.y), pack2(a1.z, a1.w));
            *(uint4*)(Ab + ar * 80 + (t & 3) * 16) = da;
        }
        #pragma unroll
        for (int j = 0; j < 2; ++j) {
            float x[8];
            #pragma unroll
            for (int i = 0; i < 8; ++i)
                x[i] = Bm[(size_t)(k0 + 8 * bw + i) * N + n0 + bc + 64 * j];
            uint4 db = make_uint4(pack2(x[0], x[1]), pack2(x[2], x[3]),
                                  pack2(x[4], x[5]), pack2(x[6], x[7]));
            *(uint4*)(Bb + (bc + 64 * j) * 80 + bw * 16) = db;
        }
        __syncthreads();
        short8 af0 = *(const short8*)(Ab + (wr * 32 + lc) * 80 + lg * 16);
        short8 af1 = *(const short8*)(Ab + (wr * 32 + 16 + lc) * 80 + lg * 16);
        short8 bfr[4];
        #pragma unroll
        for (int f = 0; f < 4; ++f)
            bfr[f] = *(const short8*)(Bb + (wc * 64 + f * 16 + lc) * 80 + lg * 16);
        #pragma unroll
        for (int f = 0; f < 4; ++f) {
            acc[0][f] = __builtin_amdgcn_mfma_f32_16x16x32_bf16(af0, bfr[f], acc[0][f], 0, 0, 0);
            acc[1][f] = __builtin_amdgcn_mfma_f32_16x16x32_bf16(af1, bfr[f], acc[1][f], 0, 0, 0);
        }
    }
    #pragma unroll
    for (int m = 0; m < 2; ++m)
        #pragma unroll
        for (int f = 0; f < 4; ++f)
            #pragma unroll
            for (int i = 0; i < 4; ++i) {
                int row = m0 + wr * 32 + m * 16 + lg * 4 + i;
                int col = n0 + wc * 64 + f * 16 + lc;
                float v = acc[m][f][i];
                if (RELU) v = fmaxf(v, 0.f);
                Cm[(size_t)row * N + col] = v;
            }
}

__global__ __launch_bounds__(256) void k_prob(const float* __restrict__ emb,
                                              const float* __restrict__ cn_sq,
                                              float* __restrict__ S) {
    __shared__ float red[256];
    int b = blockIdx.x, t = threadIdx.x;
    float s = 0.f;
    #pragma unroll
    for (int j = 0; j < 3; ++j) { float v = emb[(size_t)b * 768 + t + j * 256]; s += v * v; }
    red[t] = s; __syncthreads();
    for (int st = 128; st > 0; st >>= 1) { if (t < st) red[t] += red[t + st]; __syncthreads(); }
    float rn = fmaxf(sqrtf(red[0]), 1e-12f);
    __syncthreads();
    float vals[2]; float sum = 0.f;
    #pragma unroll
    for (int j = 0; j < 2; ++j) {
        int cc = t + j * 256;
        float sc = S[(size_t)b * 512 + cc];
        float cn = fmaxf(sqrtf(cn_sq[cc]), 1e-12f);
        float v = (sc / (rn * cn) > 0.1f) ? sc : 0.f;
        vals[j] = v; sum += v;
    }
    red[t] = sum; __syncthreads();
    for (int st = 128; st > 0; st >>= 1) { if (t < st) red[t] += red[t + st]; __syncthreads(); }
    float denom = red[0] + 0.001f;
    #pragma unroll
    for (int j = 0; j < 2; ++j) S[(size_t)b * 512 + (t + j * 256)] = vals[j] / denom;
}

__global__ void k_en(const float* __restrict__ X, float* __restrict__ en) {
    int n4 = blockIdx.x * 256 + threadIdx.x;
    float4 s = make_float4(0.f, 0.f, 0.f, 0.f);
    #pragma unroll 4
    for (int d = 0; d < 768; ++d) {
        float4 v = *(const float4*)&X[(size_t)d * 65536 + n4 * 4];
        s.x += v.x * v.x; s.y += v.y * v.y; s.z += v.z * v.z; s.w += v.w * v.w;
    }
    *(float4*)&en[n4 * 4] = s;
}

__global__ __launch_bounds__(256, 4) void k_cx_topk(const float* __restrict__ cpt,
                                                    const float* __restrict__ X,
                                                    const float* __restrict__ cn_sq,
                                                    const float* __restrict__ en,
                                                    float2* __restrict__ cand) {
    __shared__ __align__(16) char smem_c[34048];
    float* Ct = (float*)smem_c;
    char* Ab = smem_c;
    char* Bb = smem_c + 5120;
    const int t = threadIdx.x;
    const int l = t & 63, w = t >> 6;
    const int wr = w >> 1, wc = w & 1;
    const int lg = l >> 4, lc = l & 15;
    const int c0 = blockIdx.y * 64;
    const int nbase = blockIdx.x * 512;
    const float FINF = __builtin_inff();
    const int sc_ = t & 63, sw = t >> 6;
    const int r = t >> 2, g = t & 3;
    float topd[10], topv[10];
    #pragma unroll
    for (int i = 0; i < 10; ++i) { topd[i] = FINF; topv[i] = 0.f; }
    const float cnr = cn_sq[c0 + r];
    #pragma unroll 1
    for (int s = 0; s < 4; ++s) {
        const int n0 = nbase + s * 128;
        f32x4 acc[2][4];
        #pragma unroll
        for (int m = 0; m < 2; ++m)
            #pragma unroll
            for (int f = 0; f < 4; ++f) acc[m][f] = (f32x4){0.f, 0.f, 0.f, 0.f};
        #pragma unroll 1
        for (int k0 = 0; k0 < 768; k0 += 32) {
            __syncthreads();
            {
                float x[8];
                #pragma unroll
                for (int i = 0; i < 8; ++i)
                    x[i] = cpt[(size_t)(k0 + 8 * sw + i) * 512 + c0 + sc_];
                uint4 da = make_uint4(pack2(x[0], x[1]), pack2(x[2], x[3]),
                                      pack2(x[4], x[5]), pack2(x[6], x[7]));
                *(uint4*)(Ab + sc_ * 80 + sw * 16) = da;
            }
            #pragma unroll
            for (int j = 0; j < 2; ++j) {
                float x[8];
                #pragma unroll
                for (int i = 0; i < 8; ++i)
                    x[i] = X[(size_t)(k0 + 8 * sw + i) * 65536 + n0 + sc_ + 64 * j];
                uint4 db = make_uint4(pack2(x[0], x[1]), pack2(x[2], x[3]),
                                      pack2(x[4], x[5]), pack2(x[6], x[7]));
                *(uint4*)(Bb + (sc_ + 64 * j) * 80 + sw * 16) = db;
            }
            __syncthreads();
            short8 af0 = *(const short8*)(Ab + (wr * 32 + lc) * 80 + lg * 16);
            short8 af1 = *(const short8*)(Ab + (wr * 32 + 16 + lc) * 80 + lg * 16);
            short8 bfr[4];
            #pragma unroll
            for (int f = 0; f < 4; ++f)
                bfr[f] = *(const short8*)(Bb + (wc * 64 + f * 16 + lc) * 80 + lg * 16);
            #pragma unroll
            for (int f = 0; f < 4; ++f) {
                acc[0][f] = __builtin_amdgcn_mfma_f32_16x16x32_bf16(af0, bfr[f], acc[0][f], 0, 0, 0);
                acc[1][f] = __builtin_amdgcn_mfma_f32_16x16x32_bf16(af1, bfr[f], acc[1][f], 0, 0, 0);
            }
        }
        __syncthreads();
        #pragma unroll
        for (int m = 0; m < 2; ++m)
            #pragma unroll
            for (int f = 0; f < 4; ++f)
                #pragma unroll
                for (int i = 0; i < 4; ++i)
                    Ct[(wr * 32 + m * 16 + lg * 4 + i) * 133 + wc * 64 + f * 16 + lc] = acc[m][f][i];
        __syncthreads();
        #pragma unroll 1
        for (int u = 0; u < 32; ++u) {
            int c = u * 4 + g;
            float val = Ct[r * 133 + c];
            float dist = cnr + en[n0 + c] - 2.f * val;
            if (dist < topd[9]) {
                topd[9] = dist; topv[9] = val;
                #pragma unroll
                for (int i = 9; i > 0; --i) {
                    if (topd[i] < topd[i - 1]) {
                        float td = topd[i]; topd[i] = topd[i - 1]; topd[i - 1] = td;
                        float tv = topv[i]; topv[i] = topv[i - 1]; topv[i - 1] = tv;
                    }
                }
            }
        }
        __syncthreads();
    }
    float* ML = (float*)smem_c;
    #pragma unroll
    for (int i = 0; i < 10; ++i) {
        ML[t * 20 + 2 * i] = topd[i];
        ML[t * 20 + 2 * i + 1] = topv[i];
    }
    __syncthreads();
    if (g == 0) {
        #pragma unroll 1
        for (int o = 1; o < 4; ++o) {
            const float* L = &ML[(t + o) * 20];
            #pragma unroll 1
            for (int i = 0; i < 10; ++i) {
                float nd = L[2 * i];
                if (nd >= topd[9]) break;
                float nv = L[2 * i + 1];
                topd[9] = nd; topv[9] = nv;
                #pragma unroll
                for (int x = 9; x > 0; --x) {
                    if (topd[x] < topd[x - 1]) {
                        float td = topd[x]; topd[x] = topd[x - 1]; topd[x - 1] = td;
                        float tv = topv[x]; topv[x] = topv[x - 1]; topv[x - 1] = tv;
                    }
                }
            }
        }
        float2* dst = &cand[((size_t)(c0 + r) * 128 + blockIdx.x) * 10];
        #pragma unroll
        for (int i = 0; i < 10; ++i) dst[i] = make_float2(topd[i], topv[i]);
    }
}

// ======================= launcher =======================
extern "C" void kernel_launch(void* const* d_in, const int* in_sizes, int n_in,
                              void* d_out, int out_size, void* d_ws, size_t ws_size,
                              hipStream_t stream) {
    const float* emb = (const float*)d_in[0];   // [8192 x 768]
    const float* X   = (const float*)d_in[1];   // [768 x 65536]
    const float* cpt = (const float*)d_in[2];   // [768 x 512]
    const float* r1  = (const float*)d_in[3];   // [512 x 256]
    const float* r2  = (const float*)d_in[4];   // [256 x 768]
    float* out = (float*)d_out;
    float* ws = (float*)d_ws;
    float* S = out + 6291456;                   // prob region doubles as score scratch

    const size_t OFF_CN = 0, OFF_EN = 512, OFF_ACC = 66048, OFF_XBT = 66560;
    const size_t OFF_EMBB = 25232384, OFF_CPTB = 28378112, OFF_R1T = 28574720;
    const size_t OFF_R2T = 28640256, OFF_PRBB = 28738560, OFF_RL1B = 30835712;
    const size_t OFF_CAND = 31884288;
    const size_t WS_NEED = OFF_CAND * 4;        // cand lives in out-region on fast path

    if (ws_size >= WS_NEED) {
        float* cn_sq = ws + OFF_CN;
        float* en    = ws + OFF_EN;
        float* acc   = ws + OFF_ACC;
        ushort* XbT  = (ushort*)(ws + OFF_XBT);
        ushort* embb = (ushort*)(ws + OFF_EMBB);
        ushort* cptb = (ushort*)(ws + OFF_CPTB);
        ushort* r1T  = (ushort*)(ws + OFF_R1T);
        ushort* r2T  = (ushort*)(ws + OFF_R2T);
        ushort* prbb = (ushort*)(ws + OFF_PRBB);
        ushort* rl1b = (ushort*)(ws + OFF_RL1B);
        float2* cand = (float2*)out;            // [512 rows][512 nb][10] = 21 MB, write-once

        k_zero<<<259, 256, 0, stream>>>(ws, 66056);
        k_col_sumsq<<<dim3(2, 8), 256, 0, stream>>>(cpt, cn_sq);
        k_row_stats<<<48, 256, 0, stream>>>(cpt, acc);
        k_tc<1><<<dim3(256, 24), 256, 0, stream>>>(X, XbT, en, 65536, 768);
        k_tc<0><<<dim3(2, 24), 256, 0, stream>>>(cpt, cptb, nullptr, 512, 768);
        k_tc<0><<<dim3(1, 16), 256, 0, stream>>>(r1, r1T, nullptr, 256, 512);
        k_tc<0><<<dim3(3, 8), 256, 0, stream>>>(r2, r2T, nullptr, 768, 256);
        k_cvt_emb<<<3072, 256, 0, stream>>>(emb, embb);
        // knn chain first: cand occupies out[0..5.25M floats], freed before rec2 writes out
        k_cx_topk4<<<dim3(512, 4), 256, 0, stream>>>(cptb, XbT, cn_sq, en, cand);
        k_knn_merge<5120><<<512, 256, 0, stream>>>(cand, acc);
        gemm_bt<1, 0, 0><<<dim3(128, 4), 256, 0, stream>>>(embb, cptb, S, nullptr, 8192, 512, 768);
        k_prob2<<<8192, 256, 0, stream>>>(emb, cpt, cn_sq, S, prbb);
        gemm_bt<0, 1, 1><<<dim3(128, 2), 256, 0, stream>>>(prbb, r1T, nullptr, rl1b, 8192, 256, 512);
        gemm_bt<1, 0, 0><<<dim3(128, 6), 256, 0, stream>>>(rl1b, r2T, out, nullptr, 8192, 768, 256);
        k_finalize<<<1, 64, 0, stream>>>(acc, out);
    } else {
        float* cn_sq = ws;
        float* en    = ws + 512;
        float* acc   = ws + 66048;
        float* rl1   = ws + 66560;
        float2* cand = (float2*)(ws + 66560 + 8192 * 256);
        k_init<<<1, 256, 0, stream>>>(cn_sq, acc);
        k_col_sumsq<<<dim3(2, 8), 256, 0, stream>>>(cpt, cn_sq);
        k_row_stats<<<48, 256, 0, stream>>>(cpt, acc);
        k_gemm<0><<<dim3(128, 4), 256, 0, stream>>>(emb, cpt, S, 8192, 512, 768);
        k_prob<<<8192, 256, 0, stream>>>(emb, cn_sq, S);
        k_gemm_bf<1><<<dim3(128, 2), 256, 0, stream>>>(S, r1, rl1, 8192, 256, 512);
        k_gemm_bf<0><<<dim3(128, 6), 256, 0, stream>>>(rl1, r2, out, 8192, 768, 256);
        k_en<<<64, 256, 0, stream>>>(X, en);
        k_cx_topk<<<dim3(128, 8), 256, 0, stream>>>(cpt, X, cn_sq, en, cand);
        k_knn_merge<1280><<<512, 256, 0, stream>>>(cand, acc);
        k_finalize<<<1, 64, 0, stream>>>(acc, out);
    }
}

// Round 9
// 487.814 us; speedup vs baseline: 1.0081x; 1.0081x over previous
//
#include <hip/hip_runtime.h>

// Problem constants: B=8192, D=768, C=512, H=256, N=65536, k=10.
// Outputs (flat): rec_layer_2 [8192*768], prob [8192*512], L1, L2.

typedef __attribute__((ext_vector_type(8))) short short8;
typedef __attribute__((ext_vector_type(4))) float f32x4;
typedef unsigned int u32;

__device__ __forceinline__ ushort f2bf(float f) {
    unsigned u = __builtin_bit_cast(unsigned, f);
    u += 0x7FFFu + ((u >> 16) & 1u);          // round-to-nearest-even
    return (ushort)(u >> 16);
}
__device__ __forceinline__ unsigned pack2(float lo, float hi) {
    return (unsigned)f2bf(lo) | ((unsigned)f2bf(hi) << 16);
}
// async global->LDS, 16B per lane; lds dest = wave-uniform base + lane*16
__device__ __forceinline__ void gll16(const void* g, void* l) {
    __builtin_amdgcn_global_load_lds((const __attribute__((address_space(1))) u32*)g,
                                     (__attribute__((address_space(3))) u32*)l, 16, 0, 0);
}

// ======================= shared small kernels =======================
__global__ void k_zero(float* p, int n) {
    int i = blockIdx.x * 256 + threadIdx.x;
    if (i < n) p[i] = 0.f;
}
__global__ void k_init(float* cn_sq, float* acc) {
    int t = threadIdx.x;
    cn_sq[t] = 0.f; cn_sq[t + 256] = 0.f;
    if (t < 8) acc[t] = 0.f;
}
__global__ void k_col_sumsq(const float* __restrict__ cpt, float* __restrict__ cn_sq) {
    int c = blockIdx.x * 256 + threadIdx.x;
    int d0 = blockIdx.y * 96;
    float s = 0.f;
    #pragma unroll 4
    for (int d = d0; d < d0 + 96; ++d) { float v = cpt[d * 512 + c]; s += v * v; }
    atomicAdd(&cn_sq[c], s);
}
__global__ void k_row_stats(const float* __restrict__ cpt, float* __restrict__ acc) {
    __shared__ float red[256];
    int t = threadIdx.x;
    int d = blockIdx.x * 16;
    float rowsq = 0.f, tot = 0.f;
    for (int r = 0; r < 16; ++r, ++d) {
        float v1 = cpt[d * 512 + t], v2 = cpt[d * 512 + 256 + t];
        tot += v1 * v1 + v2 * v2;
        red[t] = v1 + v2;
        __syncthreads();
        for (int st = 128; st > 0; st >>= 1) {
            if (t < st) red[t] += red[t + st];
            __syncthreads();
        }
        if (t == 0) rowsq += red[0] * red[0];
        __syncthreads();
    }
    red[t] = tot; __syncthreads();
    for (int st = 128; st > 0; st >>= 1) {
        if (t < st) red[t] += red[t + st];
        __syncthreads();
    }
    if (t == 0) { atomicAdd(&acc[1], rowsq); atomicAdd(&acc[2], red[0]); }
}

template <int NB>
__global__ __launch_bounds__(256) void k_knn_merge(const float2* __restrict__ cand,
                                                   float* __restrict__ acc) {
    __shared__ float2 buf[NB];
    __shared__ float2 l2[160];
    int c = blockIdx.x, t = threadIdx.x;
    const float FINF = __builtin_inff();
    const float2* src = &cand[(size_t)c * NB];
    for (int i = t; i < NB; i += 256) buf[i] = src[i];
    __syncthreads();
    if (t < 16) {
        float td[10], tv[10];
        #pragma unroll
        for (int i = 0; i < 10; ++i) { td[i] = FINF; tv[i] = 0.f; }
        const int per = NB / 16;
        for (int j = t * per; j < t * per + per; ++j) {
            float nd = buf[j].x;
            if (nd < td[9]) {
                td[9] = nd; tv[9] = buf[j].y;
                #pragma unroll
                for (int x = 9; x > 0; --x)
                    if (td[x] < td[x - 1]) {
                        float a = td[x]; td[x] = td[x - 1]; td[x - 1] = a;
                        float b = tv[x]; tv[x] = tv[x - 1]; tv[x - 1] = b;
                    }
            }
        }
        #pragma unroll
        for (int i = 0; i < 10; ++i) l2[t * 10 + i] = make_float2(td[i], tv[i]);
    }
    __syncthreads();
    if (t == 0) {
        float td[10], tv[10];
        #pragma unroll
        for (int i = 0; i < 10; ++i) { td[i] = FINF; tv[i] = 0.f; }
        for (int j = 0; j < 160; ++j) {
            float nd = l2[j].x;
            if (nd < td[9]) {
                td[9] = nd; tv[9] = l2[j].y;
                #pragma unroll
                for (int x = 9; x > 0; --x)
                    if (td[x] < td[x - 1]) {
                        float a = td[x]; td[x] = td[x - 1]; td[x - 1] = a;
                        float b = tv[x]; tv[x] = tv[x - 1]; tv[x - 1] = b;
                    }
            }
        }
        float s = 0.f;
        #pragma unroll
        for (int i = 0; i < 10; ++i) s += tv[i];
        atomicAdd(&acc[0], s);
    }
}
__global__ void k_finalize(const float* __restrict__ acc, float* __restrict__ out) {
    if (threadIdx.x == 0) {
        out[10485760] = acc[0] / 5120.0f;
        out[10485761] = (acc[1] - acc[2]) / 262144.0f;
    }
}

// ======================= FAST PATH =======================
template <int EN>
__global__ __launch_bounds__(256) void k_tc(const float* __restrict__ src,
                                            ushort* __restrict__ dst,
                                            float* __restrict__ en,
                                            int Ncols, int D) {
    __shared__ float tile[32][256];
    const int t = threadIdx.x;
    const int n0 = blockIdx.x * 256;
    const int d0 = blockIdx.y * 32;
    float s = 0.f;
    #pragma unroll 8
    for (int dd = 0; dd < 32; ++dd) {
        float v = src[(size_t)(d0 + dd) * Ncols + n0 + t];
        tile[dd][t] = v;
        if (EN) s += v * v;
    }
    if (EN) atomicAdd(&en[n0 + t], s);
    __syncthreads();
    ushort* drow = dst + (size_t)(n0 + t) * D + d0;
    #pragma unroll
    for (int q = 0; q < 4; ++q) {
        uint4 d4;
        d4.x = pack2(tile[q * 8 + 0][t], tile[q * 8 + 1][t]);
        d4.y = pack2(tile[q * 8 + 2][t], tile[q * 8 + 3][t]);
        d4.z = pack2(tile[q * 8 + 4][t], tile[q * 8 + 5][t]);
        d4.w = pack2(tile[q * 8 + 6][t], tile[q * 8 + 7][t]);
        *(uint4*)(drow + q * 8) = d4;
    }
}

__global__ void k_cvt_emb(const float* __restrict__ src, ushort* __restrict__ dst) {
    int i = (blockIdx.x * 256 + threadIdx.x) * 8;
    float4 a = *(const float4*)&src[i], b = *(const float4*)&src[i + 4];
    uint4 d4 = make_uint4(pack2(a.x, a.y), pack2(a.z, a.w), pack2(b.x, b.y), pack2(b.z, b.w));
    *(uint4*)&dst[i] = d4;
}

// C = A[MxK] @ B[NxK]^T, bf16 in, gload_lds staging, tile 64x128, BK=64 (R5 proven).
template <int WF32, int WB16, int RELU>
__global__ __launch_bounds__(256, 4) void gemm_bt(const ushort* __restrict__ A,
                                                  const ushort* __restrict__ B,
                                                  float* __restrict__ C,
                                                  ushort* __restrict__ Cb,
                                                  int M, int N, int K) {
    __shared__ __align__(16) char smem[24576];
    char* Ab = smem;              // [64 rows][128 B]
    char* Bb = smem + 8192;       // [128 rows][128 B]
    const int t = threadIdx.x;
    const int l = t & 63, w = t >> 6;
    const int wr = w >> 1, wc = w & 1;
    const int lg = l >> 4, lc = l & 15;
    const int m0 = blockIdx.x * 64, n0 = blockIdx.y * 128;
    const int sr8 = l >> 3, oct = l & 7;
    const int arw0 = 16 * w + sr8, arw1 = arw0 + 8;
    const ushort* ga0 = A + (size_t)(m0 + arw0) * K + (oct ^ (arw0 & 7)) * 8;
    const ushort* ga1 = A + (size_t)(m0 + arw1) * K + (oct ^ (arw1 & 7)) * 8;
    char* la0 = Ab + w * 2048;
    char* la1 = Ab + w * 2048 + 1024;
    const int brw0 = 32 * w + sr8, brw1 = brw0 + 8, brw2 = brw0 + 16, brw3 = brw0 + 24;
    const ushort* gb0 = B + (size_t)(n0 + brw0) * K + (oct ^ (brw0 & 7)) * 8;
    const ushort* gb1 = B + (size_t)(n0 + brw1) * K + (oct ^ (brw1 & 7)) * 8;
    const ushort* gb2 = B + (size_t)(n0 + brw2) * K + (oct ^ (brw2 & 7)) * 8;
    const ushort* gb3 = B + (size_t)(n0 + brw3) * K + (oct ^ (brw3 & 7)) * 8;
    char* lb0 = Bb + w * 4096;
    char* lb1 = Bb + w * 4096 + 1024;
    char* lb2 = Bb + w * 4096 + 2048;
    char* lb3 = Bb + w * 4096 + 3072;
    const int ar0 = wr * 32 + lc, ar1 = ar0 + 16;
    int aoff[2][2], boff[2][4];
    #pragma unroll
    for (int kk = 0; kk < 2; ++kk) {
        aoff[kk][0] = ar0 * 128 + (((kk * 4 + lg) ^ (ar0 & 7)) * 16);
        aoff[kk][1] = ar1 * 128 + (((kk * 4 + lg) ^ (ar1 & 7)) * 16);
        #pragma unroll
        for (int f = 0; f < 4; ++f) {
            int bc = wc * 64 + f * 16 + lc;
            boff[kk][f] = bc * 128 + (((kk * 4 + lg) ^ (bc & 7)) * 16);
        }
    }
    f32x4 acc[2][4];
    #pragma unroll
    for (int m = 0; m < 2; ++m)
        #pragma unroll
        for (int f = 0; f < 4; ++f) acc[m][f] = (f32x4){0.f, 0.f, 0.f, 0.f};

    #pragma unroll 1
    for (int k0 = 0; k0 < K; k0 += 64) {
        __syncthreads();
        gll16(ga0 + k0, la0); gll16(ga1 + k0, la1);
        gll16(gb0 + k0, lb0); gll16(gb1 + k0, lb1);
        gll16(gb2 + k0, lb2); gll16(gb3 + k0, lb3);
        __syncthreads();
        #pragma unroll
        for (int kk = 0; kk < 2; ++kk) {
            short8 a0 = *(const short8*)(Ab + aoff[kk][0]);
            short8 a1 = *(const short8*)(Ab + aoff[kk][1]);
            short8 bfr[4];
            #pragma unroll
            for (int f = 0; f < 4; ++f) bfr[f] = *(const short8*)(Bb + boff[kk][f]);
            #pragma unroll
            for (int f = 0; f < 4; ++f) {
                acc[0][f] = __builtin_amdgcn_mfma_f32_16x16x32_bf16(a0, bfr[f], acc[0][f], 0, 0, 0);
                acc[1][f] = __builtin_amdgcn_mfma_f32_16x16x32_bf16(a1, bfr[f], acc[1][f], 0, 0, 0);
            }
        }
    }
    #pragma unroll
    for (int m = 0; m < 2; ++m)
        #pragma unroll
        for (int f = 0; f < 4; ++f)
            #pragma unroll
            for (int i = 0; i < 4; ++i) {
                int row = m0 + wr * 32 + m * 16 + lg * 4 + i;
                int col = n0 + wc * 64 + f * 16 + lc;
                float v = acc[m][f][i];
                if (RELU) v = fmaxf(v, 0.f);
                if (WF32) C[(size_t)row * N + col] = v;
                if (WB16) Cb[(size_t)row * N + col] = f2bf(v);
            }
}

// prob epilogue with exact fp32 fixup for flagged entries
__global__ __launch_bounds__(256) void k_prob2(const float* __restrict__ emb,
                                               const float* __restrict__ cpt,
                                               const float* __restrict__ cn_sq,
                                               float* __restrict__ S,
                                               ushort* __restrict__ probb) {
    __shared__ float erow[768];
    __shared__ float sval[512];
    __shared__ int idxl[512];
    __shared__ int cnt;
    __shared__ float redw[4];
    const int b = blockIdx.x, t = threadIdx.x;
    const int l = t & 63, w = t >> 6;
    if (t == 0) cnt = 0;
    float s = 0.f;
    #pragma unroll
    for (int j = 0; j < 3; ++j) {
        float v = emb[(size_t)b * 768 + t + j * 256];
        erow[t + j * 256] = v; s += v * v;
    }
    #pragma unroll
    for (int o = 32; o > 0; o >>= 1) s += __shfl_down(s, o);
    if (l == 0) redw[w] = s;
    __syncthreads();
    const float rn = fmaxf(sqrtf(redw[0] + redw[1] + redw[2] + redw[3]), 1e-12f);
    #pragma unroll
    for (int j = 0; j < 2; ++j) {
        int c = t + j * 256;
        sval[c] = 0.f;
        float cn = fmaxf(sqrtf(cn_sq[c]), 1e-12f);
        float sn = S[(size_t)b * 512 + c] / (rn * cn);
        if (sn > 0.1f - 4e-3f) { int p = atomicAdd(&cnt, 1); idxl[p] = c; }
    }
    __syncthreads();
    const int nf = cnt;
    for (int q0 = 0; q0 < nf; q0 += 4) {
        int q = q0 + w;
        if (q < nf) {
            int c = idxl[q];
            float p = 0.f;
            #pragma unroll
            for (int ii = 0; ii < 12; ++ii) {
                int d = l + ii * 64;
                p += erow[d] * cpt[(size_t)d * 512 + c];
            }
            #pragma unroll
            for (int o = 32; o > 0; o >>= 1) p += __shfl_down(p, o);
            if (l == 0) {
                float cn = fmaxf(sqrtf(cn_sq[c]), 1e-12f);
                sval[c] = (p / (rn * cn) > 0.1f) ? p : 0.f;
            }
        }
    }
    __syncthreads();
    float s2 = sval[t] + sval[t + 256];
    #pragma unroll
    for (int o = 32; o > 0; o >>= 1) s2 += __shfl_down(s2, o);
    if (l == 0) redw[w] = s2;
    __syncthreads();
    const float denom = redw[0] + redw[1] + redw[2] + redw[3] + 0.001f;
    #pragma unroll
    for (int j = 0; j < 2; ++j) {
        int c = t + j * 256;
        float pr = sval[c] / denom;
        S[(size_t)b * 512 + c] = pr;
        probb[(size_t)b * 512 + c] = f2bf(pr);
    }
}

// cx GEMM: 128x128 tile, BK=64, 4 waves 2x2 (each 64x64, acc[4][4]),
// R5-proven 128B-row oct^(row&7) swizzle, single-buffered gload_lds.
// Fused top-10 in 2 scan phases. grid (512 nb, 4 cgroups).
// cand[grow*512+nb] in out-region (write-once).
__global__ __launch_bounds__(256, 3) void k_cx_topk5(const ushort* __restrict__ cptb, // [512][768]
                                                     const ushort* __restrict__ XbT,  // [65536][768]
                                                     const float* __restrict__ cn_sq,
                                                     const float* __restrict__ en,
                                                     float2* __restrict__ cand) {
    __shared__ __align__(16) char smem[34048];
    char* Ab = smem;              // [128 rows][128 B] = 16 KB
    char* Bb = smem + 16384;      // [128 rows][128 B] = 16 KB
    float* Ct = (float*)smem;     // [64][133] f32 (34048 B) aliased
    float* ML = (float*)smem;     // [256][20] aliased

    const int t = threadIdx.x;
    const int l = t & 63, w = t >> 6;
    const int wr = w >> 1, wc = w & 1;
    const int lg = l >> 4, lc = l & 15;
    const int c0 = blockIdx.y * 128;
    const int n0 = blockIdx.x * 128;
    const float FINF = __builtin_inff();

    // staging: wave w covers rows 32w..32w+31 of A and of B (4 calls each, 8 rows/call)
    const int sr8 = l >> 3, oct = l & 7;
    int arow[4], asrc[4];
    #pragma unroll
    for (int j = 0; j < 4; ++j) {
        arow[j] = 32 * w + 8 * j + sr8;
        asrc[j] = (oct ^ (arow[j] & 7)) * 8;
    }
    const ushort* ga[4];
    const ushort* gb[4];
    #pragma unroll
    for (int j = 0; j < 4; ++j) {
        ga[j] = cptb + (size_t)(c0 + arow[j]) * 768 + asrc[j];
        gb[j] = XbT + (size_t)(n0 + arow[j]) * 768 + asrc[j];
    }

    // fragment read offsets: row a -> a*128 + ((kk*4+lg)^(a&7))*16
    int aoff[2][4], boff[2][4];
    #pragma unroll
    for (int kk = 0; kk < 2; ++kk) {
        #pragma unroll
        for (int mi = 0; mi < 4; ++mi) {
            int a = wr * 64 + mi * 16 + lc;
            aoff[kk][mi] = a * 128 + (((kk * 4 + lg) ^ (a & 7)) * 16);
        }
        #pragma unroll
        for (int f = 0; f < 4; ++f) {
            int b = wc * 64 + f * 16 + lc;
            boff[kk][f] = b * 128 + (((kk * 4 + lg) ^ (b & 7)) * 16);
        }
    }

    f32x4 acc[4][4];
    #pragma unroll
    for (int mi = 0; mi < 4; ++mi)
        #pragma unroll
        for (int f = 0; f < 4; ++f) acc[mi][f] = (f32x4){0.f, 0.f, 0.f, 0.f};

    #pragma unroll 1
    for (int k0 = 0; k0 < 768; k0 += 64) {
        __syncthreads();
        #pragma unroll
        for (int j = 0; j < 4; ++j) {
            gll16(ga[j] + k0, Ab + (32 * w + 8 * j) * 128);
            gll16(gb[j] + k0, Bb + (32 * w + 8 * j) * 128);
        }
        __syncthreads();
        #pragma unroll
        for (int kk = 0; kk < 2; ++kk) {
            short8 av[4], bv[4];
            #pragma unroll
            for (int mi = 0; mi < 4; ++mi) av[mi] = *(const short8*)(Ab + aoff[kk][mi]);
            #pragma unroll
            for (int f = 0; f < 4; ++f) bv[f] = *(const short8*)(Bb + boff[kk][f]);
            #pragma unroll
            for (int f = 0; f < 4; ++f)
                #pragma unroll
                for (int mi = 0; mi < 4; ++mi)
                    acc[mi][f] = __builtin_amdgcn_mfma_f32_16x16x32_bf16(av[mi], bv[f], acc[mi][f], 0, 0, 0);
        }
    }

    const int r = t >> 2, g = t & 3;
    // ---- 2 scan phases: waves with wr==p stage their 64x128 half ----
    #pragma unroll 1
    for (int p = 0; p < 2; ++p) {
        __syncthreads();
        if (wr == p) {
            #pragma unroll
            for (int mi = 0; mi < 4; ++mi)
                #pragma unroll
                for (int f = 0; f < 4; ++f)
                    #pragma unroll
                    for (int i = 0; i < 4; ++i)
                        Ct[(mi * 16 + lg * 4 + i) * 133 + wc * 64 + f * 16 + lc] = acc[mi][f][i];
        }
        __syncthreads();
        const int grow = c0 + p * 64 + r;
        const float cnr = cn_sq[grow];
        float topd[10], topv[10];
        #pragma unroll
        for (int i = 0; i < 10; ++i) { topd[i] = FINF; topv[i] = 0.f; }
        #pragma unroll 1
        for (int u = 0; u < 32; ++u) {
            int c = u * 4 + g;
            float val = Ct[r * 133 + c];
            float dist = cnr + en[n0 + c] - 2.f * val;
            if (dist < topd[9]) {
                topd[9] = dist; topv[9] = val;
                #pragma unroll
                for (int i = 9; i > 0; --i) {
                    if (topd[i] < topd[i - 1]) {
                        float td = topd[i]; topd[i] = topd[i - 1]; topd[i - 1] = td;
                        float tv = topv[i]; topv[i] = topv[i - 1]; topv[i - 1] = tv;
                    }
                }
            }
        }
        __syncthreads();   // Ct reads done before ML overwrite (alias)
        #pragma unroll
        for (int i = 0; i < 10; ++i) {
            ML[t * 20 + 2 * i] = topd[i];
            ML[t * 20 + 2 * i + 1] = topv[i];
        }
        __syncthreads();
        if (g == 0) {
            #pragma unroll 1
            for (int o = 1; o < 4; ++o) {
                const float* L = &ML[(t + o) * 20];
                #pragma unroll 1
                for (int i = 0; i < 10; ++i) {
                    float nd = L[2 * i];
                    if (nd >= topd[9]) break;
                    float nv = L[2 * i + 1];
                    topd[9] = nd; topv[9] = nv;
                    #pragma unroll
                    for (int x = 9; x > 0; --x) {
                        if (topd[x] < topd[x - 1]) {
                            float td = topd[x]; topd[x] = topd[x - 1]; topd[x - 1] = td;
                            float tv = topv[x]; topv[x] = topv[x - 1]; topv[x - 1] = tv;
                        }
                    }
                }
            }
            float2* dst = &cand[((size_t)grow * 512 + blockIdx.x) * 10];
            #pragma unroll
            for (int i = 0; i < 10; ++i) dst[i] = make_float2(topd[i], topv[i]);
        }
    }
}

// ======================= FALLBACK PATH (round-3, proven) =======================
template <int RELU>
__global__ __launch_bounds__(256) void k_gemm(const float* __restrict__ A,
                                              const float* __restrict__ Bm,
                                              float* __restrict__ Cm,
                                              int M, int N, int K) {
    __shared__ float As[16][68];
    __shared__ float Bs[16][128];
    const int t = threadIdx.x;
    const int m0 = blockIdx.x * 64, n0 = blockIdx.y * 128;
    const int tm = t >> 4, tn = t & 15;
    float acc[4][8] = {};
    #pragma unroll 1
    for (int k0 = 0; k0 < K; k0 += 16) {
        {
            int i = t >> 2, kk4 = (t & 3) * 4;
            float4 av = *(const float4*)&A[(size_t)(m0 + i) * K + k0 + kk4];
            As[kk4 + 0][i] = av.x; As[kk4 + 1][i] = av.y;
            As[kk4 + 2][i] = av.z; As[kk4 + 3][i] = av.w;
        }
        {
            int kk = t >> 5, c4 = (t & 31) * 4;
            *(float4*)&Bs[kk][c4] = *(const float4*)&Bm[(size_t)(k0 + kk) * N + n0 + c4];
            *(float4*)&Bs[kk + 8][c4] = *(const float4*)&Bm[(size_t)(k0 + kk + 8) * N + n0 + c4];
        }
        __syncthreads();
        #pragma unroll
        for (int k = 0; k < 16; ++k) {
            float4 a4 = *(const float4*)&As[k][tm * 4];
            float4 b0 = *(const float4*)&Bs[k][tn * 4];
            float4 b1 = *(const float4*)&Bs[k][64 + tn * 4];
            float av[4] = {a4.x, a4.y, a4.z, a4.w};
            float bv[8] = {b0.x, b0.y, b0.z, b0.w, b1.x, b1.y, b1.z, b1.w};
            #pragma unroll
            for (int i = 0; i < 4; ++i)
                #pragma unroll
                for (int j = 0; j < 8; ++j) acc[i][j] += av[i] * bv[j];
        }
        __syncthreads();
    }
    #pragma unroll
    for (int i = 0; i < 4; ++i) {
        int row = m0 + tm * 4 + i;
        float4 o0 = make_float4(acc[i][0], acc[i][1], acc[i][2], acc[i][3]);
        float4 o1 = make_float4(acc[i][4], acc[i][5], acc[i][6], acc[i][7]);
        if (RELU) {
            o0.x = fmaxf(o0.x, 0.f); o0.y = fmaxf(o0.y, 0.f);
            o0.z = fmaxf(o0.z, 0.f); o0.w = fmaxf(o0.w, 0.f);
            o1.x = fmaxf(o1.x, 0.f); o1.y = fmaxf(o1.y, 0.f);
            o1.z = fmaxf(o1.z, 0.f); o1.w = fmaxf(o1.w, 0.f);
        }
        *(float4*)&Cm[(size_t)row * N + n0 + tn * 4] = o0;
        *(float4*)&Cm[(size_t)row * N + n0 + 64 + tn * 4] = o1;
    }
}

template <int RELU>
__global__ __launch_bounds__(256) void k_gemm_bf(const float* __restrict__ A,
                                                 const float* __restrict__ Bm,
                                                 float* __restrict__ Cm,
                                                 int M, int N, int K) {
    __shared__ __align__(16) char smem[15360];
    char* Ab = smem;
    char* Bb = smem + 5120;
    const int t = threadIdx.x;
    const int l = t & 63, w = t >> 6;
    const int wr = w >> 1, wc = w & 1;
    const int lg = l >> 4, lc = l & 15;
    const int m0 = blockIdx.x * 64, n0 = blockIdx.y * 128;
    const int ar = t >> 2, ak = (t & 3) * 8;
    const int bc = t & 63, bw = t >> 6;
    f32x4 acc[2][4];
    #pragma unroll
    for (int m = 0; m < 2; ++m)
        #pragma unroll
        for (int f = 0; f < 4; ++f) acc[m][f] = (f32x4){0.f, 0.f, 0.f, 0.f};
    #pragma unroll 1
    for (int k0 = 0; k0 < K; k0 += 32) {
        __syncthreads();
        {
            const float* p = &A[(size_t)(m0 + ar) * K + k0 + ak];
            float4 a0 = *(const float4*)p;
            float4 a1 = *(const float4*)(p + 4);
            uint4 da = make_uint4(pack2(a0.x, a0.y), pack2(a0.z, a0.w),
                                  pack2(a1.x, a1.y), pack2(a1.z, a1.w));
            *(uint4*)(Ab + ar * 80 + (t & 3) * 16) = da;
        }
        #pragma unroll
        for (int j = 0; j < 2; ++j) {
            float x[8];
            #pragma unroll
            for (int i = 0; i < 8; ++i)
                x[i] = Bm[(size_t)(k0 + 8 * bw + i) * N + n0 + bc + 64 * j];
            uint4 db = make_uint4(pack2(x[0], x[1]), pack2(x[2], x[3]),
                                  pack2(x[4], x[5]), pack2(x[6], x[7]));
            *(uint4*)(Bb + (bc + 64 * j) * 80 + bw * 16) = db;
        }
        __syncthreads();
        short8 af0 = *(const short8*)(Ab + (wr * 32 + lc) * 80 + lg * 16);
        short8 af1 = *(const short8*)(Ab + (wr * 32 + 16 + lc) * 80 + lg * 16);
        short8 bfr[4];
        #pragma unroll
        for (int f = 0; f < 4; ++f)
            bfr[f] = *(const short8*)(Bb + (wc * 64 + f * 16 + lc) * 80 + lg * 16);
        #pragma unroll
        for (int f = 0; f < 4; ++f) {
            acc[0][f] = __builtin_amdgcn_mfma_f32_16x16x32_bf16(af0, bfr[f], acc[0][f], 0, 0, 0);
            acc[1][f] = __builtin_amdgcn_mfma_f32_16x16x32_bf16(af1, bfr[f], acc[1][f], 0, 0, 0);
        }
    }
    #pragma unroll
    for (int m = 0; m < 2; ++m)
        #pragma unroll
        for (int f = 0; f < 4; ++f)
            #pragma unroll
            for (int i = 0; i < 4; ++i) {
                int row = m0 + wr * 32 + m * 16 + lg * 4 + i;
                int col = n0 + wc * 64 + f * 16 + lc;
                float v = acc[m][f][i];
                if (RELU) v = fmaxf(v, 0.f);
                Cm[(size_t)row * N + col] = v;
            }
}

__global__ __launch_bounds__(256) void k_prob(const float* __restrict__ emb,
                                              const float* __restrict__ cn_sq,
                                              float* __restrict__ S) {
    __shared__ float red[256];
    int b = blockIdx.x, t = threadIdx.x;
    float s = 0.f;
    #pragma unroll
    for (int j = 0; j < 3; ++j) { float v = emb[(size_t)b * 768 + t + j * 256]; s += v * v; }
    red[t] = s; __syncthreads();
    for (int st = 128; st > 0; st >>= 1) { if (t < st) red[t] += red[t + st]; __syncthreads(); }
    float rn = fmaxf(sqrtf(red[0]), 1e-12f);
    __syncthreads();
    float vals[2]; float sum = 0.f;
    #pragma unroll
    for (int j = 0; j < 2; ++j) {
        int cc = t + j * 256;
        float sc = S[(size_t)b * 512 + cc];
        float cn = fmaxf(sqrtf(cn_sq[cc]), 1e-12f);
        float v = (sc / (rn * cn) > 0.1f) ? sc : 0.f;
        vals[j] = v; sum += v;
    }
    red[t] = sum; __syncthreads();
    for (int st = 128; st > 0; st >>= 1) { if (t < st) red[t] += red[t + st]; __syncthreads(); }
    float denom = red[0] + 0.001f;
    #pragma unroll
    for (int j = 0; j < 2; ++j) S[(size_t)b * 512 + (t + j * 256)] = vals[j] / denom;
}

__global__ void k_en(const float* __restrict__ X, float* __restrict__ en) {
    int n4 = blockIdx.x * 256 + threadIdx.x;
    float4 s = make_float4(0.f, 0.f, 0.f, 0.f);
    #pragma unroll 4
    for (int d = 0; d < 768; ++d) {
        float4 v = *(const float4*)&X[(size_t)d * 65536 + n4 * 4];
        s.x += v.x * v.x; s.y += v.y * v.y; s.z += v.z * v.z; s.w += v.w * v.w;
    }
    *(float4*)&en[n4 * 4] = s;
}

__global__ __launch_bounds__(256, 4) void k_cx_topk(const float* __restrict__ cpt,
                                                    const float* __restrict__ X,
                                                    const float* __restrict__ cn_sq,
                                                    const float* __restrict__ en,
                                                    float2* __restrict__ cand) {
    __shared__ __align__(16) char smem_c[34048];
    float* Ct = (float*)smem_c;
    char* Ab = smem_c;
    char* Bb = smem_c + 5120;
    const int t = threadIdx.x;
    const int l = t & 63, w = t >> 6;
    const int wr = w >> 1, wc = w & 1;
    const int lg = l >> 4, lc = l & 15;
    const int c0 = blockIdx.y * 64;
    const int nbase = blockIdx.x * 512;
    const float FINF = __builtin_inff();
    const int sc_ = t & 63, sw = t >> 6;
    const int r = t >> 2, g = t & 3;
    float topd[10], topv[10];
    #pragma unroll
    for (int i = 0; i < 10; ++i) { topd[i] = FINF; topv[i] = 0.f; }
    const float cnr = cn_sq[c0 + r];
    #pragma unroll 1
    for (int s = 0; s < 4; ++s) {
        const int n0 = nbase + s * 128;
        f32x4 acc[2][4];
        #pragma unroll
        for (int m = 0; m < 2; ++m)
            #pragma unroll
            for (int f = 0; f < 4; ++f) acc[m][f] = (f32x4){0.f, 0.f, 0.f, 0.f};
        #pragma unroll 1
        for (int k0 = 0; k0 < 768; k0 += 32) {
            __syncthreads();
            {
                float x[8];
                #pragma unroll
                for (int i = 0; i < 8; ++i)
                    x[i] = cpt[(size_t)(k0 + 8 * sw + i) * 512 + c0 + sc_];
                uint4 da = make_uint4(pack2(x[0], x[1]), pack2(x[2], x[3]),
                                      pack2(x[4], x[5]), pack2(x[6], x[7]));
                *(uint4*)(Ab + sc_ * 80 + sw * 16) = da;
            }
            #pragma unroll
            for (int j = 0; j < 2; ++j) {
                float x[8];
                #pragma unroll
                for (int i = 0; i < 8; ++i)
                    x[i] = X[(size_t)(k0 + 8 * sw + i) * 65536 + n0 + sc_ + 64 * j];
                uint4 db = make_uint4(pack2(x[0], x[1]), pack2(x[2], x[3]),
                                      pack2(x[4], x[5]), pack2(x[6], x[7]));
                *(uint4*)(Bb + (sc_ + 64 * j) * 80 + sw * 16) = db;
            }
            __syncthreads();
            short8 af0 = *(const short8*)(Ab + (wr * 32 + lc) * 80 + lg * 16);
            short8 af1 = *(const short8*)(Ab + (wr * 32 + 16 + lc) * 80 + lg * 16);
            short8 bfr[4];
            #pragma unroll
            for (int f = 0; f < 4; ++f)
                bfr[f] = *(const short8*)(Bb + (wc * 64 + f * 16 + lc) * 80 + lg * 16);
            #pragma unroll
            for (int f = 0; f < 4; ++f) {
                acc[0][f] = __builtin_amdgcn_mfma_f32_16x16x32_bf16(af0, bfr[f], acc[0][f], 0, 0, 0);
                acc[1][f] = __builtin_amdgcn_mfma_f32_16x16x32_bf16(af1, bfr[f], acc[1][f], 0, 0, 0);
            }
        }
        __syncthreads();
        #pragma unroll
        for (int m = 0; m < 2; ++m)
            #pragma unroll
            for (int f = 0; f < 4; ++f)
                #pragma unroll
                for (int i = 0; i < 4; ++i)
                    Ct[(wr * 32 + m * 16 + lg * 4 + i) * 133 + wc * 64 + f * 16 + lc] = acc[m][f][i];
        __syncthreads();
        #pragma unroll 1
        for (int u = 0; u < 32; ++u) {
            int c = u * 4 + g;
            float val = Ct[r * 133 + c];
            float dist = cnr + en[n0 + c] - 2.f * val;
            if (dist < topd[9]) {
                topd[9] = dist; topv[9] = val;
                #pragma unroll
                for (int i = 9; i > 0; --i) {
                    if (topd[i] < topd[i - 1]) {
                        float td = topd[i]; topd[i] = topd[i - 1]; topd[i - 1] = td;
                        float tv = topv[i]; topv[i] = topv[i - 1]; topv[i - 1] = tv;
                    }
                }
            }
        }
        __syncthreads();
    }
    float* ML = (float*)smem_c;
    #pragma unroll
    for (int i = 0; i < 10; ++i) {
        ML[t * 20 + 2 * i] = topd[i];
        ML[t * 20 + 2 * i + 1] = topv[i];
    }
    __syncthreads();
    if (g == 0) {
        #pragma unroll 1
        for (int o = 1; o < 4; ++o) {
            const float* L = &ML[(t + o) * 20];
            #pragma unroll 1
            for (int i = 0; i < 10; ++i) {
                float nd = L[2 * i];
                if (nd >= topd[9]) break;
                float nv = L[2 * i + 1];
                topd[9] = nd; topv[9] = nv;
                #pragma unroll
                for (int x = 9; x > 0; --x) {
                    if (topd[x] < topd[x - 1]) {
                        float td = topd[x]; topd[x] = topd[x - 1]; topd[x - 1] = td;
                        float tv = topv[x]; topv[x] = topv[x - 1]; topv[x - 1] = tv;
                    }
                }
            }
        }
        float2* dst = &cand[((size_t)(c0 + r) * 128 + blockIdx.x) * 10];
        #pragma unroll
        for (int i = 0; i < 10; ++i) dst[i] = make_float2(topd[i], topv[i]);
    }
}

// ======================= launcher =======================
extern "C" void kernel_launch(void* const* d_in, const int* in_sizes, int n_in,
                              void* d_out, int out_size, void* d_ws, size_t ws_size,
                              hipStream_t stream) {
    const float* emb = (const float*)d_in[0];   // [8192 x 768]
    const float* X   = (const float*)d_in[1];   // [768 x 65536]
    const float* cpt = (const float*)d_in[2];   // [768 x 512]
    const float* r1  = (const float*)d_in[3];   // [512 x 256]
    const float* r2  = (const float*)d_in[4];   // [256 x 768]
    float* out = (float*)d_out;
    float* ws = (float*)d_ws;
    float* S = out + 6291456;                   // prob region doubles as score scratch

    const size_t OFF_CN = 0, OFF_EN = 512, OFF_ACC = 66048, OFF_XBT = 66560;
    const size_t OFF_EMBB = 25232384, OFF_CPTB = 28378112, OFF_R1T = 28574720;
    const size_t OFF_R2T = 28640256, OFF_PRBB = 28738560, OFF_RL1B = 30835712;
    const size_t OFF_CAND = 31884288;
    const size_t WS_NEED = OFF_CAND * 4;        // cand lives in out-region on fast path

    if (ws_size >= WS_NEED) {
        float* cn_sq = ws + OFF_CN;
        float* en    = ws + OFF_EN;
        float* acc   = ws + OFF_ACC;
        ushort* XbT  = (ushort*)(ws + OFF_XBT);
        ushort* embb = (ushort*)(ws + OFF_EMBB);
        ushort* cptb = (ushort*)(ws + OFF_CPTB);
        ushort* r1T  = (ushort*)(ws + OFF_R1T);
        ushort* r2T  = (ushort*)(ws + OFF_R2T);
        ushort* prbb = (ushort*)(ws + OFF_PRBB);
        ushort* rl1b = (ushort*)(ws + OFF_RL1B);
        float2* cand = (float2*)out;            // [512 rows][512 nb][10] = 21 MB, write-once

        k_zero<<<259, 256, 0, stream>>>(ws, 66056);
        k_col_sumsq<<<dim3(2, 8), 256, 0, stream>>>(cpt, cn_sq);
        k_row_stats<<<48, 256, 0, stream>>>(cpt, acc);
        k_tc<1><<<dim3(256, 24), 256, 0, stream>>>(X, XbT, en, 65536, 768);
        k_tc<0><<<dim3(2, 24), 256, 0, stream>>>(cpt, cptb, nullptr, 512, 768);
        k_tc<0><<<dim3(1, 16), 256, 0, stream>>>(r1, r1T, nullptr, 256, 512);
        k_tc<0><<<dim3(3, 8), 256, 0, stream>>>(r2, r2T, nullptr, 768, 256);
        k_cvt_emb<<<3072, 256, 0, stream>>>(emb, embb);
        // knn chain first: cand occupies out[0..5.25M floats], freed before rec2 writes out
        k_cx_topk5<<<dim3(512, 4), 256, 0, stream>>>(cptb, XbT, cn_sq, en, cand);
        k_knn_merge<5120><<<512, 256, 0, stream>>>(cand, acc);
        gemm_bt<1, 0, 0><<<dim3(128, 4), 256, 0, stream>>>(embb, cptb, S, nullptr, 8192, 512, 768);
        k_prob2<<<8192, 256, 0, stream>>>(emb, cpt, cn_sq, S, prbb);
        gemm_bt<0, 1, 1><<<dim3(128, 2), 256, 0, stream>>>(prbb, r1T, nullptr, rl1b, 8192, 256, 512);
        gemm_bt<1, 0, 0><<<dim3(128, 6), 256, 0, stream>>>(rl1b, r2T, out, nullptr, 8192, 768, 256);
        k_finalize<<<1, 64, 0, stream>>>(acc, out);
    } else {
        float* cn_sq = ws;
        float* en    = ws + 512;
        float* acc   = ws + 66048;
        float* rl1   = ws + 66560;
        float2* cand = (float2*)(ws + 66560 + 8192 * 256);
        k_init<<<1, 256, 0, stream>>>(cn_sq, acc);
        k_col_sumsq<<<dim3(2, 8), 256, 0, stream>>>(cpt, cn_sq);
        k_row_stats<<<48, 256, 0, stream>>>(cpt, acc);
        k_gemm<0><<<dim3(128, 4), 256, 0, stream>>>(emb, cpt, S, 8192, 512, 768);
        k_prob<<<8192, 256, 0, stream>>>(emb, cn_sq, S);
        k_gemm_bf<1><<<dim3(128, 2), 256, 0, stream>>>(S, r1, rl1, 8192, 256, 512);
        k_gemm_bf<0><<<dim3(128, 6), 256, 0, stream>>>(rl1, r2, out, 8192, 768, 256);
        k_en<<<64, 256, 0, stream>>>(X, en);
        k_cx_topk<<<dim3(128, 8), 256, 0, stream>>>(cpt, X, cn_sq, en, cand);
        k_knn_merge<1280><<<512, 256, 0, stream>>>(cand, acc);
        k_finalize<<<1, 64, 0, stream>>>(acc, out);
    }
}

// Round 11
// 370.638 us; speedup vs baseline: 1.3268x; 1.3161x over previous
//
#include <hip/hip_runtime.h>

// Problem constants: B=8192, D=768, C=512, H=256, N=65536, k=10.
// Outputs (flat): rec_layer_2 [8192*768], prob [8192*512], L1, L2.

typedef __attribute__((ext_vector_type(8))) short short8;
typedef __attribute__((ext_vector_type(4))) float f32x4;
typedef unsigned int u32;

__device__ __forceinline__ ushort f2bf(float f) {
    unsigned u = __builtin_bit_cast(unsigned, f);
    u += 0x7FFFu + ((u >> 16) & 1u);          // round-to-nearest-even
    return (ushort)(u >> 16);
}
__device__ __forceinline__ unsigned pack2(float lo, float hi) {
    return (unsigned)f2bf(lo) | ((unsigned)f2bf(hi) << 16);
}
// async global->LDS, 16B per lane; lds dest = wave-uniform base + lane*16
__device__ __forceinline__ void gll16(const void* g, void* l) {
    __builtin_amdgcn_global_load_lds((const __attribute__((address_space(1))) u32*)g,
                                     (__attribute__((address_space(3))) u32*)l, 16, 0, 0);
}

// ======================= shared small kernels =======================
__global__ void k_zero(float* p, int n) {
    int i = blockIdx.x * 256 + threadIdx.x;
    if (i < n) p[i] = 0.f;
}
__global__ void k_init(float* cn_sq, float* acc) {
    int t = threadIdx.x;
    cn_sq[t] = 0.f; cn_sq[t + 256] = 0.f;
    if (t < 8) acc[t] = 0.f;
}
__global__ void k_col_sumsq(const float* __restrict__ cpt, float* __restrict__ cn_sq) {
    int c = blockIdx.x * 256 + threadIdx.x;
    int d0 = blockIdx.y * 96;
    float s = 0.f;
    #pragma unroll 4
    for (int d = d0; d < d0 + 96; ++d) { float v = cpt[d * 512 + c]; s += v * v; }
    atomicAdd(&cn_sq[c], s);
}
__global__ void k_row_stats(const float* __restrict__ cpt, float* __restrict__ acc) {
    __shared__ float red[256];
    int t = threadIdx.x;
    int d = blockIdx.x * 16;
    float rowsq = 0.f, tot = 0.f;
    for (int r = 0; r < 16; ++r, ++d) {
        float v1 = cpt[d * 512 + t], v2 = cpt[d * 512 + 256 + t];
        tot += v1 * v1 + v2 * v2;
        red[t] = v1 + v2;
        __syncthreads();
        for (int st = 128; st > 0; st >>= 1) {
            if (t < st) red[t] += red[t + st];
            __syncthreads();
        }
        if (t == 0) rowsq += red[0] * red[0];
        __syncthreads();
    }
    red[t] = tot; __syncthreads();
    for (int st = 128; st > 0; st >>= 1) {
        if (t < st) red[t] += red[t + st];
        __syncthreads();
    }
    if (t == 0) { atomicAdd(&acc[1], rowsq); atomicAdd(&acc[2], red[0]); }
}

template <int NB>
__global__ __launch_bounds__(256) void k_knn_merge(const float2* __restrict__ cand,
                                                   float* __restrict__ acc) {
    __shared__ float2 buf[NB];
    __shared__ float2 l2[160];
    int c = blockIdx.x, t = threadIdx.x;
    const float FINF = __builtin_inff();
    const float2* src = &cand[(size_t)c * NB];
    for (int i = t; i < NB; i += 256) buf[i] = src[i];
    __syncthreads();
    if (t < 16) {
        float td[10], tv[10];
        #pragma unroll
        for (int i = 0; i < 10; ++i) { td[i] = FINF; tv[i] = 0.f; }
        const int per = NB / 16;
        for (int j = t * per; j < t * per + per; ++j) {
            float nd = buf[j].x;
            if (nd < td[9]) {
                td[9] = nd; tv[9] = buf[j].y;
                #pragma unroll
                for (int x = 9; x > 0; --x)
                    if (td[x] < td[x - 1]) {
                        float a = td[x]; td[x] = td[x - 1]; td[x - 1] = a;
                        float b = tv[x]; tv[x] = tv[x - 1]; tv[x - 1] = b;
                    }
            }
        }
        #pragma unroll
        for (int i = 0; i < 10; ++i) l2[t * 10 + i] = make_float2(td[i], tv[i]);
    }
    __syncthreads();
    if (t == 0) {
        float td[10], tv[10];
        #pragma unroll
        for (int i = 0; i < 10; ++i) { td[i] = FINF; tv[i] = 0.f; }
        for (int j = 0; j < 160; ++j) {
            float nd = l2[j].x;
            if (nd < td[9]) {
                td[9] = nd; tv[9] = l2[j].y;
                #pragma unroll
                for (int x = 9; x > 0; --x)
                    if (td[x] < td[x - 1]) {
                        float a = td[x]; td[x] = td[x - 1]; td[x - 1] = a;
                        float b = tv[x]; tv[x] = tv[x - 1]; tv[x - 1] = b;
                    }
            }
        }
        float s = 0.f;
        #pragma unroll
        for (int i = 0; i < 10; ++i) s += tv[i];
        atomicAdd(&acc[0], s);
    }
}
__global__ void k_finalize(const float* __restrict__ acc, float* __restrict__ out) {
    if (threadIdx.x == 0) {
        out[10485760] = acc[0] / 5120.0f;
        out[10485761] = (acc[1] - acc[2]) / 262144.0f;
    }
}

// ======================= FAST PATH =======================
template <int EN>
__global__ __launch_bounds__(256) void k_tc(const float* __restrict__ src,
                                            ushort* __restrict__ dst,
                                            float* __restrict__ en,
                                            int Ncols, int D) {
    __shared__ float tile[32][256];
    const int t = threadIdx.x;
    const int n0 = blockIdx.x * 256;
    const int d0 = blockIdx.y * 32;
    float s = 0.f;
    #pragma unroll 8
    for (int dd = 0; dd < 32; ++dd) {
        float v = src[(size_t)(d0 + dd) * Ncols + n0 + t];
        tile[dd][t] = v;
        if (EN) s += v * v;
    }
    if (EN) atomicAdd(&en[n0 + t], s);
    __syncthreads();
    ushort* drow = dst + (size_t)(n0 + t) * D + d0;
    #pragma unroll
    for (int q = 0; q < 4; ++q) {
        uint4 d4;
        d4.x = pack2(tile[q * 8 + 0][t], tile[q * 8 + 1][t]);
        d4.y = pack2(tile[q * 8 + 2][t], tile[q * 8 + 3][t]);
        d4.z = pack2(tile[q * 8 + 4][t], tile[q * 8 + 5][t]);
        d4.w = pack2(tile[q * 8 + 6][t], tile[q * 8 + 7][t]);
        *(uint4*)(drow + q * 8) = d4;
    }
}

__global__ void k_cvt_emb(const float* __restrict__ src, ushort* __restrict__ dst) {
    int i = (blockIdx.x * 256 + threadIdx.x) * 8;
    float4 a = *(const float4*)&src[i], b = *(const float4*)&src[i + 4];
    uint4 d4 = make_uint4(pack2(a.x, a.y), pack2(a.z, a.w), pack2(b.x, b.y), pack2(b.z, b.w));
    *(uint4*)&dst[i] = d4;
}

// C = A[MxK] @ B[NxK]^T, bf16 in, gload_lds staging, tile 64x128, BK=64.
// LDS rows 128B, slot swizzle oct^=(row&7); stage: 8 lanes/row, 1KB/call.
template <int WF32, int WB16, int RELU>
__global__ __launch_bounds__(256, 4) void gemm_bt(const ushort* __restrict__ A,
                                                  const ushort* __restrict__ B,
                                                  float* __restrict__ C,
                                                  ushort* __restrict__ Cb,
                                                  int M, int N, int K) {
    __shared__ __align__(16) char smem[24576];
    char* Ab = smem;              // [64 rows][128 B]
    char* Bb = smem + 8192;       // [128 rows][128 B]
    const int t = threadIdx.x;
    const int l = t & 63, w = t >> 6;
    const int wr = w >> 1, wc = w & 1;
    const int lg = l >> 4, lc = l & 15;
    const int m0 = blockIdx.x * 64, n0 = blockIdx.y * 128;
    const int sr8 = l >> 3, oct = l & 7;
    // A staging: 2 calls, rows 16w+8j+sr8
    const int arw0 = 16 * w + sr8, arw1 = arw0 + 8;
    const ushort* ga0 = A + (size_t)(m0 + arw0) * K + (oct ^ (arw0 & 7)) * 8;
    const ushort* ga1 = A + (size_t)(m0 + arw1) * K + (oct ^ (arw1 & 7)) * 8;
    char* la0 = Ab + w * 2048;
    char* la1 = Ab + w * 2048 + 1024;
    // B staging: 4 calls, rows 32w+8j+sr8
    const int brw0 = 32 * w + sr8, brw1 = brw0 + 8, brw2 = brw0 + 16, brw3 = brw0 + 24;
    const ushort* gb0 = B + (size_t)(n0 + brw0) * K + (oct ^ (brw0 & 7)) * 8;
    const ushort* gb1 = B + (size_t)(n0 + brw1) * K + (oct ^ (brw1 & 7)) * 8;
    const ushort* gb2 = B + (size_t)(n0 + brw2) * K + (oct ^ (brw2 & 7)) * 8;
    const ushort* gb3 = B + (size_t)(n0 + brw3) * K + (oct ^ (brw3 & 7)) * 8;
    char* lb0 = Bb + w * 4096;
    char* lb1 = Bb + w * 4096 + 1024;
    char* lb2 = Bb + w * 4096 + 2048;
    char* lb3 = Bb + w * 4096 + 3072;
    // fragment read offsets (swizzled), [kk][...]
    const int ar0 = wr * 32 + lc, ar1 = ar0 + 16;
    int aoff[2][2], boff[2][4];
    #pragma unroll
    for (int kk = 0; kk < 2; ++kk) {
        aoff[kk][0] = ar0 * 128 + (((kk * 4 + lg) ^ (ar0 & 7)) * 16);
        aoff[kk][1] = ar1 * 128 + (((kk * 4 + lg) ^ (ar1 & 7)) * 16);
        #pragma unroll
        for (int f = 0; f < 4; ++f) {
            int bc = wc * 64 + f * 16 + lc;
            boff[kk][f] = bc * 128 + (((kk * 4 + lg) ^ (bc & 7)) * 16);
        }
    }
    f32x4 acc[2][4];
    #pragma unroll
    for (int m = 0; m < 2; ++m)
        #pragma unroll
        for (int f = 0; f < 4; ++f) acc[m][f] = (f32x4){0.f, 0.f, 0.f, 0.f};

    #pragma unroll 1
    for (int k0 = 0; k0 < K; k0 += 64) {
        __syncthreads();
        gll16(ga0 + k0, la0); gll16(ga1 + k0, la1);
        gll16(gb0 + k0, lb0); gll16(gb1 + k0, lb1);
        gll16(gb2 + k0, lb2); gll16(gb3 + k0, lb3);
        __syncthreads();
        #pragma unroll
        for (int kk = 0; kk < 2; ++kk) {
            short8 a0 = *(const short8*)(Ab + aoff[kk][0]);
            short8 a1 = *(const short8*)(Ab + aoff[kk][1]);
            short8 bfr[4];
            #pragma unroll
            for (int f = 0; f < 4; ++f) bfr[f] = *(const short8*)(Bb + boff[kk][f]);
            #pragma unroll
            for (int f = 0; f < 4; ++f) {
                acc[0][f] = __builtin_amdgcn_mfma_f32_16x16x32_bf16(a0, bfr[f], acc[0][f], 0, 0, 0);
                acc[1][f] = __builtin_amdgcn_mfma_f32_16x16x32_bf16(a1, bfr[f], acc[1][f], 0, 0, 0);
            }
        }
    }
    #pragma unroll
    for (int m = 0; m < 2; ++m)
        #pragma unroll
        for (int f = 0; f < 4; ++f)
            #pragma unroll
            for (int i = 0; i < 4; ++i) {
                int row = m0 + wr * 32 + m * 16 + lg * 4 + i;
                int col = n0 + wc * 64 + f * 16 + lc;
                float v = acc[m][f][i];
                if (RELU) v = fmaxf(v, 0.f);
                if (WF32) C[(size_t)row * N + col] = v;
                if (WB16) Cb[(size_t)row * N + col] = f2bf(v);
            }
}

// prob epilogue with exact fp32 fixup for flagged (near/above threshold) entries
__global__ __launch_bounds__(256) void k_prob2(const float* __restrict__ emb,
                                               const float* __restrict__ cpt,
                                               const float* __restrict__ cn_sq,
                                               float* __restrict__ S,
                                               ushort* __restrict__ probb) {
    __shared__ float erow[768];
    __shared__ float sval[512];
    __shared__ int idxl[512];
    __shared__ int cnt;
    __shared__ float redw[4];
    const int b = blockIdx.x, t = threadIdx.x;
    const int l = t & 63, w = t >> 6;
    if (t == 0) cnt = 0;
    float s = 0.f;
    #pragma unroll
    for (int j = 0; j < 3; ++j) {
        float v = emb[(size_t)b * 768 + t + j * 256];
        erow[t + j * 256] = v; s += v * v;
    }
    #pragma unroll
    for (int o = 32; o > 0; o >>= 1) s += __shfl_down(s, o);
    if (l == 0) redw[w] = s;
    __syncthreads();
    const float rn = fmaxf(sqrtf(redw[0] + redw[1] + redw[2] + redw[3]), 1e-12f);
    #pragma unroll
    for (int j = 0; j < 2; ++j) {
        int c = t + j * 256;
        sval[c] = 0.f;
        float cn = fmaxf(sqrtf(cn_sq[c]), 1e-12f);
        float sn = S[(size_t)b * 512 + c] / (rn * cn);
        if (sn > 0.1f - 4e-3f) { int p = atomicAdd(&cnt, 1); idxl[p] = c; }
    }
    __syncthreads();
    const int nf = cnt;
    for (int q0 = 0; q0 < nf; q0 += 4) {
        int q = q0 + w;
        if (q < nf) {
            int c = idxl[q];
            float p = 0.f;
            #pragma unroll
            for (int ii = 0; ii < 12; ++ii) {
                int d = l + ii * 64;
                p += erow[d] * cpt[(size_t)d * 512 + c];
            }
            #pragma unroll
            for (int o = 32; o > 0; o >>= 1) p += __shfl_down(p, o);
            if (l == 0) {
                float cn = fmaxf(sqrtf(cn_sq[c]), 1e-12f);
                sval[c] = (p / (rn * cn) > 0.1f) ? p : 0.f;
            }
        }
    }
    __syncthreads();
    float s2 = sval[t] + sval[t + 256];
    #pragma unroll
    for (int o = 32; o > 0; o >>= 1) s2 += __shfl_down(s2, o);
    if (l == 0) redw[w] = s2;
    __syncthreads();
    const float denom = redw[0] + redw[1] + redw[2] + redw[3] + 0.001f;
    #pragma unroll
    for (int j = 0; j < 2; ++j) {
        int c = t + j * 256;
        float pr = sval[c] / denom;
        S[(size_t)b * 512 + c] = pr;
        probb[(size_t)b * 512 + c] = f2bf(pr);
    }
}

// cx GEMM (bf16, gload_lds, BK=64) + fused per-block top-10. grid (128, 8).
__global__ __launch_bounds__(256, 4) void k_cx_topk2(const ushort* __restrict__ cptb, // [512][768]
                                                     const ushort* __restrict__ XbT,  // [65536][768]
                                                     const float* __restrict__ cn_sq,
                                                     const float* __restrict__ en,
                                                     float2* __restrict__ cand) {
    __shared__ __align__(16) char smem[34048];
    char* Ab = smem;              // [64][128B]
    char* Bb = smem + 8192;       // [128][128B]
    float* Ct = (float*)smem;     // [64][133] aliased

    const int t = threadIdx.x;
    const int l = t & 63, w = t >> 6;
    const int wr = w >> 1, wc = w & 1;
    const int lg = l >> 4, lc = l & 15;
    const int c0 = blockIdx.y * 64;
    const int nbase = blockIdx.x * 512;
    const float FINF = __builtin_inff();

    const int sr8 = l >> 3, oct = l & 7;
    const int arw0 = 16 * w + sr8, arw1 = arw0 + 8;
    const ushort* ga0 = cptb + (size_t)(c0 + arw0) * 768 + (oct ^ (arw0 & 7)) * 8;
    const ushort* ga1 = cptb + (size_t)(c0 + arw1) * 768 + (oct ^ (arw1 & 7)) * 8;
    char* la0 = Ab + w * 2048;
    char* la1 = Ab + w * 2048 + 1024;
    const int brw0 = 32 * w + sr8, brw1 = brw0 + 8, brw2 = brw0 + 16, brw3 = brw0 + 24;
    const int bs0 = (oct ^ (brw0 & 7)) * 8, bs1 = (oct ^ (brw1 & 7)) * 8;
    const int bs2 = (oct ^ (brw2 & 7)) * 8, bs3 = (oct ^ (brw3 & 7)) * 8;
    char* lb0 = Bb + w * 4096;
    char* lb1 = Bb + w * 4096 + 1024;
    char* lb2 = Bb + w * 4096 + 2048;
    char* lb3 = Bb + w * 4096 + 3072;

    const int ar0 = wr * 32 + lc, ar1 = ar0 + 16;
    int aoff[2][2], boff[2][4];
    #pragma unroll
    for (int kk = 0; kk < 2; ++kk) {
        aoff[kk][0] = ar0 * 128 + (((kk * 4 + lg) ^ (ar0 & 7)) * 16);
        aoff[kk][1] = ar1 * 128 + (((kk * 4 + lg) ^ (ar1 & 7)) * 16);
        #pragma unroll
        for (int f = 0; f < 4; ++f) {
            int bc = wc * 64 + f * 16 + lc;
            boff[kk][f] = bc * 128 + (((kk * 4 + lg) ^ (bc & 7)) * 16);
        }
    }

    const int r = t >> 2, g = t & 3;
    float topd[10], topv[10];
    #pragma unroll
    for (int i = 0; i < 10; ++i) { topd[i] = FINF; topv[i] = 0.f; }
    const float cnr = cn_sq[c0 + r];

    #pragma unroll 1
    for (int s = 0; s < 4; ++s) {
        const int n0 = nbase + s * 128;
        const ushort* gb0 = XbT + (size_t)(n0 + brw0) * 768 + bs0;
        const ushort* gb1 = XbT + (size_t)(n0 + brw1) * 768 + bs1;
        const ushort* gb2 = XbT + (size_t)(n0 + brw2) * 768 + bs2;
        const ushort* gb3 = XbT + (size_t)(n0 + brw3) * 768 + bs3;
        f32x4 acc[2][4];
        #pragma unroll
        for (int m = 0; m < 2; ++m)
            #pragma unroll
            for (int f = 0; f < 4; ++f) acc[m][f] = (f32x4){0.f, 0.f, 0.f, 0.f};

        #pragma unroll 1
        for (int k0 = 0; k0 < 768; k0 += 64) {
            __syncthreads();
            gll16(ga0 + k0, la0); gll16(ga1 + k0, la1);
            gll16(gb0 + k0, lb0); gll16(gb1 + k0, lb1);
            gll16(gb2 + k0, lb2); gll16(gb3 + k0, lb3);
            __syncthreads();
            #pragma unroll
            for (int kk = 0; kk < 2; ++kk) {
                short8 a0 = *(const short8*)(Ab + aoff[kk][0]);
                short8 a1 = *(const short8*)(Ab + aoff[kk][1]);
                short8 bfr[4];
                #pragma unroll
                for (int f = 0; f < 4; ++f) bfr[f] = *(const short8*)(Bb + boff[kk][f]);
                #pragma unroll
                for (int f = 0; f < 4; ++f) {
                    acc[0][f] = __builtin_amdgcn_mfma_f32_16x16x32_bf16(a0, bfr[f], acc[0][f], 0, 0, 0);
                    acc[1][f] = __builtin_amdgcn_mfma_f32_16x16x32_bf16(a1, bfr[f], acc[1][f], 0, 0, 0);
                }
            }
        }
        __syncthreads();
        #pragma unroll
        for (int m = 0; m < 2; ++m)
            #pragma unroll
            for (int f = 0; f < 4; ++f)
                #pragma unroll
                for (int i = 0; i < 4; ++i)
                    Ct[(wr * 32 + m * 16 + lg * 4 + i) * 133 + wc * 64 + f * 16 + lc] = acc[m][f][i];
        __syncthreads();
        #pragma unroll 1
        for (int u = 0; u < 32; ++u) {
            int c = u * 4 + g;
            float val = Ct[r * 133 + c];
            float dist = cnr + en[n0 + c] - 2.f * val;
            if (dist < topd[9]) {
                topd[9] = dist; topv[9] = val;
                #pragma unroll
                for (int i = 9; i > 0; --i) {
                    if (topd[i] < topd[i - 1]) {
                        float td = topd[i]; topd[i] = topd[i - 1]; topd[i - 1] = td;
                        float tv = topv[i]; topv[i] = topv[i - 1]; topv[i - 1] = tv;
                    }
                }
            }
        }
        __syncthreads();
    }
    float* ML = (float*)smem;
    #pragma unroll
    for (int i = 0; i < 10; ++i) {
        ML[t * 20 + 2 * i] = topd[i];
        ML[t * 20 + 2 * i + 1] = topv[i];
    }
    __syncthreads();
    if (g == 0) {
        #pragma unroll 1
        for (int o = 1; o < 4; ++o) {
            const float* L = &ML[(t + o) * 20];
            #pragma unroll 1
            for (int i = 0; i < 10; ++i) {
                float nd = L[2 * i];
                if (nd >= topd[9]) break;
                float nv = L[2 * i + 1];
                topd[9] = nd; topv[9] = nv;
                #pragma unroll
                for (int x = 9; x > 0; --x) {
                    if (topd[x] < topd[x - 1]) {
                        float td = topd[x]; topd[x] = topd[x - 1]; topd[x - 1] = td;
                        float tv = topv[x]; topv[x] = topv[x - 1]; topv[x - 1] = tv;
                    }
                }
            }
        }
        float2* dst = &cand[((size_t)(c0 + r) * 128 + blockIdx.x) * 10];
        #pragma unroll
        for (int i = 0; i < 10; ++i) dst[i] = make_float2(topd[i], topv[i]);
    }
}

// ======================= FALLBACK PATH (round-3, proven) =======================
template <int RELU>
__global__ __launch_bounds__(256) void k_gemm(const float* __restrict__ A,
                                              const float* __restrict__ Bm,
                                              float* __restrict__ Cm,
                                              int M, int N, int K) {
    __shared__ float As[16][68];
    __shared__ float Bs[16][128];
    const int t = threadIdx.x;
    const int m0 = blockIdx.x * 64, n0 = blockIdx.y * 128;
    const int tm = t >> 4, tn = t & 15;
    float acc[4][8] = {};
    #pragma unroll 1
    for (int k0 = 0; k0 < K; k0 += 16) {
        {
            int i = t >> 2, kk4 = (t & 3) * 4;
            float4 av = *(const float4*)&A[(size_t)(m0 + i) * K + k0 + kk4];
            As[kk4 + 0][i] = av.x; As[kk4 + 1][i] = av.y;
            As[kk4 + 2][i] = av.z; As[kk4 + 3][i] = av.w;
        }
        {
            int kk = t >> 5, c4 = (t & 31) * 4;
            *(float4*)&Bs[kk][c4] = *(const float4*)&Bm[(size_t)(k0 + kk) * N + n0 + c4];
            *(float4*)&Bs[kk + 8][c4] = *(const float4*)&Bm[(size_t)(k0 + kk + 8) * N + n0 + c4];
        }
        __syncthreads();
        #pragma unroll
        for (int k = 0; k < 16; ++k) {
            float4 a4 = *(const float4*)&As[k][tm * 4];
            float4 b0 = *(const float4*)&Bs[k][tn * 4];
            float4 b1 = *(const float4*)&Bs[k][64 + tn * 4];
            float av[4] = {a4.x, a4.y, a4.z, a4.w};
            float bv[8] = {b0.x, b0.y, b0.z, b0.w, b1.x, b1.y, b1.z, b1.w};
            #pragma unroll
            for (int i = 0; i < 4; ++i)
                #pragma unroll
                for (int j = 0; j < 8; ++j) acc[i][j] += av[i] * bv[j];
        }
        __syncthreads();
    }
    #pragma unroll
    for (int i = 0; i < 4; ++i) {
        int row = m0 + tm * 4 + i;
        float4 o0 = make_float4(acc[i][0], acc[i][1], acc[i][2], acc[i][3]);
        float4 o1 = make_float4(acc[i][4], acc[i][5], acc[i][6], acc[i][7]);
        if (RELU) {
            o0.x = fmaxf(o0.x, 0.f); o0.y = fmaxf(o0.y, 0.f);
            o0.z = fmaxf(o0.z, 0.f); o0.w = fmaxf(o0.w, 0.f);
            o1.x = fmaxf(o1.x, 0.f); o1.y = fmaxf(o1.y, 0.f);
            o1.z = fmaxf(o1.z, 0.f); o1.w = fmaxf(o1.w, 0.f);
        }
        *(float4*)&Cm[(size_t)row * N + n0 + tn * 4] = o0;
        *(float4*)&Cm[(size_t)row * N + n0 + 64 + tn * 4] = o1;
    }
}

template <int RELU>
__global__ __launch_bounds__(256) void k_gemm_bf(const float* __restrict__ A,
                                                 const float* __restrict__ Bm,
                                                 float* __restrict__ Cm,
                                                 int M, int N, int K) {
    __shared__ __align__(16) char smem[15360];
    char* Ab = smem;
    char* Bb = smem + 5120;
    const int t = threadIdx.x;
    const int l = t & 63, w = t >> 6;
    const int wr = w >> 1, wc = w & 1;
    const int lg = l >> 4, lc = l & 15;
    const int m0 = blockIdx.x * 64, n0 = blockIdx.y * 128;
    const int ar = t >> 2, ak = (t & 3) * 8;
    const int bc = t & 63, bw = t >> 6;
    f32x4 acc[2][4];
    #pragma unroll
    for (int m = 0; m < 2; ++m)
        #pragma unroll
        for (int f = 0; f < 4; ++f) acc[m][f] = (f32x4){0.f, 0.f, 0.f, 0.f};
    #pragma unroll 1
    for (int k0 = 0; k0 < K; k0 += 32) {
        __syncthreads();
        {
            const float* p = &A[(size_t)(m0 + ar) * K + k0 + ak];
            float4 a0 = *(const float4*)p;
            float4 a1 = *(const float4*)(p + 4);
            uint4 da = make_uint4(pack2(a0.x, a0.y), pack2(a0.z, a0.w),
                                  pack2(a1.x, a1.y), pack2(a1.z, a1.w));
            *(uint4*)(Ab + ar * 80 + (t & 3) * 16) = da;
        }
        #pragma unroll
        for (int j = 0; j < 2; ++j) {
            float x[8];
            #pragma unroll
            for (int i = 0; i < 8; ++i)
                x[i] = Bm[(size_t)(k0 + 8 * bw + i) * N + n0 + bc + 64 * j];
            uint4 db = make_uint4(pack2(x[0], x[1]), pack2(x[2], x[3]),
                                  pack2(x[4], x[5]), pack2(x[6], x[7]));
            *(uint4*)(Bb + (bc + 64 * j) * 80 + bw * 16) = db;
        }
        __syncthreads();
        short8 af0 = *(const short8*)(Ab + (wr * 32 + lc) * 80 + lg * 16);
        short8 af1 = *(const short8*)(Ab + (wr * 32 + 16 + lc) * 80 + lg * 16);
        short8 bfr[4];
        #pragma unroll
        for (int f = 0; f < 4; ++f)
            bfr[f] = *(const short8*)(Bb + (wc * 64 + f * 16 + lc) * 80 + lg * 16);
        #pragma unroll
        for (int f = 0; f < 4; ++f) {
            acc[0][f] = __builtin_amdgcn_mfma_f32_16x16x32_bf16(af0, bfr[f], acc[0][f], 0, 0, 0);
            acc[1][f] = __builtin_amdgcn_mfma_f32_16x16x32_bf16(af1, bfr[f], acc[1][f], 0, 0, 0);
        }
    }
    #pragma unroll
    for (int m = 0; m < 2; ++m)
        #pragma unroll
        for (int f = 0; f < 4; ++f)
            #pragma unroll
            for (int i = 0; i < 4; ++i) {
                int row = m0 + wr * 32 + m * 16 + lg * 4 + i;
                int col = n0 + wc * 64 + f * 16 + lc;
                float v = acc[m][f][i];
                if (RELU) v = fmaxf(v, 0.f);
                Cm[(size_t)row * N + col] = v;
            }
}

__global__ __launch_bounds__(256) void k_prob(const float* __restrict__ emb,
                                              const float* __restrict__ cn_sq,
                                              float* __restrict__ S) {
    __shared__ float red[256];
    int b = blockIdx.x, t = threadIdx.x;
    float s = 0.f;
    #pragma unroll
    for (int j = 0; j < 3; ++j) { float v = emb[(size_t)b * 768 + t + j * 256]; s += v * v; }
    red[t] = s; __syncthreads();
    for (int st = 128; st > 0; st >>= 1) { if (t < st) red[t] += red[t + st]; __syncthreads(); }
    float rn = fmaxf(sqrtf(red[0]), 1e-12f);
    __syncthreads();
    float vals[2]; float sum = 0.f;
    #pragma unroll
    for (int j = 0; j < 2; ++j) {
        int cc = t + j * 256;
        float sc = S[(size_t)b * 512 + cc];
        float cn = fmaxf(sqrtf(cn_sq[cc]), 1e-12f);
        float v = (sc / (rn * cn) > 0.1f) ? sc : 0.f;
        vals[j] = v; sum += v;
    }
    red[t] = sum; __syncthreads();
    for (int st = 128; st > 0; st >>= 1) { if (t < st) red[t] += red[t + st]; __syncthreads(); }
    float denom = red[0] + 0.001f;
    #pragma unroll
    for (int j = 0; j < 2; ++j) S[(size_t)b * 512 + (t + j * 256)] = vals[j] / denom;
}

__global__ void k_en(const float* __restrict__ X, float* __restrict__ en) {
    int n4 = blockIdx.x * 256 + threadIdx.x;
    float4 s = make_float4(0.f, 0.f, 0.f, 0.f);
    #pragma unroll 4
    for (int d = 0; d < 768; ++d) {
        float4 v = *(const float4*)&X[(size_t)d * 65536 + n4 * 4];
        s.x += v.x * v.x; s.y += v.y * v.y; s.z += v.z * v.z; s.w += v.w * v.w;
    }
    *(float4*)&en[n4 * 4] = s;
}

__global__ __launch_bounds__(256, 4) void k_cx_topk(const float* __restrict__ cpt,
                                                    const float* __restrict__ X,
                                                    const float* __restrict__ cn_sq,
                                                    const float* __restrict__ en,
                                                    float2* __restrict__ cand) {
    __shared__ __align__(16) char smem_c[34048];
    float* Ct = (float*)smem_c;
    char* Ab = smem_c;
    char* Bb = smem_c + 5120;
    const int t = threadIdx.x;
    const int l = t & 63, w = t >> 6;
    const int wr = w >> 1, wc = w & 1;
    const int lg = l >> 4, lc = l & 15;
    const int c0 = blockIdx.y * 64;
    const int nbase = blockIdx.x * 512;
    const float FINF = __builtin_inff();
    const int sc_ = t & 63, sw = t >> 6;
    const int r = t >> 2, g = t & 3;
    float topd[10], topv[10];
    #pragma unroll
    for (int i = 0; i < 10; ++i) { topd[i] = FINF; topv[i] = 0.f; }
    const float cnr = cn_sq[c0 + r];
    #pragma unroll 1
    for (int s = 0; s < 4; ++s) {
        const int n0 = nbase + s * 128;
        f32x4 acc[2][4];
        #pragma unroll
        for (int m = 0; m < 2; ++m)
            #pragma unroll
            for (int f = 0; f < 4; ++f) acc[m][f] = (f32x4){0.f, 0.f, 0.f, 0.f};
        #pragma unroll 1
        for (int k0 = 0; k0 < 768; k0 += 32) {
            __syncthreads();
            {
                float x[8];
                #pragma unroll
                for (int i = 0; i < 8; ++i)
                    x[i] = cpt[(size_t)(k0 + 8 * sw + i) * 512 + c0 + sc_];
                uint4 da = make_uint4(pack2(x[0], x[1]), pack2(x[2], x[3]),
                                      pack2(x[4], x[5]), pack2(x[6], x[7]));
                *(uint4*)(Ab + sc_ * 80 + sw * 16) = da;
            }
            #pragma unroll
            for (int j = 0; j < 2; ++j) {
                float x[8];
                #pragma unroll
                for (int i = 0; i < 8; ++i)
                    x[i] = X[(size_t)(k0 + 8 * sw + i) * 65536 + n0 + sc_ + 64 * j];
                uint4 db = make_uint4(pack2(x[0], x[1]), pack2(x[2], x[3]),
                                      pack2(x[4], x[5]), pack2(x[6], x[7]));
                *(uint4*)(Bb + (sc_ + 64 * j) * 80 + sw * 16) = db;
            }
            __syncthreads();
            short8 af0 = *(const short8*)(Ab + (wr * 32 + lc) * 80 + lg * 16);
            short8 af1 = *(const short8*)(Ab + (wr * 32 + 16 + lc) * 80 + lg * 16);
            short8 bfr[4];
            #pragma unroll
            for (int f = 0; f < 4; ++f)
                bfr[f] = *(const short8*)(Bb + (wc * 64 + f * 16 + lc) * 80 + lg * 16);
            #pragma unroll
            for (int f = 0; f < 4; ++f) {
                acc[0][f] = __builtin_amdgcn_mfma_f32_16x16x32_bf16(af0, bfr[f], acc[0][f], 0, 0, 0);
                acc[1][f] = __builtin_amdgcn_mfma_f32_16x16x32_bf16(af1, bfr[f], acc[1][f], 0, 0, 0);
            }
        }
        __syncthreads();
        #pragma unroll
        for (int m = 0; m < 2; ++m)
            #pragma unroll
            for (int f = 0; f < 4; ++f)
                #pragma unroll
                for (int i = 0; i < 4; ++i)
                    Ct[(wr * 32 + m * 16 + lg * 4 + i) * 133 + wc * 64 + f * 16 + lc] = acc[m][f][i];
        __syncthreads();
        #pragma unroll 1
        for (int u = 0; u < 32; ++u) {
            int c = u * 4 + g;
            float val = Ct[r * 133 + c];
            float dist = cnr + en[n0 + c] - 2.f * val;
            if (dist < topd[9]) {
                topd[9] = dist; topv[9] = val;
                #pragma unroll
                for (int i = 9; i > 0; --i) {
                    if (topd[i] < topd[i - 1]) {
                        float td = topd[i]; topd[i] = topd[i - 1]; topd[i - 1] = td;
                        float tv = topv[i]; topv[i] = topv[i - 1]; topv[i - 1] = tv;
                    }
                }
            }
        }
        __syncthreads();
    }
    float* ML = (float*)smem_c;
    #pragma unroll
    for (int i = 0; i < 10; ++i) {
        ML[t * 20 + 2 * i] = topd[i];
        ML[t * 20 + 2 * i + 1] = topv[i];
    }
    __syncthreads();
    if (g == 0) {
        #pragma unroll 1
        for (int o = 1; o < 4; ++o) {
            const float* L = &ML[(t + o) * 20];
            #pragma unroll 1
            for (int i = 0; i < 10; ++i) {
                float nd = L[2 * i];
                if (nd >= topd[9]) break;
                float nv = L[2 * i + 1];
                topd[9] = nd; topv[9] = nv;
                #pragma unroll
                for (int x = 9; x > 0; --x) {
                    if (topd[x] < topd[x - 1]) {
                        float td = topd[x]; topd[x] = topd[x - 1]; topd[x - 1] = td;
                        float tv = topv[x]; topv[x] = topv[x - 1]; topv[x - 1] = tv;
                    }
                }
            }
        }
        float2* dst = &cand[((size_t)(c0 + r) * 128 + blockIdx.x) * 10];
        #pragma unroll
        for (int i = 0; i < 10; ++i) dst[i] = make_float2(topd[i], topv[i]);
    }
}

// ======================= launcher =======================
extern "C" void kernel_launch(void* const* d_in, const int* in_sizes, int n_in,
                              void* d_out, int out_size, void* d_ws, size_t ws_size,
                              hipStream_t stream) {
    const float* emb = (const float*)d_in[0];   // [8192 x 768]
    const float* X   = (const float*)d_in[1];   // [768 x 65536]
    const float* cpt = (const float*)d_in[2];   // [768 x 512]
    const float* r1  = (const float*)d_in[3];   // [512 x 256]
    const float* r2  = (const float*)d_in[4];   // [256 x 768]
    float* out = (float*)d_out;
    float* ws = (float*)d_ws;
    float* S = out + 6291456;                   // prob region doubles as score scratch

    const size_t OFF_CN = 0, OFF_EN = 512, OFF_ACC = 66048, OFF_XBT = 66560;
    const size_t OFF_EMBB = 25232384, OFF_CPTB = 28378112, OFF_R1T = 28574720;
    const size_t OFF_R2T = 28640256, OFF_PRBB = 28738560, OFF_RL1B = 30835712;
    const size_t OFF_CAND = 31884288, WS_NEED = 33195008ull * 4ull;

    if (ws_size >= WS_NEED) {
        float* cn_sq = ws + OFF_CN;
        float* en    = ws + OFF_EN;
        float* acc   = ws + OFF_ACC;
        ushort* XbT  = (ushort*)(ws + OFF_XBT);
        ushort* embb = (ushort*)(ws + OFF_EMBB);
        ushort* cptb = (ushort*)(ws + OFF_CPTB);
        ushort* r1T  = (ushort*)(ws + OFF_R1T);
        ushort* r2T  = (ushort*)(ws + OFF_R2T);
        ushort* prbb = (ushort*)(ws + OFF_PRBB);
        ushort* rl1b = (ushort*)(ws + OFF_RL1B);
        float2* cand = (float2*)(ws + OFF_CAND);

        k_zero<<<259, 256, 0, stream>>>(ws, 66056);
        k_col_sumsq<<<dim3(2, 8), 256, 0, stream>>>(cpt, cn_sq);
        k_row_stats<<<48, 256, 0, stream>>>(cpt, acc);
        k_tc<1><<<dim3(256, 24), 256, 0, stream>>>(X, XbT, en, 65536, 768);
        k_tc<0><<<dim3(2, 24), 256, 0, stream>>>(cpt, cptb, nullptr, 512, 768);
        k_tc<0><<<dim3(1, 16), 256, 0, stream>>>(r1, r1T, nullptr, 256, 512);
        k_tc<0><<<dim3(3, 8), 256, 0, stream>>>(r2, r2T, nullptr, 768, 256);
        k_cvt_emb<<<3072, 256, 0, stream>>>(emb, embb);
        gemm_bt<1, 0, 0><<<dim3(128, 4), 256, 0, stream>>>(embb, cptb, S, nullptr, 8192, 512, 768);
        k_prob2<<<8192, 256, 0, stream>>>(emb, cpt, cn_sq, S, prbb);
        gemm_bt<0, 1, 1><<<dim3(128, 2), 256, 0, stream>>>(prbb, r1T, nullptr, rl1b, 8192, 256, 512);
        gemm_bt<1, 0, 0><<<dim3(128, 6), 256, 0, stream>>>(rl1b, r2T, out, nullptr, 8192, 768, 256);
        k_cx_topk2<<<dim3(128, 8), 256, 0, stream>>>(cptb, XbT, cn_sq, en, cand);
        k_knn_merge<1280><<<512, 256, 0, stream>>>(cand, acc);
        k_finalize<<<1, 64, 0, stream>>>(acc, out);
    } else {
        float* cn_sq = ws;
        float* en    = ws + 512;
        float* acc   = ws + 66048;
        float* rl1   = ws + 66560;
        float2* cand = (float2*)(ws + 66560 + 8192 * 256);
        k_init<<<1, 256, 0, stream>>>(cn_sq, acc);
        k_col_sumsq<<<dim3(2, 8), 256, 0, stream>>>(cpt, cn_sq);
        k_row_stats<<<48, 256, 0, stream>>>(cpt, acc);
        k_gemm<0><<<dim3(128, 4), 256, 0, stream>>>(emb, cpt, S, 8192, 512, 768);
        k_prob<<<8192, 256, 0, stream>>>(emb, cn_sq, S);
        k_gemm_bf<1><<<dim3(128, 2), 256, 0, stream>>>(S, r1, rl1, 8192, 256, 512);
        k_gemm_bf<0><<<dim3(128, 6), 256, 0, stream>>>(rl1, r2, out, 8192, 768, 256);
        k_en<<<64, 256, 0, stream>>>(X, en);
        k_cx_topk<<<dim3(128, 8), 256, 0, stream>>>(cpt, X, cn_sq, en, cand);
        k_knn_merge<1280><<<512, 256, 0, stream>>>(cand, acc);
        k_finalize<<<1, 64, 0, stream>>>(acc, out);
    }
}

// Round 12
// 358.960 us; speedup vs baseline: 1.3700x; 1.0325x over previous
//
#include <hip/hip_runtime.h>

// Problem constants: B=8192, D=768, C=512, H=256, N=65536, k=10.
// Outputs (flat): rec_layer_2 [8192*768], prob [8192*512], L1, L2.

typedef __attribute__((ext_vector_type(8))) short short8;
typedef __attribute__((ext_vector_type(4))) float f32x4;
typedef unsigned int u32;

__device__ __forceinline__ ushort f2bf(float f) {
    unsigned u = __builtin_bit_cast(unsigned, f);
    u += 0x7FFFu + ((u >> 16) & 1u);          // round-to-nearest-even
    return (ushort)(u >> 16);
}
__device__ __forceinline__ unsigned pack2(float lo, float hi) {
    return (unsigned)f2bf(lo) | ((unsigned)f2bf(hi) << 16);
}
// async global->LDS, 16B per lane; lds dest = wave-uniform base + lane*16
__device__ __forceinline__ void gll16(const void* g, void* l) {
    __builtin_amdgcn_global_load_lds((const __attribute__((address_space(1))) u32*)g,
                                     (__attribute__((address_space(3))) u32*)l, 16, 0, 0);
}

// ======================= shared small kernels =======================
__global__ void k_zero(float* p, int n) {
    int i = blockIdx.x * 256 + threadIdx.x;
    if (i < n) p[i] = 0.f;
}
__global__ void k_init(float* cn_sq, float* acc) {
    int t = threadIdx.x;
    cn_sq[t] = 0.f; cn_sq[t + 256] = 0.f;
    if (t < 8) acc[t] = 0.f;
}
__global__ void k_col_sumsq(const float* __restrict__ cpt, float* __restrict__ cn_sq) {
    int c = blockIdx.x * 256 + threadIdx.x;
    int d0 = blockIdx.y * 96;
    float s = 0.f;
    #pragma unroll 4
    for (int d = d0; d < d0 + 96; ++d) { float v = cpt[d * 512 + c]; s += v * v; }
    atomicAdd(&cn_sq[c], s);
}
__global__ void k_row_stats(const float* __restrict__ cpt, float* __restrict__ acc) {
    __shared__ float red[256];
    int t = threadIdx.x;
    int d = blockIdx.x * 16;
    float rowsq = 0.f, tot = 0.f;
    for (int r = 0; r < 16; ++r, ++d) {
        float v1 = cpt[d * 512 + t], v2 = cpt[d * 512 + 256 + t];
        tot += v1 * v1 + v2 * v2;
        red[t] = v1 + v2;
        __syncthreads();
        for (int st = 128; st > 0; st >>= 1) {
            if (t < st) red[t] += red[t + st];
            __syncthreads();
        }
        if (t == 0) rowsq += red[0] * red[0];
        __syncthreads();
    }
    red[t] = tot; __syncthreads();
    for (int st = 128; st > 0; st >>= 1) {
        if (t < st) red[t] += red[t + st];
        __syncthreads();
    }
    if (t == 0) { atomicAdd(&acc[1], rowsq); atomicAdd(&acc[2], red[0]); }
}

template <int NB>
__global__ __launch_bounds__(256) void k_knn_merge(const float2* __restrict__ cand,
                                                   float* __restrict__ acc) {
    __shared__ float2 buf[NB];
    __shared__ float2 l2[160];
    int c = blockIdx.x, t = threadIdx.x;
    const float FINF = __builtin_inff();
    const float2* src = &cand[(size_t)c * NB];
    for (int i = t; i < NB; i += 256) buf[i] = src[i];
    __syncthreads();
    if (t < 16) {
        float td[10], tv[10];
        #pragma unroll
        for (int i = 0; i < 10; ++i) { td[i] = FINF; tv[i] = 0.f; }
        const int per = NB / 16;
        for (int j = t * per; j < t * per + per; ++j) {
            float nd = buf[j].x;
            if (nd < td[9]) {
                td[9] = nd; tv[9] = buf[j].y;
                #pragma unroll
                for (int x = 9; x > 0; --x)
                    if (td[x] < td[x - 1]) {
                        float a = td[x]; td[x] = td[x - 1]; td[x - 1] = a;
                        float b = tv[x]; tv[x] = tv[x - 1]; tv[x - 1] = b;
                    }
            }
        }
        #pragma unroll
        for (int i = 0; i < 10; ++i) l2[t * 10 + i] = make_float2(td[i], tv[i]);
    }
    __syncthreads();
    if (t == 0) {
        float td[10], tv[10];
        #pragma unroll
        for (int i = 0; i < 10; ++i) { td[i] = FINF; tv[i] = 0.f; }
        for (int j = 0; j < 160; ++j) {
            float nd = l2[j].x;
            if (nd < td[9]) {
                td[9] = nd; tv[9] = l2[j].y;
                #pragma unroll
                for (int x = 9; x > 0; --x)
                    if (td[x] < td[x - 1]) {
                        float a = td[x]; td[x] = td[x - 1]; td[x - 1] = a;
                        float b = tv[x]; tv[x] = tv[x - 1]; tv[x - 1] = b;
                    }
            }
        }
        float s = 0.f;
        #pragma unroll
        for (int i = 0; i < 10; ++i) s += tv[i];
        atomicAdd(&acc[0], s);
    }
}
__global__ void k_finalize(const float* __restrict__ acc, float* __restrict__ out) {
    if (threadIdx.x == 0) {
        out[10485760] = acc[0] / 5120.0f;
        out[10485761] = (acc[1] - acc[2]) / 262144.0f;
    }
}

// ======================= FAST PATH =======================
template <int EN>
__global__ __launch_bounds__(256) void k_tc(const float* __restrict__ src,
                                            ushort* __restrict__ dst,
                                            float* __restrict__ en,
                                            int Ncols, int D) {
    __shared__ float tile[32][256];
    const int t = threadIdx.x;
    const int n0 = blockIdx.x * 256;
    const int d0 = blockIdx.y * 32;
    float s = 0.f;
    #pragma unroll 8
    for (int dd = 0; dd < 32; ++dd) {
        float v = src[(size_t)(d0 + dd) * Ncols + n0 + t];
        tile[dd][t] = v;
        if (EN) s += v * v;
    }
    if (EN) atomicAdd(&en[n0 + t], s);
    __syncthreads();
    ushort* drow = dst + (size_t)(n0 + t) * D + d0;
    #pragma unroll
    for (int q = 0; q < 4; ++q) {
        uint4 d4;
        d4.x = pack2(tile[q * 8 + 0][t], tile[q * 8 + 1][t]);
        d4.y = pack2(tile[q * 8 + 2][t], tile[q * 8 + 3][t]);
        d4.z = pack2(tile[q * 8 + 4][t], tile[q * 8 + 5][t]);
        d4.w = pack2(tile[q * 8 + 6][t], tile[q * 8 + 7][t]);
        *(uint4*)(drow + q * 8) = d4;
    }
}

__global__ void k_cvt_emb(const float* __restrict__ src, ushort* __restrict__ dst) {
    int i = (blockIdx.x * 256 + threadIdx.x) * 8;
    float4 a = *(const float4*)&src[i], b = *(const float4*)&src[i + 4];
    uint4 d4 = make_uint4(pack2(a.x, a.y), pack2(a.z, a.w), pack2(b.x, b.y), pack2(b.z, b.w));
    *(uint4*)&dst[i] = d4;
}

// C = A[MxK] @ B[NxK]^T, bf16 in, gload_lds staging, tile 64x128, BK=64.
// LDS rows 128B, slot swizzle oct^=(row&7); stage: 8 lanes/row, 1KB/call.
template <int WF32, int WB16, int RELU>
__global__ __launch_bounds__(256, 4) void gemm_bt(const ushort* __restrict__ A,
                                                  const ushort* __restrict__ B,
                                                  float* __restrict__ C,
                                                  ushort* __restrict__ Cb,
                                                  int M, int N, int K) {
    __shared__ __align__(16) char smem[24576];
    char* Ab = smem;              // [64 rows][128 B]
    char* Bb = smem + 8192;       // [128 rows][128 B]
    const int t = threadIdx.x;
    const int l = t & 63, w = t >> 6;
    const int wr = w >> 1, wc = w & 1;
    const int lg = l >> 4, lc = l & 15;
    const int m0 = blockIdx.x * 64, n0 = blockIdx.y * 128;
    const int sr8 = l >> 3, oct = l & 7;
    const int arw0 = 16 * w + sr8, arw1 = arw0 + 8;
    const ushort* ga0 = A + (size_t)(m0 + arw0) * K + (oct ^ (arw0 & 7)) * 8;
    const ushort* ga1 = A + (size_t)(m0 + arw1) * K + (oct ^ (arw1 & 7)) * 8;
    char* la0 = Ab + w * 2048;
    char* la1 = Ab + w * 2048 + 1024;
    const int brw0 = 32 * w + sr8, brw1 = brw0 + 8, brw2 = brw0 + 16, brw3 = brw0 + 24;
    const ushort* gb0 = B + (size_t)(n0 + brw0) * K + (oct ^ (brw0 & 7)) * 8;
    const ushort* gb1 = B + (size_t)(n0 + brw1) * K + (oct ^ (brw1 & 7)) * 8;
    const ushort* gb2 = B + (size_t)(n0 + brw2) * K + (oct ^ (brw2 & 7)) * 8;
    const ushort* gb3 = B + (size_t)(n0 + brw3) * K + (oct ^ (brw3 & 7)) * 8;
    char* lb0 = Bb + w * 4096;
    char* lb1 = Bb + w * 4096 + 1024;
    char* lb2 = Bb + w * 4096 + 2048;
    char* lb3 = Bb + w * 4096 + 3072;
    const int ar0 = wr * 32 + lc, ar1 = ar0 + 16;
    int aoff[2][2], boff[2][4];
    #pragma unroll
    for (int kk = 0; kk < 2; ++kk) {
        aoff[kk][0] = ar0 * 128 + (((kk * 4 + lg) ^ (ar0 & 7)) * 16);
        aoff[kk][1] = ar1 * 128 + (((kk * 4 + lg) ^ (ar1 & 7)) * 16);
        #pragma unroll
        for (int f = 0; f < 4; ++f) {
            int bc = wc * 64 + f * 16 + lc;
            boff[kk][f] = bc * 128 + (((kk * 4 + lg) ^ (bc & 7)) * 16);
        }
    }
    f32x4 acc[2][4];
    #pragma unroll
    for (int m = 0; m < 2; ++m)
        #pragma unroll
        for (int f = 0; f < 4; ++f) acc[m][f] = (f32x4){0.f, 0.f, 0.f, 0.f};

    #pragma unroll 1
    for (int k0 = 0; k0 < K; k0 += 64) {
        __syncthreads();
        gll16(ga0 + k0, la0); gll16(ga1 + k0, la1);
        gll16(gb0 + k0, lb0); gll16(gb1 + k0, lb1);
        gll16(gb2 + k0, lb2); gll16(gb3 + k0, lb3);
        __syncthreads();
        #pragma unroll
        for (int kk = 0; kk < 2; ++kk) {
            short8 a0 = *(const short8*)(Ab + aoff[kk][0]);
            short8 a1 = *(const short8*)(Ab + aoff[kk][1]);
            short8 bfr[4];
            #pragma unroll
            for (int f = 0; f < 4; ++f) bfr[f] = *(const short8*)(Bb + boff[kk][f]);
            #pragma unroll
            for (int f = 0; f < 4; ++f) {
                acc[0][f] = __builtin_amdgcn_mfma_f32_16x16x32_bf16(a0, bfr[f], acc[0][f], 0, 0, 0);
                acc[1][f] = __builtin_amdgcn_mfma_f32_16x16x32_bf16(a1, bfr[f], acc[1][f], 0, 0, 0);
            }
        }
    }
    #pragma unroll
    for (int m = 0; m < 2; ++m)
        #pragma unroll
        for (int f = 0; f < 4; ++f)
            #pragma unroll
            for (int i = 0; i < 4; ++i) {
                int row = m0 + wr * 32 + m * 16 + lg * 4 + i;
                int col = n0 + wc * 64 + f * 16 + lc;
                float v = acc[m][f][i];
                if (RELU) v = fmaxf(v, 0.f);
                if (WF32) C[(size_t)row * N + col] = v;
                if (WB16) Cb[(size_t)row * N + col] = f2bf(v);
            }
}

// prob epilogue with exact fp32 fixup for flagged (near/above threshold) entries
__global__ __launch_bounds__(256) void k_prob2(const float* __restrict__ emb,
                                               const float* __restrict__ cpt,
                                               const float* __restrict__ cn_sq,
                                               float* __restrict__ S,
                                               ushort* __restrict__ probb) {
    __shared__ float erow[768];
    __shared__ float sval[512];
    __shared__ int idxl[512];
    __shared__ int cnt;
    __shared__ float redw[4];
    const int b = blockIdx.x, t = threadIdx.x;
    const int l = t & 63, w = t >> 6;
    if (t == 0) cnt = 0;
    float s = 0.f;
    #pragma unroll
    for (int j = 0; j < 3; ++j) {
        float v = emb[(size_t)b * 768 + t + j * 256];
        erow[t + j * 256] = v; s += v * v;
    }
    #pragma unroll
    for (int o = 32; o > 0; o >>= 1) s += __shfl_down(s, o);
    if (l == 0) redw[w] = s;
    __syncthreads();
    const float rn = fmaxf(sqrtf(redw[0] + redw[1] + redw[2] + redw[3]), 1e-12f);
    #pragma unroll
    for (int j = 0; j < 2; ++j) {
        int c = t + j * 256;
        sval[c] = 0.f;
        float cn = fmaxf(sqrtf(cn_sq[c]), 1e-12f);
        float sn = S[(size_t)b * 512 + c] / (rn * cn);
        if (sn > 0.1f - 4e-3f) { int p = atomicAdd(&cnt, 1); idxl[p] = c; }
    }
    __syncthreads();
    const int nf = cnt;
    for (int q0 = 0; q0 < nf; q0 += 4) {
        int q = q0 + w;
        if (q < nf) {
            int c = idxl[q];
            float p = 0.f;
            #pragma unroll
            for (int ii = 0; ii < 12; ++ii) {
                int d = l + ii * 64;
                p += erow[d] * cpt[(size_t)d * 512 + c];
            }
            #pragma unroll
            for (int o = 32; o > 0; o >>= 1) p += __shfl_down(p, o);
            if (l == 0) {
                float cn = fmaxf(sqrtf(cn_sq[c]), 1e-12f);
                sval[c] = (p / (rn * cn) > 0.1f) ? p : 0.f;
            }
        }
    }
    __syncthreads();
    float s2 = sval[t] + sval[t + 256];
    #pragma unroll
    for (int o = 32; o > 0; o >>= 1) s2 += __shfl_down(s2, o);
    if (l == 0) redw[w] = s2;
    __syncthreads();
    const float denom = redw[0] + redw[1] + redw[2] + redw[3] + 0.001f;
    #pragma unroll
    for (int j = 0; j < 2; ++j) {
        int c = t + j * 256;
        float pr = sval[c] / denom;
        S[(size_t)b * 512 + c] = pr;
        probb[(size_t)b * 512 + c] = f2bf(pr);
    }
}

// cx GEMM (bf16, gload_lds, BK=64) + fused per-block top-10. grid (128, 8).
// R12: Ct stride 132 (16B-aligned cols) + float4-vectorized scan.
__global__ __launch_bounds__(256, 4) void k_cx_topk2(const ushort* __restrict__ cptb, // [512][768]
                                                     const ushort* __restrict__ XbT,  // [65536][768]
                                                     const float* __restrict__ cn_sq,
                                                     const float* __restrict__ en,
                                                     float2* __restrict__ cand) {
    __shared__ __align__(16) char smem[34048];
    char* Ab = smem;              // [64][128B]
    char* Bb = smem + 8192;       // [128][128B]
    float* Ct = (float*)smem;     // [64][132] f32 (33792 B) aliased

    const int t = threadIdx.x;
    const int l = t & 63, w = t >> 6;
    const int wr = w >> 1, wc = w & 1;
    const int lg = l >> 4, lc = l & 15;
    const int c0 = blockIdx.y * 64;
    const int nbase = blockIdx.x * 512;
    const float FINF = __builtin_inff();

    const int sr8 = l >> 3, oct = l & 7;
    const int arw0 = 16 * w + sr8, arw1 = arw0 + 8;
    const ushort* ga0 = cptb + (size_t)(c0 + arw0) * 768 + (oct ^ (arw0 & 7)) * 8;
    const ushort* ga1 = cptb + (size_t)(c0 + arw1) * 768 + (oct ^ (arw1 & 7)) * 8;
    char* la0 = Ab + w * 2048;
    char* la1 = Ab + w * 2048 + 1024;
    const int brw0 = 32 * w + sr8, brw1 = brw0 + 8, brw2 = brw0 + 16, brw3 = brw0 + 24;
    const int bs0 = (oct ^ (brw0 & 7)) * 8, bs1 = (oct ^ (brw1 & 7)) * 8;
    const int bs2 = (oct ^ (brw2 & 7)) * 8, bs3 = (oct ^ (brw3 & 7)) * 8;
    char* lb0 = Bb + w * 4096;
    char* lb1 = Bb + w * 4096 + 1024;
    char* lb2 = Bb + w * 4096 + 2048;
    char* lb3 = Bb + w * 4096 + 3072;

    const int ar0 = wr * 32 + lc, ar1 = ar0 + 16;
    int aoff[2][2], boff[2][4];
    #pragma unroll
    for (int kk = 0; kk < 2; ++kk) {
        aoff[kk][0] = ar0 * 128 + (((kk * 4 + lg) ^ (ar0 & 7)) * 16);
        aoff[kk][1] = ar1 * 128 + (((kk * 4 + lg) ^ (ar1 & 7)) * 16);
        #pragma unroll
        for (int f = 0; f < 4; ++f) {
            int bc = wc * 64 + f * 16 + lc;
            boff[kk][f] = bc * 128 + (((kk * 4 + lg) ^ (bc & 7)) * 16);
        }
    }

    const int r = t >> 2, g = t & 3;
    float topd[10], topv[10];
    #pragma unroll
    for (int i = 0; i < 10; ++i) { topd[i] = FINF; topv[i] = 0.f; }
    const float cnr = cn_sq[c0 + r];

    auto ins = [&](float d, float v) {
        if (d < topd[9]) {
            topd[9] = d; topv[9] = v;
            #pragma unroll
            for (int x = 9; x > 0; --x) {
                if (topd[x] < topd[x - 1]) {
                    float td = topd[x]; topd[x] = topd[x - 1]; topd[x - 1] = td;
                    float tv = topv[x]; topv[x] = topv[x - 1]; topv[x - 1] = tv;
                }
            }
        }
    };

    #pragma unroll 1
    for (int s = 0; s < 4; ++s) {
        const int n0 = nbase + s * 128;
        const ushort* gb0 = XbT + (size_t)(n0 + brw0) * 768 + bs0;
        const ushort* gb1 = XbT + (size_t)(n0 + brw1) * 768 + bs1;
        const ushort* gb2 = XbT + (size_t)(n0 + brw2) * 768 + bs2;
        const ushort* gb3 = XbT + (size_t)(n0 + brw3) * 768 + bs3;
        f32x4 acc[2][4];
        #pragma unroll
        for (int m = 0; m < 2; ++m)
            #pragma unroll
            for (int f = 0; f < 4; ++f) acc[m][f] = (f32x4){0.f, 0.f, 0.f, 0.f};

        #pragma unroll 1
        for (int k0 = 0; k0 < 768; k0 += 64) {
            __syncthreads();
            gll16(ga0 + k0, la0); gll16(ga1 + k0, la1);
            gll16(gb0 + k0, lb0); gll16(gb1 + k0, lb1);
            gll16(gb2 + k0, lb2); gll16(gb3 + k0, lb3);
            __syncthreads();
            #pragma unroll
            for (int kk = 0; kk < 2; ++kk) {
                short8 a0 = *(const short8*)(Ab + aoff[kk][0]);
                short8 a1 = *(const short8*)(Ab + aoff[kk][1]);
                short8 bfr[4];
                #pragma unroll
                for (int f = 0; f < 4; ++f) bfr[f] = *(const short8*)(Bb + boff[kk][f]);
                #pragma unroll
                for (int f = 0; f < 4; ++f) {
                    acc[0][f] = __builtin_amdgcn_mfma_f32_16x16x32_bf16(a0, bfr[f], acc[0][f], 0, 0, 0);
                    acc[1][f] = __builtin_amdgcn_mfma_f32_16x16x32_bf16(a1, bfr[f], acc[1][f], 0, 0, 0);
                }
            }
        }
        __syncthreads();
        // ---- write C tile (C/D map: col = lane&15, row = (lane>>4)*4 + reg)
        #pragma unroll
        for (int m = 0; m < 2; ++m)
            #pragma unroll
            for (int f = 0; f < 4; ++f)
                #pragma unroll
                for (int i = 0; i < 4; ++i)
                    Ct[(wr * 32 + m * 16 + lg * 4 + i) * 132 + wc * 64 + f * 16 + lc] = acc[m][f][i];
        __syncthreads();
        // ---- scan: thread (r,g) covers cols c = g*4 + 16u (aligned float4 chunks)
        #pragma unroll
        for (int u = 0; u < 8; ++u) {
            int c = g * 4 + u * 16;
            float4 v4 = *(const float4*)&Ct[r * 132 + c];
            float4 e4 = *(const float4*)&en[n0 + c];
            float d0 = cnr + e4.x - 2.f * v4.x;
            float d1 = cnr + e4.y - 2.f * v4.y;
            float d2 = cnr + e4.z - 2.f * v4.z;
            float d3 = cnr + e4.w - 2.f * v4.w;
            ins(d0, v4.x); ins(d1, v4.y); ins(d2, v4.z); ins(d3, v4.w);
        }
        __syncthreads();
    }
    float* ML = (float*)smem;
    #pragma unroll
    for (int i = 0; i < 10; ++i) {
        ML[t * 20 + 2 * i] = topd[i];
        ML[t * 20 + 2 * i + 1] = topv[i];
    }
    __syncthreads();
    if (g == 0) {
        #pragma unroll 1
        for (int o = 1; o < 4; ++o) {
            const float* L = &ML[(t + o) * 20];
            #pragma unroll 1
            for (int i = 0; i < 10; ++i) {
                float nd = L[2 * i];
                if (nd >= topd[9]) break;
                float nv = L[2 * i + 1];
                topd[9] = nd; topv[9] = nv;
                #pragma unroll
                for (int x = 9; x > 0; --x) {
                    if (topd[x] < topd[x - 1]) {
                        float td = topd[x]; topd[x] = topd[x - 1]; topd[x - 1] = td;
                        float tv = topv[x]; topv[x] = topv[x - 1]; topv[x - 1] = tv;
                    }
                }
            }
        }
        float2* dst = &cand[((size_t)(c0 + r) * 128 + blockIdx.x) * 10];
        #pragma unroll
        for (int i = 0; i < 10; ++i) dst[i] = make_float2(topd[i], topv[i]);
    }
}

// ======================= FALLBACK PATH (round-3, proven) =======================
template <int RELU>
__global__ __launch_bounds__(256) void k_gemm(const float* __restrict__ A,
                                              const float* __restrict__ Bm,
                                              float* __restrict__ Cm,
                                              int M, int N, int K) {
    __shared__ float As[16][68];
    __shared__ float Bs[16][128];
    const int t = threadIdx.x;
    const int m0 = blockIdx.x * 64, n0 = blockIdx.y * 128;
    const int tm = t >> 4, tn = t & 15;
    float acc[4][8] = {};
    #pragma unroll 1
    for (int k0 = 0; k0 < K; k0 += 16) {
        {
            int i = t >> 2, kk4 = (t & 3) * 4;
            float4 av = *(const float4*)&A[(size_t)(m0 + i) * K + k0 + kk4];
            As[kk4 + 0][i] = av.x; As[kk4 + 1][i] = av.y;
            As[kk4 + 2][i] = av.z; As[kk4 + 3][i] = av.w;
        }
        {
            int kk = t >> 5, c4 = (t & 31) * 4;
            *(float4*)&Bs[kk][c4] = *(const float4*)&Bm[(size_t)(k0 + kk) * N + n0 + c4];
            *(float4*)&Bs[kk + 8][c4] = *(const float4*)&Bm[(size_t)(k0 + kk + 8) * N + n0 + c4];
        }
        __syncthreads();
        #pragma unroll
        for (int k = 0; k < 16; ++k) {
            float4 a4 = *(const float4*)&As[k][tm * 4];
            float4 b0 = *(const float4*)&Bs[k][tn * 4];
            float4 b1 = *(const float4*)&Bs[k][64 + tn * 4];
            float av[4] = {a4.x, a4.y, a4.z, a4.w};
            float bv[8] = {b0.x, b0.y, b0.z, b0.w, b1.x, b1.y, b1.z, b1.w};
            #pragma unroll
            for (int i = 0; i < 4; ++i)
                #pragma unroll
                for (int j = 0; j < 8; ++j) acc[i][j] += av[i] * bv[j];
        }
        __syncthreads();
    }
    #pragma unroll
    for (int i = 0; i < 4; ++i) {
        int row = m0 + tm * 4 + i;
        float4 o0 = make_float4(acc[i][0], acc[i][1], acc[i][2], acc[i][3]);
        float4 o1 = make_float4(acc[i][4], acc[i][5], acc[i][6], acc[i][7]);
        if (RELU) {
            o0.x = fmaxf(o0.x, 0.f); o0.y = fmaxf(o0.y, 0.f);
            o0.z = fmaxf(o0.z, 0.f); o0.w = fmaxf(o0.w, 0.f);
            o1.x = fmaxf(o1.x, 0.f); o1.y = fmaxf(o1.y, 0.f);
            o1.z = fmaxf(o1.z, 0.f); o1.w = fmaxf(o1.w, 0.f);
        }
        *(float4*)&Cm[(size_t)row * N + n0 + tn * 4] = o0;
        *(float4*)&Cm[(size_t)row * N + n0 + 64 + tn * 4] = o1;
    }
}

template <int RELU>
__global__ __launch_bounds__(256) void k_gemm_bf(const float* __restrict__ A,
                                                 const float* __restrict__ Bm,
                                                 float* __restrict__ Cm,
                                                 int M, int N, int K) {
    __shared__ __align__(16) char smem[15360];
    char* Ab = smem;
    char* Bb = smem + 5120;
    const int t = threadIdx.x;
    const int l = t & 63, w = t >> 6;
    const int wr = w >> 1, wc = w & 1;
    const int lg = l >> 4, lc = l & 15;
    const int m0 = blockIdx.x * 64, n0 = blockIdx.y * 128;
    const int ar = t >> 2, ak = (t & 3) * 8;
    const int bc = t & 63, bw = t >> 6;
    f32x4 acc[2][4];
    #pragma unroll
    for (int m = 0; m < 2; ++m)
        #pragma unroll
        for (int f = 0; f < 4; ++f) acc[m][f] = (f32x4){0.f, 0.f, 0.f, 0.f};
    #pragma unroll 1
    for (int k0 = 0; k0 < K; k0 += 32) {
        __syncthreads();
        {
            const float* p = &A[(size_t)(m0 + ar) * K + k0 + ak];
            float4 a0 = *(const float4*)p;
            float4 a1 = *(const float4*)(p + 4);
            uint4 da = make_uint4(pack2(a0.x, a0.y), pack2(a0.z, a0.w),
                                  pack2(a1.x, a1.y), pack2(a1.z, a1.w));
            *(uint4*)(Ab + ar * 80 + (t & 3) * 16) = da;
        }
        #pragma unroll
        for (int j = 0; j < 2; ++j) {
            float x[8];
            #pragma unroll
            for (int i = 0; i < 8; ++i)
                x[i] = Bm[(size_t)(k0 + 8 * bw + i) * N + n0 + bc + 64 * j];
            uint4 db = make_uint4(pack2(x[0], x[1]), pack2(x[2], x[3]),
                                  pack2(x[4], x[5]), pack2(x[6], x[7]));
            *(uint4*)(Bb + (bc + 64 * j) * 80 + bw * 16) = db;
        }
        __syncthreads();
        short8 af0 = *(const short8*)(Ab + (wr * 32 + lc) * 80 + lg * 16);
        short8 af1 = *(const short8*)(Ab + (wr * 32 + 16 + lc) * 80 + lg * 16);
        short8 bfr[4];
        #pragma unroll
        for (int f = 0; f < 4; ++f)
            bfr[f] = *(const short8*)(Bb + (wc * 64 + f * 16 + lc) * 80 + lg * 16);
        #pragma unroll
        for (int f = 0; f < 4; ++f) {
            acc[0][f] = __builtin_amdgcn_mfma_f32_16x16x32_bf16(af0, bfr[f], acc[0][f], 0, 0, 0);
            acc[1][f] = __builtin_amdgcn_mfma_f32_16x16x32_bf16(af1, bfr[f], acc[1][f], 0, 0, 0);
        }
    }
    #pragma unroll
    for (int m = 0; m < 2; ++m)
        #pragma unroll
        for (int f = 0; f < 4; ++f)
            #pragma unroll
            for (int i = 0; i < 4; ++i) {
                int row = m0 + wr * 32 + m * 16 + lg * 4 + i;
                int col = n0 + wc * 64 + f * 16 + lc;
                float v = acc[m][f][i];
                if (RELU) v = fmaxf(v, 0.f);
                Cm[(size_t)row * N + col] = v;
            }
}

__global__ __launch_bounds__(256) void k_prob(const float* __restrict__ emb,
                                              const float* __restrict__ cn_sq,
                                              float* __restrict__ S) {
    __shared__ float red[256];
    int b = blockIdx.x, t = threadIdx.x;
    float s = 0.f;
    #pragma unroll
    for (int j = 0; j < 3; ++j) { float v = emb[(size_t)b * 768 + t + j * 256]; s += v * v; }
    red[t] = s; __syncthreads();
    for (int st = 128; st > 0; st >>= 1) { if (t < st) red[t] += red[t + st]; __syncthreads(); }
    float rn = fmaxf(sqrtf(red[0]), 1e-12f);
    __syncthreads();
    float vals[2]; float sum = 0.f;
    #pragma unroll
    for (int j = 0; j < 2; ++j) {
        int cc = t + j * 256;
        float sc = S[(size_t)b * 512 + cc];
        float cn = fmaxf(sqrtf(cn_sq[cc]), 1e-12f);
        float v = (sc / (rn * cn) > 0.1f) ? sc : 0.f;
        vals[j] = v; sum += v;
    }
    red[t] = sum; __syncthreads();
    for (int st = 128; st > 0; st >>= 1) { if (t < st) red[t] += red[t + st]; __syncthreads(); }
    float denom = red[0] + 0.001f;
    #pragma unroll
    for (int j = 0; j < 2; ++j) S[(size_t)b * 512 + (t + j * 256)] = vals[j] / denom;
}

__global__ void k_en(const float* __restrict__ X, float* __restrict__ en) {
    int n4 = blockIdx.x * 256 + threadIdx.x;
    float4 s = make_float4(0.f, 0.f, 0.f, 0.f);
    #pragma unroll 4
    for (int d = 0; d < 768; ++d) {
        float4 v = *(const float4*)&X[(size_t)d * 65536 + n4 * 4];
        s.x += v.x * v.x; s.y += v.y * v.y; s.z += v.z * v.z; s.w += v.w * v.w;
    }
    *(float4*)&en[n4 * 4] = s;
}

__global__ __launch_bounds__(256, 4) void k_cx_topk(const float* __restrict__ cpt,
                                                    const float* __restrict__ X,
                                                    const float* __restrict__ cn_sq,
                                                    const float* __restrict__ en,
                                                    float2* __restrict__ cand) {
    __shared__ __align__(16) char smem_c[34048];
    float* Ct = (float*)smem_c;
    char* Ab = smem_c;
    char* Bb = smem_c + 5120;
    const int t = threadIdx.x;
    const int l = t & 63, w = t >> 6;
    const int wr = w >> 1, wc = w & 1;
    const int lg = l >> 4, lc = l & 15;
    const int c0 = blockIdx.y * 64;
    const int nbase = blockIdx.x * 512;
    const float FINF = __builtin_inff();
    const int sc_ = t & 63, sw = t >> 6;
    const int r = t >> 2, g = t & 3;
    float topd[10], topv[10];
    #pragma unroll
    for (int i = 0; i < 10; ++i) { topd[i] = FINF; topv[i] = 0.f; }
    const float cnr = cn_sq[c0 + r];
    #pragma unroll 1
    for (int s = 0; s < 4; ++s) {
        const int n0 = nbase + s * 128;
        f32x4 acc[2][4];
        #pragma unroll
        for (int m = 0; m < 2; ++m)
            #pragma unroll
            for (int f = 0; f < 4; ++f) acc[m][f] = (f32x4){0.f, 0.f, 0.f, 0.f};
        #pragma unroll 1
        for (int k0 = 0; k0 < 768; k0 += 32) {
            __syncthreads();
            {
                float x[8];
                #pragma unroll
                for (int i = 0; i < 8; ++i)
                    x[i] = cpt[(size_t)(k0 + 8 * sw + i) * 512 + c0 + sc_];
                uint4 da = make_uint4(pack2(x[0], x[1]), pack2(x[2], x[3]),
                                      pack2(x[4], x[5]), pack2(x[6], x[7]));
                *(uint4*)(Ab + sc_ * 80 + sw * 16) = da;
            }
            #pragma unroll
            for (int j = 0; j < 2; ++j) {
                float x[8];
                #pragma unroll
                for (int i = 0; i < 8; ++i)
                    x[i] = X[(size_t)(k0 + 8 * sw + i) * 65536 + n0 + sc_ + 64 * j];
                uint4 db = make_uint4(pack2(x[0], x[1]), pack2(x[2], x[3]),
                                      pack2(x[4], x[5]), pack2(x[6], x[7]));
                *(uint4*)(Bb + (sc_ + 64 * j) * 80 + sw * 16) = db;
            }
            __syncthreads();
            short8 af0 = *(const short8*)(Ab + (wr * 32 + lc) * 80 + lg * 16);
            short8 af1 = *(const short8*)(Ab + (wr * 32 + 16 + lc) * 80 + lg * 16);
            short8 bfr[4];
            #pragma unroll
            for (int f = 0; f < 4; ++f)
                bfr[f] = *(const short8*)(Bb + (wc * 64 + f * 16 + lc) * 80 + lg * 16);
            #pragma unroll
            for (int f = 0; f < 4; ++f) {
                acc[0][f] = __builtin_amdgcn_mfma_f32_16x16x32_bf16(af0, bfr[f], acc[0][f], 0, 0, 0);
                acc[1][f] = __builtin_amdgcn_mfma_f32_16x16x32_bf16(af1, bfr[f], acc[1][f], 0, 0, 0);
            }
        }
        __syncthreads();
        #pragma unroll
        for (int m = 0; m < 2; ++m)
            #pragma unroll
            for (int f = 0; f < 4; ++f)
                #pragma unroll
                for (int i = 0; i < 4; ++i)
                    Ct[(wr * 32 + m * 16 + lg * 4 + i) * 133 + wc * 64 + f * 16 + lc] = acc[m][f][i];
        __syncthreads();
        #pragma unroll 1
        for (int u = 0; u < 32; ++u) {
            int c = u * 4 + g;
            float val = Ct[r * 133 + c];
            float dist = cnr + en[n0 + c] - 2.f * val;
            if (dist < topd[9]) {
                topd[9] = dist; topv[9] = val;
                #pragma unroll
                for (int i = 9; i > 0; --i) {
                    if (topd[i] < topd[i - 1]) {
                        float td = topd[i]; topd[i] = topd[i - 1]; topd[i - 1] = td;
                        float tv = topv[i]; topv[i] = topv[i - 1]; topv[i - 1] = tv;
                    }
                }
            }
        }
        __syncthreads();
    }
    float* ML = (float*)smem_c;
    #pragma unroll
    for (int i = 0; i < 10; ++i) {
        ML[t * 20 + 2 * i] = topd[i];
        ML[t * 20 + 2 * i + 1] = topv[i];
    }
    __syncthreads();
    if (g == 0) {
        #pragma unroll 1
        for (int o = 1; o < 4; ++o) {
            const float* L = &ML[(t + o) * 20];
            #pragma unroll 1
            for (int i = 0; i < 10; ++i) {
                float nd = L[2 * i];
                if (nd >= topd[9]) break;
                float nv = L[2 * i + 1];
                topd[9] = nd; topv[9] = nv;
                #pragma unroll
                for (int x = 9; x > 0; --x) {
                    if (topd[x] < topd[x - 1]) {
                        float td = topd[x]; topd[x] = topd[x - 1]; topd[x - 1] = td;
                        float tv = topv[x]; topv[x] = topv[x - 1]; topv[x - 1] = tv;
                    }
                }
            }
        }
        float2* dst = &cand[((size_t)(c0 + r) * 128 + blockIdx.x) * 10];
        #pragma unroll
        for (int i = 0; i < 10; ++i) dst[i] = make_float2(topd[i], topv[i]);
    }
}

// ======================= launcher =======================
extern "C" void kernel_launch(void* const* d_in, const int* in_sizes, int n_in,
                              void* d_out, int out_size, void* d_ws, size_t ws_size,
                              hipStream_t stream) {
    const float* emb = (const float*)d_in[0];   // [8192 x 768]
    const float* X   = (const float*)d_in[1];   // [768 x 65536]
    const float* cpt = (const float*)d_in[2];   // [768 x 512]
    const float* r1  = (const float*)d_in[3];   // [512 x 256]
    const float* r2  = (const float*)d_in[4];   // [256 x 768]
    float* out = (float*)d_out;
    float* ws = (float*)d_ws;
    float* S = out + 6291456;                   // prob region doubles as score scratch

    const size_t OFF_CN = 0, OFF_EN = 512, OFF_ACC = 66048, OFF_XBT = 66560;
    const size_t OFF_EMBB = 25232384, OFF_CPTB = 28378112, OFF_R1T = 28574720;
    const size_t OFF_R2T = 28640256, OFF_PRBB = 28738560, OFF_RL1B = 30835712;
    const size_t OFF_CAND = 31884288, WS_NEED = 33195008ull * 4ull;

    if (ws_size >= WS_NEED) {
        float* cn_sq = ws + OFF_CN;
        float* en    = ws + OFF_EN;
        float* acc   = ws + OFF_ACC;
        ushort* XbT  = (ushort*)(ws + OFF_XBT);
        ushort* embb = (ushort*)(ws + OFF_EMBB);
        ushort* cptb = (ushort*)(ws + OFF_CPTB);
        ushort* r1T  = (ushort*)(ws + OFF_R1T);
        ushort* r2T  = (ushort*)(ws + OFF_R2T);
        ushort* prbb = (ushort*)(ws + OFF_PRBB);
        ushort* rl1b = (ushort*)(ws + OFF_RL1B);
        float2* cand = (float2*)(ws + OFF_CAND);

        k_zero<<<259, 256, 0, stream>>>(ws, 66056);
        k_col_sumsq<<<dim3(2, 8), 256, 0, stream>>>(cpt, cn_sq);
        k_row_stats<<<48, 256, 0, stream>>>(cpt, acc);
        k_tc<1><<<dim3(256, 24), 256, 0, stream>>>(X, XbT, en, 65536, 768);
        k_tc<0><<<dim3(2, 24), 256, 0, stream>>>(cpt, cptb, nullptr, 512, 768);
        k_tc<0><<<dim3(1, 16), 256, 0, stream>>>(r1, r1T, nullptr, 256, 512);
        k_tc<0><<<dim3(3, 8), 256, 0, stream>>>(r2, r2T, nullptr, 768, 256);
        k_cvt_emb<<<3072, 256, 0, stream>>>(emb, embb);
        gemm_bt<1, 0, 0><<<dim3(128, 4), 256, 0, stream>>>(embb, cptb, S, nullptr, 8192, 512, 768);
        k_prob2<<<8192, 256, 0, stream>>>(emb, cpt, cn_sq, S, prbb);
        gemm_bt<0, 1, 1><<<dim3(128, 2), 256, 0, stream>>>(prbb, r1T, nullptr, rl1b, 8192, 256, 512);
        gemm_bt<1, 0, 0><<<dim3(128, 6), 256, 0, stream>>>(rl1b, r2T, out, nullptr, 8192, 768, 256);
        k_cx_topk2<<<dim3(128, 8), 256, 0, stream>>>(cptb, XbT, cn_sq, en, cand);
        k_knn_merge<1280><<<512, 256, 0, stream>>>(cand, acc);
        k_finalize<<<1, 64, 0, stream>>>(acc, out);
    } else {
        float* cn_sq = ws;
        float* en    = ws + 512;
        float* acc   = ws + 66048;
        float* rl1   = ws + 66560;
        float2* cand = (float2*)(ws + 66560 + 8192 * 256);
        k_init<<<1, 256, 0, stream>>>(cn_sq, acc);
        k_col_sumsq<<<dim3(2, 8), 256, 0, stream>>>(cpt, cn_sq);
        k_row_stats<<<48, 256, 0, stream>>>(cpt, acc);
        k_gemm<0><<<dim3(128, 4), 256, 0, stream>>>(emb, cpt, S, 8192, 512, 768);
        k_prob<<<8192, 256, 0, stream>>>(emb, cn_sq, S);
        k_gemm_bf<1><<<dim3(128, 2), 256, 0, stream>>>(S, r1, rl1, 8192, 256, 512);
        k_gemm_bf<0><<<dim3(128, 6), 256, 0, stream>>>(rl1, r2, out, 8192, 768, 256);
        k_en<<<64, 256, 0, stream>>>(X, en);
        k_cx_topk<<<dim3(128, 8), 256, 0, stream>>>(cpt, X, cn_sq, en, cand);
        k_knn_merge<1280><<<512, 256, 0, stream>>>(cand, acc);
        k_finalize<<<1, 64, 0, stream>>>(acc, out);
    }
}

// Round 13
// 319.653 us; speedup vs baseline: 1.5385x; 1.1230x over previous
//
#include <hip/hip_runtime.h>

// Problem constants: B=8192, D=768, C=512, H=256, N=65536, k=10.
// Outputs (flat): rec_layer_2 [8192*768], prob [8192*512], L1, L2.

typedef __attribute__((ext_vector_type(8))) short short8;
typedef __attribute__((ext_vector_type(4))) float f32x4;
typedef unsigned int u32;

__device__ __forceinline__ ushort f2bf(float f) {
    unsigned u = __builtin_bit_cast(unsigned, f);
    u += 0x7FFFu + ((u >> 16) & 1u);          // round-to-nearest-even
    return (ushort)(u >> 16);
}
__device__ __forceinline__ unsigned pack2(float lo, float hi) {
    return (unsigned)f2bf(lo) | ((unsigned)f2bf(hi) << 16);
}
// async global->LDS, 16B per lane; lds dest = wave-uniform base + lane*16
__device__ __forceinline__ void gll16(const void* g, void* l) {
    __builtin_amdgcn_global_load_lds((const __attribute__((address_space(1))) u32*)g,
                                     (__attribute__((address_space(3))) u32*)l, 16, 0, 0);
}

// ======================= shared small kernels =======================
__global__ void k_zero(float* p, int n) {
    int i = blockIdx.x * 256 + threadIdx.x;
    if (i < n) p[i] = 0.f;
}
__global__ void k_init(float* cn_sq, float* acc) {
    int t = threadIdx.x;
    cn_sq[t] = 0.f; cn_sq[t + 256] = 0.f;
    if (t < 8) acc[t] = 0.f;
}
__global__ void k_col_sumsq(const float* __restrict__ cpt, float* __restrict__ cn_sq) {
    int c = blockIdx.x * 256 + threadIdx.x;
    int d0 = blockIdx.y * 96;
    float s = 0.f;
    #pragma unroll 4
    for (int d = d0; d < d0 + 96; ++d) { float v = cpt[d * 512 + c]; s += v * v; }
    atomicAdd(&cn_sq[c], s);
}
__global__ void k_row_stats(const float* __restrict__ cpt, float* __restrict__ acc) {
    __shared__ float red[256];
    int t = threadIdx.x;
    int d = blockIdx.x * 16;
    float rowsq = 0.f, tot = 0.f;
    for (int r = 0; r < 16; ++r, ++d) {
        float v1 = cpt[d * 512 + t], v2 = cpt[d * 512 + 256 + t];
        tot += v1 * v1 + v2 * v2;
        red[t] = v1 + v2;
        __syncthreads();
        for (int st = 128; st > 0; st >>= 1) {
            if (t < st) red[t] += red[t + st];
            __syncthreads();
        }
        if (t == 0) rowsq += red[0] * red[0];
        __syncthreads();
    }
    red[t] = tot; __syncthreads();
    for (int st = 128; st > 0; st >>= 1) {
        if (t < st) red[t] += red[t + st];
        __syncthreads();
    }
    if (t == 0) { atomicAdd(&acc[1], rowsq); atomicAdd(&acc[2], red[0]); }
}

template <int NB>
__global__ __launch_bounds__(256) void k_knn_merge(const float2* __restrict__ cand,
                                                   float* __restrict__ acc) {
    __shared__ float2 buf[NB];
    __shared__ float2 l2[160];
    int c = blockIdx.x, t = threadIdx.x;
    const float FINF = __builtin_inff();
    const float2* src = &cand[(size_t)c * NB];
    for (int i = t; i < NB; i += 256) buf[i] = src[i];
    __syncthreads();
    if (t < 16) {
        float td[10], tv[10];
        #pragma unroll
        for (int i = 0; i < 10; ++i) { td[i] = FINF; tv[i] = 0.f; }
        const int per = NB / 16;
        for (int j = t * per; j < t * per + per; ++j) {
            float nd = buf[j].x;
            if (nd < td[9]) {
                td[9] = nd; tv[9] = buf[j].y;
                #pragma unroll
                for (int x = 9; x > 0; --x)
                    if (td[x] < td[x - 1]) {
                        float a = td[x]; td[x] = td[x - 1]; td[x - 1] = a;
                        float b = tv[x]; tv[x] = tv[x - 1]; tv[x - 1] = b;
                    }
            }
        }
        #pragma unroll
        for (int i = 0; i < 10; ++i) l2[t * 10 + i] = make_float2(td[i], tv[i]);
    }
    __syncthreads();
    if (t == 0) {
        float td[10], tv[10];
        #pragma unroll
        for (int i = 0; i < 10; ++i) { td[i] = FINF; tv[i] = 0.f; }
        for (int j = 0; j < 160; ++j) {
            float nd = l2[j].x;
            if (nd < td[9]) {
                td[9] = nd; tv[9] = l2[j].y;
                #pragma unroll
                for (int x = 9; x > 0; --x)
                    if (td[x] < td[x - 1]) {
                        float a = td[x]; td[x] = td[x - 1]; td[x - 1] = a;
                        float b = tv[x]; tv[x] = tv[x - 1]; tv[x - 1] = b;
                    }
            }
        }
        float s = 0.f;
        #pragma unroll
        for (int i = 0; i < 10; ++i) s += tv[i];
        atomicAdd(&acc[0], s);
    }
}
__global__ void k_finalize(const float* __restrict__ acc, float* __restrict__ out) {
    if (threadIdx.x == 0) {
        out[10485760] = acc[0] / 5120.0f;
        out[10485761] = (acc[1] - acc[2]) / 262144.0f;
    }
}

// ======================= FAST PATH =======================
template <int EN>
__global__ __launch_bounds__(256) void k_tc(const float* __restrict__ src,
                                            ushort* __restrict__ dst,
                                            float* __restrict__ en,
                                            int Ncols, int D) {
    __shared__ float tile[32][256];
    const int t = threadIdx.x;
    const int n0 = blockIdx.x * 256;
    const int d0 = blockIdx.y * 32;
    float s = 0.f;
    #pragma unroll 8
    for (int dd = 0; dd < 32; ++dd) {
        float v = src[(size_t)(d0 + dd) * Ncols + n0 + t];
        tile[dd][t] = v;
        if (EN) s += v * v;
    }
    if (EN) atomicAdd(&en[n0 + t], s);
    __syncthreads();
    ushort* drow = dst + (size_t)(n0 + t) * D + d0;
    #pragma unroll
    for (int q = 0; q < 4; ++q) {
        uint4 d4;
        d4.x = pack2(tile[q * 8 + 0][t], tile[q * 8 + 1][t]);
        d4.y = pack2(tile[q * 8 + 2][t], tile[q * 8 + 3][t]);
        d4.z = pack2(tile[q * 8 + 4][t], tile[q * 8 + 5][t]);
        d4.w = pack2(tile[q * 8 + 6][t], tile[q * 8 + 7][t]);
        *(uint4*)(drow + q * 8) = d4;
    }
}

// fp32 transpose: src [D][Ncols] -> dst [Ncols][D] (for k_prob2's coalesced exact dot)
__global__ __launch_bounds__(256) void k_tcp(const float* __restrict__ src,
                                             float* __restrict__ dst,
                                             int Ncols, int D) {
    __shared__ float tile[32][257];
    const int t = threadIdx.x;
    const int n0 = blockIdx.x * 256;
    const int d0 = blockIdx.y * 32;
    #pragma unroll 8
    for (int dd = 0; dd < 32; ++dd)
        tile[dd][t] = src[(size_t)(d0 + dd) * Ncols + n0 + t];
    __syncthreads();
    float* drow = dst + (size_t)(n0 + t) * D + d0;
    #pragma unroll
    for (int q = 0; q < 8; ++q) {
        float4 d4 = make_float4(tile[q * 4 + 0][t], tile[q * 4 + 1][t],
                                tile[q * 4 + 2][t], tile[q * 4 + 3][t]);
        *(float4*)(drow + q * 4) = d4;
    }
}

__global__ void k_cvt_emb(const float* __restrict__ src, ushort* __restrict__ dst) {
    int i = (blockIdx.x * 256 + threadIdx.x) * 8;
    float4 a = *(const float4*)&src[i], b = *(const float4*)&src[i + 4];
    uint4 d4 = make_uint4(pack2(a.x, a.y), pack2(a.z, a.w), pack2(b.x, b.y), pack2(b.z, b.w));
    *(uint4*)&dst[i] = d4;
}

// C = A[MxK] @ B[NxK]^T, bf16 in, gload_lds staging, tile 64x128, BK=64.
// LDS rows 128B, slot swizzle oct^=(row&7); stage: 8 lanes/row, 1KB/call.
template <int WF32, int WB16, int RELU>
__global__ __launch_bounds__(256, 4) void gemm_bt(const ushort* __restrict__ A,
                                                  const ushort* __restrict__ B,
                                                  float* __restrict__ C,
                                                  ushort* __restrict__ Cb,
                                                  int M, int N, int K) {
    __shared__ __align__(16) char smem[24576];
    char* Ab = smem;              // [64 rows][128 B]
    char* Bb = smem + 8192;       // [128 rows][128 B]
    const int t = threadIdx.x;
    const int l = t & 63, w = t >> 6;
    const int wr = w >> 1, wc = w & 1;
    const int lg = l >> 4, lc = l & 15;
    const int m0 = blockIdx.x * 64, n0 = blockIdx.y * 128;
    const int sr8 = l >> 3, oct = l & 7;
    const int arw0 = 16 * w + sr8, arw1 = arw0 + 8;
    const ushort* ga0 = A + (size_t)(m0 + arw0) * K + (oct ^ (arw0 & 7)) * 8;
    const ushort* ga1 = A + (size_t)(m0 + arw1) * K + (oct ^ (arw1 & 7)) * 8;
    char* la0 = Ab + w * 2048;
    char* la1 = Ab + w * 2048 + 1024;
    const int brw0 = 32 * w + sr8, brw1 = brw0 + 8, brw2 = brw0 + 16, brw3 = brw0 + 24;
    const ushort* gb0 = B + (size_t)(n0 + brw0) * K + (oct ^ (brw0 & 7)) * 8;
    const ushort* gb1 = B + (size_t)(n0 + brw1) * K + (oct ^ (brw1 & 7)) * 8;
    const ushort* gb2 = B + (size_t)(n0 + brw2) * K + (oct ^ (brw2 & 7)) * 8;
    const ushort* gb3 = B + (size_t)(n0 + brw3) * K + (oct ^ (brw3 & 7)) * 8;
    char* lb0 = Bb + w * 4096;
    char* lb1 = Bb + w * 4096 + 1024;
    char* lb2 = Bb + w * 4096 + 2048;
    char* lb3 = Bb + w * 4096 + 3072;
    const int ar0 = wr * 32 + lc, ar1 = ar0 + 16;
    int aoff[2][2], boff[2][4];
    #pragma unroll
    for (int kk = 0; kk < 2; ++kk) {
        aoff[kk][0] = ar0 * 128 + (((kk * 4 + lg) ^ (ar0 & 7)) * 16);
        aoff[kk][1] = ar1 * 128 + (((kk * 4 + lg) ^ (ar1 & 7)) * 16);
        #pragma unroll
        for (int f = 0; f < 4; ++f) {
            int bc = wc * 64 + f * 16 + lc;
            boff[kk][f] = bc * 128 + (((kk * 4 + lg) ^ (bc & 7)) * 16);
        }
    }
    f32x4 acc[2][4];
    #pragma unroll
    for (int m = 0; m < 2; ++m)
        #pragma unroll
        for (int f = 0; f < 4; ++f) acc[m][f] = (f32x4){0.f, 0.f, 0.f, 0.f};

    #pragma unroll 1
    for (int k0 = 0; k0 < K; k0 += 64) {
        __syncthreads();
        gll16(ga0 + k0, la0); gll16(ga1 + k0, la1);
        gll16(gb0 + k0, lb0); gll16(gb1 + k0, lb1);
        gll16(gb2 + k0, lb2); gll16(gb3 + k0, lb3);
        __syncthreads();
        #pragma unroll
        for (int kk = 0; kk < 2; ++kk) {
            short8 a0 = *(const short8*)(Ab + aoff[kk][0]);
            short8 a1 = *(const short8*)(Ab + aoff[kk][1]);
            short8 bfr[4];
            #pragma unroll
            for (int f = 0; f < 4; ++f) bfr[f] = *(const short8*)(Bb + boff[kk][f]);
            #pragma unroll
            for (int f = 0; f < 4; ++f) {
                acc[0][f] = __builtin_amdgcn_mfma_f32_16x16x32_bf16(a0, bfr[f], acc[0][f], 0, 0, 0);
                acc[1][f] = __builtin_amdgcn_mfma_f32_16x16x32_bf16(a1, bfr[f], acc[1][f], 0, 0, 0);
            }
        }
    }
    #pragma unroll
    for (int m = 0; m < 2; ++m)
        #pragma unroll
        for (int f = 0; f < 4; ++f)
            #pragma unroll
            for (int i = 0; i < 4; ++i) {
                int row = m0 + wr * 32 + m * 16 + lg * 4 + i;
                int col = n0 + wc * 64 + f * 16 + lc;
                float v = acc[m][f][i];
                if (RELU) v = fmaxf(v, 0.f);
                if (WF32) C[(size_t)row * N + col] = v;
                if (WB16) Cb[(size_t)row * N + col] = f2bf(v);
            }
}

// prob epilogue with exact fp32 fixup; cptT [512][768] gives coalesced dots
__global__ __launch_bounds__(256) void k_prob2(const float* __restrict__ emb,
                                               const float* __restrict__ cptT,
                                               const float* __restrict__ cn_sq,
                                               float* __restrict__ S,
                                               ushort* __restrict__ probb) {
    __shared__ float erow[768];
    __shared__ float sval[512];
    __shared__ int idxl[512];
    __shared__ int cnt;
    __shared__ float redw[4];
    const int b = blockIdx.x, t = threadIdx.x;
    const int l = t & 63, w = t >> 6;
    if (t == 0) cnt = 0;
    float s = 0.f;
    #pragma unroll
    for (int j = 0; j < 3; ++j) {
        float v = emb[(size_t)b * 768 + t + j * 256];
        erow[t + j * 256] = v; s += v * v;
    }
    #pragma unroll
    for (int o = 32; o > 0; o >>= 1) s += __shfl_down(s, o);
    if (l == 0) redw[w] = s;
    __syncthreads();
    const float rn = fmaxf(sqrtf(redw[0] + redw[1] + redw[2] + redw[3]), 1e-12f);
    #pragma unroll
    for (int j = 0; j < 2; ++j) {
        int c = t + j * 256;
        sval[c] = 0.f;
        float cn = fmaxf(sqrtf(cn_sq[c]), 1e-12f);
        float sn = S[(size_t)b * 512 + c] / (rn * cn);
        if (sn > 0.1f - 4e-3f) { int p = atomicAdd(&cnt, 1); idxl[p] = c; }
    }
    __syncthreads();
    const int nf = cnt;
    for (int q0 = 0; q0 < nf; q0 += 4) {
        int q = q0 + w;
        if (q < nf) {
            int c = idxl[q];
            const float* cr = cptT + (size_t)c * 768;
            float p = 0.f;
            #pragma unroll
            for (int ii = 0; ii < 3; ++ii) {
                int d = l * 4 + ii * 256;
                float4 e4 = *(const float4*)&erow[d];
                float4 x4 = *(const float4*)&cr[d];
                p += e4.x * x4.x + e4.y * x4.y + e4.z * x4.z + e4.w * x4.w;
            }
            #pragma unroll
            for (int o = 32; o > 0; o >>= 1) p += __shfl_down(p, o);
            if (l == 0) {
                float cn = fmaxf(sqrtf(cn_sq[c]), 1e-12f);
                sval[c] = (p / (rn * cn) > 0.1f) ? p : 0.f;
            }
        }
    }
    __syncthreads();
    float s2 = sval[t] + sval[t + 256];
    #pragma unroll
    for (int o = 32; o > 0; o >>= 1) s2 += __shfl_down(s2, o);
    if (l == 0) redw[w] = s2;
    __syncthreads();
    const float denom = redw[0] + redw[1] + redw[2] + redw[3] + 0.001f;
    #pragma unroll
    for (int j = 0; j < 2; ++j) {
        int c = t + j * 256;
        float pr = sval[c] / denom;
        S[(size_t)b * 512 + c] = pr;
        probb[(size_t)b * 512 + c] = f2bf(pr);
    }
}

// cx GEMM (bf16, gload_lds, BK=64) + fused per-block top-10. grid (128, 8).
// Ct stride 132 (16B-aligned cols) + float4-vectorized scan.
__global__ __launch_bounds__(256, 4) void k_cx_topk2(const ushort* __restrict__ cptb, // [512][768]
                                                     const ushort* __restrict__ XbT,  // [65536][768]
                                                     const float* __restrict__ cn_sq,
                                                     const float* __restrict__ en,
                                                     float2* __restrict__ cand) {
    __shared__ __align__(16) char smem[34048];
    char* Ab = smem;              // [64][128B]
    char* Bb = smem + 8192;       // [128][128B]
    float* Ct = (float*)smem;     // [64][132] f32 (33792 B) aliased

    const int t = threadIdx.x;
    const int l = t & 63, w = t >> 6;
    const int wr = w >> 1, wc = w & 1;
    const int lg = l >> 4, lc = l & 15;
    const int c0 = blockIdx.y * 64;
    const int nbase = blockIdx.x * 512;
    const float FINF = __builtin_inff();

    const int sr8 = l >> 3, oct = l & 7;
    const int arw0 = 16 * w + sr8, arw1 = arw0 + 8;
    const ushort* ga0 = cptb + (size_t)(c0 + arw0) * 768 + (oct ^ (arw0 & 7)) * 8;
    const ushort* ga1 = cptb + (size_t)(c0 + arw1) * 768 + (oct ^ (arw1 & 7)) * 8;
    char* la0 = Ab + w * 2048;
    char* la1 = Ab + w * 2048 + 1024;
    const int brw0 = 32 * w + sr8, brw1 = brw0 + 8, brw2 = brw0 + 16, brw3 = brw0 + 24;
    const int bs0 = (oct ^ (brw0 & 7)) * 8, bs1 = (oct ^ (brw1 & 7)) * 8;
    const int bs2 = (oct ^ (brw2 & 7)) * 8, bs3 = (oct ^ (brw3 & 7)) * 8;
    char* lb0 = Bb + w * 4096;
    char* lb1 = Bb + w * 4096 + 1024;
    char* lb2 = Bb + w * 4096 + 2048;
    char* lb3 = Bb + w * 4096 + 3072;

    const int ar0 = wr * 32 + lc, ar1 = ar0 + 16;
    int aoff[2][2], boff[2][4];
    #pragma unroll
    for (int kk = 0; kk < 2; ++kk) {
        aoff[kk][0] = ar0 * 128 + (((kk * 4 + lg) ^ (ar0 & 7)) * 16);
        aoff[kk][1] = ar1 * 128 + (((kk * 4 + lg) ^ (ar1 & 7)) * 16);
        #pragma unroll
        for (int f = 0; f < 4; ++f) {
            int bc = wc * 64 + f * 16 + lc;
            boff[kk][f] = bc * 128 + (((kk * 4 + lg) ^ (bc & 7)) * 16);
        }
    }

    const int r = t >> 2, g = t & 3;
    float topd[10], topv[10];
    #pragma unroll
    for (int i = 0; i < 10; ++i) { topd[i] = FINF; topv[i] = 0.f; }
    const float cnr = cn_sq[c0 + r];

    auto ins = [&](float d, float v) {
        if (d < topd[9]) {
            topd[9] = d; topv[9] = v;
            #pragma unroll
            for (int x = 9; x > 0; --x) {
                if (topd[x] < topd[x - 1]) {
                    float td = topd[x]; topd[x] = topd[x - 1]; topd[x - 1] = td;
                    float tv = topv[x]; topv[x] = topv[x - 1]; topv[x - 1] = tv;
                }
            }
        }
    };

    #pragma unroll 1
    for (int s = 0; s < 4; ++s) {
        const int n0 = nbase + s * 128;
        const ushort* gb0 = XbT + (size_t)(n0 + brw0) * 768 + bs0;
        const ushort* gb1 = XbT + (size_t)(n0 + brw1) * 768 + bs1;
        const ushort* gb2 = XbT + (size_t)(n0 + brw2) * 768 + bs2;
        const ushort* gb3 = XbT + (size_t)(n0 + brw3) * 768 + bs3;
        f32x4 acc[2][4];
        #pragma unroll
        for (int m = 0; m < 2; ++m)
            #pragma unroll
            for (int f = 0; f < 4; ++f) acc[m][f] = (f32x4){0.f, 0.f, 0.f, 0.f};

        #pragma unroll 1
        for (int k0 = 0; k0 < 768; k0 += 64) {
            __syncthreads();
            gll16(ga0 + k0, la0); gll16(ga1 + k0, la1);
            gll16(gb0 + k0, lb0); gll16(gb1 + k0, lb1);
            gll16(gb2 + k0, lb2); gll16(gb3 + k0, lb3);
            __syncthreads();
            #pragma unroll
            for (int kk = 0; kk < 2; ++kk) {
                short8 a0 = *(const short8*)(Ab + aoff[kk][0]);
                short8 a1 = *(const short8*)(Ab + aoff[kk][1]);
                short8 bfr[4];
                #pragma unroll
                for (int f = 0; f < 4; ++f) bfr[f] = *(const short8*)(Bb + boff[kk][f]);
                #pragma unroll
                for (int f = 0; f < 4; ++f) {
                    acc[0][f] = __builtin_amdgcn_mfma_f32_16x16x32_bf16(a0, bfr[f], acc[0][f], 0, 0, 0);
                    acc[1][f] = __builtin_amdgcn_mfma_f32_16x16x32_bf16(a1, bfr[f], acc[1][f], 0, 0, 0);
                }
            }
        }
        __syncthreads();
        // ---- write C tile (C/D map: col = lane&15, row = (lane>>4)*4 + reg)
        #pragma unroll
        for (int m = 0; m < 2; ++m)
            #pragma unroll
            for (int f = 0; f < 4; ++f)
                #pragma unroll
                for (int i = 0; i < 4; ++i)
                    Ct[(wr * 32 + m * 16 + lg * 4 + i) * 132 + wc * 64 + f * 16 + lc] = acc[m][f][i];
        __syncthreads();
        // ---- scan: thread (r,g) covers cols c = g*4 + 16u (aligned float4 chunks)
        #pragma unroll
        for (int u = 0; u < 8; ++u) {
            int c = g * 4 + u * 16;
            float4 v4 = *(const float4*)&Ct[r * 132 + c];
            float4 e4 = *(const float4*)&en[n0 + c];
            float d0 = cnr + e4.x - 2.f * v4.x;
            float d1 = cnr + e4.y - 2.f * v4.y;
            float d2 = cnr + e4.z - 2.f * v4.z;
            float d3 = cnr + e4.w - 2.f * v4.w;
            ins(d0, v4.x); ins(d1, v4.y); ins(d2, v4.z); ins(d3, v4.w);
        }
        __syncthreads();
    }
    float* ML = (float*)smem;
    #pragma unroll
    for (int i = 0; i < 10; ++i) {
        ML[t * 20 + 2 * i] = topd[i];
        ML[t * 20 + 2 * i + 1] = topv[i];
    }
    __syncthreads();
    if (g == 0) {
        #pragma unroll 1
        for (int o = 1; o < 4; ++o) {
            const float* L = &ML[(t + o) * 20];
            #pragma unroll 1
            for (int i = 0; i < 10; ++i) {
                float nd = L[2 * i];
                if (nd >= topd[9]) break;
                float nv = L[2 * i + 1];
                topd[9] = nd; topv[9] = nv;
                #pragma unroll
                for (int x = 9; x > 0; --x) {
                    if (topd[x] < topd[x - 1]) {
                        float td = topd[x]; topd[x] = topd[x - 1]; topd[x - 1] = td;
                        float tv = topv[x]; topv[x] = topv[x - 1]; topv[x - 1] = tv;
                    }
                }
            }
        }
        float2* dst = &cand[((size_t)(c0 + r) * 128 + blockIdx.x) * 10];
        #pragma unroll
        for (int i = 0; i < 10; ++i) dst[i] = make_float2(topd[i], topv[i]);
    }
}

// ======================= FALLBACK PATH (round-3, proven) =======================
template <int RELU>
__global__ __launch_bounds__(256) void k_gemm(const float* __restrict__ A,
                                              const float* __restrict__ Bm,
                                              float* __restrict__ Cm,
                                              int M, int N, int K) {
    __shared__ float As[16][68];
    __shared__ float Bs[16][128];
    const int t = threadIdx.x;
    const int m0 = blockIdx.x * 64, n0 = blockIdx.y * 128;
    const int tm = t >> 4, tn = t & 15;
    float acc[4][8] = {};
    #pragma unroll 1
    for (int k0 = 0; k0 < K; k0 += 16) {
        {
            int i = t >> 2, kk4 = (t & 3) * 4;
            float4 av = *(const float4*)&A[(size_t)(m0 + i) * K + k0 + kk4];
            As[kk4 + 0][i] = av.x; As[kk4 + 1][i] = av.y;
            As[kk4 + 2][i] = av.z; As[kk4 + 3][i] = av.w;
        }
        {
            int kk = t >> 5, c4 = (t & 31) * 4;
            *(float4*)&Bs[kk][c4] = *(const float4*)&Bm[(size_t)(k0 + kk) * N + n0 + c4];
            *(float4*)&Bs[kk + 8][c4] = *(const float4*)&Bm[(size_t)(k0 + kk + 8) * N + n0 + c4];
        }
        __syncthreads();
        #pragma unroll
        for (int k = 0; k < 16; ++k) {
            float4 a4 = *(const float4*)&As[k][tm * 4];
            float4 b0 = *(const float4*)&Bs[k][tn * 4];
            float4 b1 = *(const float4*)&Bs[k][64 + tn * 4];
            float av[4] = {a4.x, a4.y, a4.z, a4.w};
            float bv[8] = {b0.x, b0.y, b0.z, b0.w, b1.x, b1.y, b1.z, b1.w};
            #pragma unroll
            for (int i = 0; i < 4; ++i)
                #pragma unroll
                for (int j = 0; j < 8; ++j) acc[i][j] += av[i] * bv[j];
        }
        __syncthreads();
    }
    #pragma unroll
    for (int i = 0; i < 4; ++i) {
        int row = m0 + tm * 4 + i;
        float4 o0 = make_float4(acc[i][0], acc[i][1], acc[i][2], acc[i][3]);
        float4 o1 = make_float4(acc[i][4], acc[i][5], acc[i][6], acc[i][7]);
        if (RELU) {
            o0.x = fmaxf(o0.x, 0.f); o0.y = fmaxf(o0.y, 0.f);
            o0.z = fmaxf(o0.z, 0.f); o0.w = fmaxf(o0.w, 0.f);
            o1.x = fmaxf(o1.x, 0.f); o1.y = fmaxf(o1.y, 0.f);
            o1.z = fmaxf(o1.z, 0.f); o1.w = fmaxf(o1.w, 0.f);
        }
        *(float4*)&Cm[(size_t)row * N + n0 + tn * 4] = o0;
        *(float4*)&Cm[(size_t)row * N + n0 + 64 + tn * 4] = o1;
    }
}

template <int RELU>
__global__ __launch_bounds__(256) void k_gemm_bf(const float* __restrict__ A,
                                                 const float* __restrict__ Bm,
                                                 float* __restrict__ Cm,
                                                 int M, int N, int K) {
    __shared__ __align__(16) char smem[15360];
    char* Ab = smem;
    char* Bb = smem + 5120;
    const int t = threadIdx.x;
    const int l = t & 63, w = t >> 6;
    const int wr = w >> 1, wc = w & 1;
    const int lg = l >> 4, lc = l & 15;
    const int m0 = blockIdx.x * 64, n0 = blockIdx.y * 128;
    const int ar = t >> 2, ak = (t & 3) * 8;
    const int bc = t & 63, bw = t >> 6;
    f32x4 acc[2][4];
    #pragma unroll
    for (int m = 0; m < 2; ++m)
        #pragma unroll
        for (int f = 0; f < 4; ++f) acc[m][f] = (f32x4){0.f, 0.f, 0.f, 0.f};
    #pragma unroll 1
    for (int k0 = 0; k0 < K; k0 += 32) {
        __syncthreads();
        {
            const float* p = &A[(size_t)(m0 + ar) * K + k0 + ak];
            float4 a0 = *(const float4*)p;
            float4 a1 = *(const float4*)(p + 4);
            uint4 da = make_uint4(pack2(a0.x, a0.y), pack2(a0.z, a0.w),
                                  pack2(a1.x, a1.y), pack2(a1.z, a1.w));
            *(uint4*)(Ab + ar * 80 + (t & 3) * 16) = da;
        }
        #pragma unroll
        for (int j = 0; j < 2; ++j) {
            float x[8];
            #pragma unroll
            for (int i = 0; i < 8; ++i)
                x[i] = Bm[(size_t)(k0 + 8 * bw + i) * N + n0 + bc + 64 * j];
            uint4 db = make_uint4(pack2(x[0], x[1]), pack2(x[2], x[3]),
                                  pack2(x[4], x[5]), pack2(x[6], x[7]));
            *(uint4*)(Bb + (bc + 64 * j) * 80 + bw * 16) = db;
        }
        __syncthreads();
        short8 af0 = *(const short8*)(Ab + (wr * 32 + lc) * 80 + lg * 16);
        short8 af1 = *(const short8*)(Ab + (wr * 32 + 16 + lc) * 80 + lg * 16);
        short8 bfr[4];
        #pragma unroll
        for (int f = 0; f < 4; ++f)
            bfr[f] = *(const short8*)(Bb + (wc * 64 + f * 16 + lc) * 80 + lg * 16);
        #pragma unroll
        for (int f = 0; f < 4; ++f) {
            acc[0][f] = __builtin_amdgcn_mfma_f32_16x16x32_bf16(af0, bfr[f], acc[0][f], 0, 0, 0);
            acc[1][f] = __builtin_amdgcn_mfma_f32_16x16x32_bf16(af1, bfr[f], acc[1][f], 0, 0, 0);
        }
    }
    #pragma unroll
    for (int m = 0; m < 2; ++m)
        #pragma unroll
        for (int f = 0; f < 4; ++f)
            #pragma unroll
            for (int i = 0; i < 4; ++i) {
                int row = m0 + wr * 32 + m * 16 + lg * 4 + i;
                int col = n0 + wc * 64 + f * 16 + lc;
                float v = acc[m][f][i];
                if (RELU) v = fmaxf(v, 0.f);
                Cm[(size_t)row * N + col] = v;
            }
}

__global__ __launch_bounds__(256) void k_prob(const float* __restrict__ emb,
                                              const float* __restrict__ cn_sq,
                                              float* __restrict__ S) {
    __shared__ float red[256];
    int b = blockIdx.x, t = threadIdx.x;
    float s = 0.f;
    #pragma unroll
    for (int j = 0; j < 3; ++j) { float v = emb[(size_t)b * 768 + t + j * 256]; s += v * v; }
    red[t] = s; __syncthreads();
    for (int st = 128; st > 0; st >>= 1) { if (t < st) red[t] += red[t + st]; __syncthreads(); }
    float rn = fmaxf(sqrtf(red[0]), 1e-12f);
    __syncthreads();
    float vals[2]; float sum = 0.f;
    #pragma unroll
    for (int j = 0; j < 2; ++j) {
        int cc = t + j * 256;
        float sc = S[(size_t)b * 512 + cc];
        float cn = fmaxf(sqrtf(cn_sq[cc]), 1e-12f);
        float v = (sc / (rn * cn) > 0.1f) ? sc : 0.f;
        vals[j] = v; sum += v;
    }
    red[t] = sum; __syncthreads();
    for (int st = 128; st > 0; st >>= 1) { if (t < st) red[t] += red[t + st]; __syncthreads(); }
    float denom = red[0] + 0.001f;
    #pragma unroll
    for (int j = 0; j < 2; ++j) S[(size_t)b * 512 + (t + j * 256)] = vals[j] / denom;
}

__global__ void k_en(const float* __restrict__ X, float* __restrict__ en) {
    int n4 = blockIdx.x * 256 + threadIdx.x;
    float4 s = make_float4(0.f, 0.f, 0.f, 0.f);
    #pragma unroll 4
    for (int d = 0; d < 768; ++d) {
        float4 v = *(const float4*)&X[(size_t)d * 65536 + n4 * 4];
        s.x += v.x * v.x; s.y += v.y * v.y; s.z += v.z * v.z; s.w += v.w * v.w;
    }
    *(float4*)&en[n4 * 4] = s;
}

__global__ __launch_bounds__(256, 4) void k_cx_topk(const float* __restrict__ cpt,
                                                    const float* __restrict__ X,
                                                    const float* __restrict__ cn_sq,
                                                    const float* __restrict__ en,
                                                    float2* __restrict__ cand) {
    __shared__ __align__(16) char smem_c[34048];
    float* Ct = (float*)smem_c;
    char* Ab = smem_c;
    char* Bb = smem_c + 5120;
    const int t = threadIdx.x;
    const int l = t & 63, w = t >> 6;
    const int wr = w >> 1, wc = w & 1;
    const int lg = l >> 4, lc = l & 15;
    const int c0 = blockIdx.y * 64;
    const int nbase = blockIdx.x * 512;
    const float FINF = __builtin_inff();
    const int sc_ = t & 63, sw = t >> 6;
    const int r = t >> 2, g = t & 3;
    float topd[10], topv[10];
    #pragma unroll
    for (int i = 0; i < 10; ++i) { topd[i] = FINF; topv[i] = 0.f; }
    const float cnr = cn_sq[c0 + r];
    #pragma unroll 1
    for (int s = 0; s < 4; ++s) {
        const int n0 = nbase + s * 128;
        f32x4 acc[2][4];
        #pragma unroll
        for (int m = 0; m < 2; ++m)
            #pragma unroll
            for (int f = 0; f < 4; ++f) acc[m][f] = (f32x4){0.f, 0.f, 0.f, 0.f};
        #pragma unroll 1
        for (int k0 = 0; k0 < 768; k0 += 32) {
            __syncthreads();
            {
                float x[8];
                #pragma unroll
                for (int i = 0; i < 8; ++i)
                    x[i] = cpt[(size_t)(k0 + 8 * sw + i) * 512 + c0 + sc_];
                uint4 da = make_uint4(pack2(x[0], x[1]), pack2(x[2], x[3]),
                                      pack2(x[4], x[5]), pack2(x[6], x[7]));
                *(uint4*)(Ab + sc_ * 80 + sw * 16) = da;
            }
            #pragma unroll
            for (int j = 0; j < 2; ++j) {
                float x[8];
                #pragma unroll
                for (int i = 0; i < 8; ++i)
                    x[i] = X[(size_t)(k0 + 8 * sw + i) * 65536 + n0 + sc_ + 64 * j];
                uint4 db = make_uint4(pack2(x[0], x[1]), pack2(x[2], x[3]),
                                      pack2(x[4], x[5]), pack2(x[6], x[7]));
                *(uint4*)(Bb + (sc_ + 64 * j) * 80 + sw * 16) = db;
            }
            __syncthreads();
            short8 af0 = *(const short8*)(Ab + (wr * 32 + lc) * 80 + lg * 16);
            short8 af1 = *(const short8*)(Ab + (wr * 32 + 16 + lc) * 80 + lg * 16);
            short8 bfr[4];
            #pragma unroll
            for (int f = 0; f < 4; ++f)
                bfr[f] = *(const short8*)(Bb + (wc * 64 + f * 16 + lc) * 80 + lg * 16);
            #pragma unroll
            for (int f = 0; f < 4; ++f) {
                acc[0][f] = __builtin_amdgcn_mfma_f32_16x16x32_bf16(af0, bfr[f], acc[0][f], 0, 0, 0);
                acc[1][f] = __builtin_amdgcn_mfma_f32_16x16x32_bf16(af1, bfr[f], acc[1][f], 0, 0, 0);
            }
        }
        __syncthreads();
        #pragma unroll
        for (int m = 0; m < 2; ++m)
            #pragma unroll
            for (int f = 0; f < 4; ++f)
                #pragma unroll
                for (int i = 0; i < 4; ++i)
                    Ct[(wr * 32 + m * 16 + lg * 4 + i) * 133 + wc * 64 + f * 16 + lc] = acc[m][f][i];
        __syncthreads();
        #pragma unroll 1
        for (int u = 0; u < 32; ++u) {
            int c = u * 4 + g;
            float val = Ct[r * 133 + c];
            float dist = cnr + en[n0 + c] - 2.f * val;
            if (dist < topd[9]) {
                topd[9] = dist; topv[9] = val;
                #pragma unroll
                for (int i = 9; i > 0; --i) {
                    if (topd[i] < topd[i - 1]) {
                        float td = topd[i]; topd[i] = topd[i - 1]; topd[i - 1] = td;
                        float tv = topv[i]; topv[i] = topv[i - 1]; topv[i - 1] = tv;
                    }
                }
            }
        }
        __syncthreads();
    }
    float* ML = (float*)smem_c;
    #pragma unroll
    for (int i = 0; i < 10; ++i) {
        ML[t * 20 + 2 * i] = topd[i];
        ML[t * 20 + 2 * i + 1] = topv[i];
    }
    __syncthreads();
    if (g == 0) {
        #pragma unroll 1
        for (int o = 1; o < 4; ++o) {
            const float* L = &ML[(t + o) * 20];
            #pragma unroll 1
            for (int i = 0; i < 10; ++i) {
                float nd = L[2 * i];
                if (nd >= topd[9]) break;
                float nv = L[2 * i + 1];
                topd[9] = nd; topv[9] = nv;
                #pragma unroll
                for (int x = 9; x > 0; --x) {
                    if (topd[x] < topd[x - 1]) {
                        float td = topd[x]; topd[x] = topd[x - 1]; topd[x - 1] = td;
                        float tv = topv[x]; topv[x] = topv[x - 1]; topv[x - 1] = tv;
                    }
                }
            }
        }
        float2* dst = &cand[((size_t)(c0 + r) * 128 + blockIdx.x) * 10];
        #pragma unroll
        for (int i = 0; i < 10; ++i) dst[i] = make_float2(topd[i], topv[i]);
    }
}

// ======================= launcher =======================
extern "C" void kernel_launch(void* const* d_in, const int* in_sizes, int n_in,
                              void* d_out, int out_size, void* d_ws, size_t ws_size,
                              hipStream_t stream) {
    const float* emb = (const float*)d_in[0];   // [8192 x 768]
    const float* X   = (const float*)d_in[1];   // [768 x 65536]
    const float* cpt = (const float*)d_in[2];   // [768 x 512]
    const float* r1  = (const float*)d_in[3];   // [512 x 256]
    const float* r2  = (const float*)d_in[4];   // [256 x 768]
    float* out = (float*)d_out;
    float* ws = (float*)d_ws;
    float* S = out + 6291456;                   // prob region doubles as score scratch

    const size_t OFF_CN = 0, OFF_EN = 512, OFF_ACC = 66048, OFF_XBT = 66560;
    const size_t OFF_EMBB = 25232384, OFF_CPTB = 28378112, OFF_R1T = 28574720;
    const size_t OFF_R2T = 28640256, OFF_PRBB = 28738560, OFF_RL1B = 30835712;
    const size_t OFF_CAND = 31884288, WS_NEED = 33195008ull * 4ull;

    if (ws_size >= WS_NEED) {
        float* cn_sq = ws + OFF_CN;
        float* en    = ws + OFF_EN;
        float* acc   = ws + OFF_ACC;
        ushort* XbT  = (ushort*)(ws + OFF_XBT);
        ushort* embb = (ushort*)(ws + OFF_EMBB);
        ushort* cptb = (ushort*)(ws + OFF_CPTB);
        ushort* r1T  = (ushort*)(ws + OFF_R1T);
        ushort* r2T  = (ushort*)(ws + OFF_R2T);
        ushort* prbb = (ushort*)(ws + OFF_PRBB);
        ushort* rl1b = (ushort*)(ws + OFF_RL1B);
        float2* cand = (float2*)(ws + OFF_CAND);
        float* cptT  = ws + OFF_CAND;           // [512][768] fp32, aliases cand (used before cx writes it)

        k_zero<<<259, 256, 0, stream>>>(ws, 66056);
        k_col_sumsq<<<dim3(2, 8), 256, 0, stream>>>(cpt, cn_sq);
        k_row_stats<<<48, 256, 0, stream>>>(cpt, acc);
        k_tc<1><<<dim3(256, 24), 256, 0, stream>>>(X, XbT, en, 65536, 768);
        k_tc<0><<<dim3(2, 24), 256, 0, stream>>>(cpt, cptb, nullptr, 512, 768);
        k_tcp<<<dim3(2, 24), 256, 0, stream>>>(cpt, cptT, 512, 768);
        k_tc<0><<<dim3(1, 16), 256, 0, stream>>>(r1, r1T, nullptr, 256, 512);
        k_tc<0><<<dim3(3, 8), 256, 0, stream>>>(r2, r2T, nullptr, 768, 256);
        k_cvt_emb<<<3072, 256, 0, stream>>>(emb, embb);
        gemm_bt<1, 0, 0><<<dim3(128, 4), 256, 0, stream>>>(embb, cptb, S, nullptr, 8192, 512, 768);
        k_prob2<<<8192, 256, 0, stream>>>(emb, cptT, cn_sq, S, prbb);
        gemm_bt<0, 1, 1><<<dim3(128, 2), 256, 0, stream>>>(prbb, r1T, nullptr, rl1b, 8192, 256, 512);
        gemm_bt<1, 0, 0><<<dim3(128, 6), 256, 0, stream>>>(rl1b, r2T, out, nullptr, 8192, 768, 256);
        k_cx_topk2<<<dim3(128, 8), 256, 0, stream>>>(cptb, XbT, cn_sq, en, cand);
        k_knn_merge<1280><<<512, 256, 0, stream>>>(cand, acc);
        k_finalize<<<1, 64, 0, stream>>>(acc, out);
    } else {
        float* cn_sq = ws;
        float* en    = ws + 512;
        float* acc   = ws + 66048;
        float* rl1   = ws + 66560;
        float2* cand = (float2*)(ws + 66560 + 8192 * 256);
        k_init<<<1, 256, 0, stream>>>(cn_sq, acc);
        k_col_sumsq<<<dim3(2, 8), 256, 0, stream>>>(cpt, cn_sq);
        k_row_stats<<<48, 256, 0, stream>>>(cpt, acc);
        k_gemm<0><<<dim3(128, 4), 256, 0, stream>>>(emb, cpt, S, 8192, 512, 768);
        k_prob<<<8192, 256, 0, stream>>>(emb, cn_sq, S);
        k_gemm_bf<1><<<dim3(128, 2), 256, 0, stream>>>(S, r1, rl1, 8192, 256, 512);
        k_gemm_bf<0><<<dim3(128, 6), 256, 0, stream>>>(rl1, r2, out, 8192, 768, 256);
        k_en<<<64, 256, 0, stream>>>(X, en);
        k_cx_topk<<<dim3(128, 8), 256, 0, stream>>>(cpt, X, cn_sq, en, cand);
        k_knn_merge<1280><<<512, 256, 0, stream>>>(cand, acc);
        k_finalize<<<1, 64, 0, stream>>>(acc, out);
    }
}

// Round 14
// 298.303 us; speedup vs baseline: 1.6486x; 1.0716x over previous
//
#include <hip/hip_runtime.h>

// Problem constants: B=8192, D=768, C=512, H=256, N=65536, k=10.
// Outputs (flat): rec_layer_2 [8192*768], prob [8192*512], L1, L2.

typedef __attribute__((ext_vector_type(8))) short short8;
typedef __attribute__((ext_vector_type(4))) float f32x4;
typedef unsigned int u32;

__device__ __forceinline__ ushort f2bf(float f) {
    unsigned u = __builtin_bit_cast(unsigned, f);
    u += 0x7FFFu + ((u >> 16) & 1u);          // round-to-nearest-even
    return (ushort)(u >> 16);
}
__device__ __forceinline__ unsigned pack2(float lo, float hi) {
    return (unsigned)f2bf(lo) | ((unsigned)f2bf(hi) << 16);
}
// async global->LDS, 16B per lane; lds dest = wave-uniform base + lane*16
__device__ __forceinline__ void gll16(const void* g, void* l) {
    __builtin_amdgcn_global_load_lds((const __attribute__((address_space(1))) u32*)g,
                                     (__attribute__((address_space(3))) u32*)l, 16, 0, 0);
}

// ======================= shared small kernels =======================
__global__ void k_zero(float* p, int n) {
    int i = blockIdx.x * 256 + threadIdx.x;
    if (i < n) p[i] = 0.f;
}
__global__ void k_init(float* cn_sq, float* acc) {
    int t = threadIdx.x;
    cn_sq[t] = 0.f; cn_sq[t + 256] = 0.f;
    if (t < 8) acc[t] = 0.f;
}
__global__ void k_col_sumsq(const float* __restrict__ cpt, float* __restrict__ cn_sq) {
    int c = blockIdx.x * 256 + threadIdx.x;
    int d0 = blockIdx.y * 96;
    float s = 0.f;
    #pragma unroll 4
    for (int d = d0; d < d0 + 96; ++d) { float v = cpt[d * 512 + c]; s += v * v; }
    atomicAdd(&cn_sq[c], s);
}
__global__ void k_row_stats(const float* __restrict__ cpt, float* __restrict__ acc) {
    __shared__ float red[256];
    int t = threadIdx.x;
    int d = blockIdx.x * 16;
    float rowsq = 0.f, tot = 0.f;
    for (int r = 0; r < 16; ++r, ++d) {
        float v1 = cpt[d * 512 + t], v2 = cpt[d * 512 + 256 + t];
        tot += v1 * v1 + v2 * v2;
        red[t] = v1 + v2;
        __syncthreads();
        for (int st = 128; st > 0; st >>= 1) {
            if (t < st) red[t] += red[t + st];
            __syncthreads();
        }
        if (t == 0) rowsq += red[0] * red[0];
        __syncthreads();
    }
    red[t] = tot; __syncthreads();
    for (int st = 128; st > 0; st >>= 1) {
        if (t < st) red[t] += red[t + st];
        __syncthreads();
    }
    if (t == 0) { atomicAdd(&acc[1], rowsq); atomicAdd(&acc[2], red[0]); }
}

// fallback-path merge: float2 candidates
template <int NB>
__global__ __launch_bounds__(256) void k_knn_merge(const float2* __restrict__ cand,
                                                   float* __restrict__ acc) {
    __shared__ float2 buf[NB];
    __shared__ float2 l2[160];
    int c = blockIdx.x, t = threadIdx.x;
    const float FINF = __builtin_inff();
    const float2* src = &cand[(size_t)c * NB];
    for (int i = t; i < NB; i += 256) buf[i] = src[i];
    __syncthreads();
    if (t < 16) {
        float td[10], tv[10];
        #pragma unroll
        for (int i = 0; i < 10; ++i) { td[i] = FINF; tv[i] = 0.f; }
        const int per = NB / 16;
        for (int j = t * per; j < t * per + per; ++j) {
            float nd = buf[j].x;
            if (nd < td[9]) {
                td[9] = nd; tv[9] = buf[j].y;
                #pragma unroll
                for (int x = 9; x > 0; --x)
                    if (td[x] < td[x - 1]) {
                        float a = td[x]; td[x] = td[x - 1]; td[x - 1] = a;
                        float b = tv[x]; tv[x] = tv[x - 1]; tv[x - 1] = b;
                    }
            }
        }
        #pragma unroll
        for (int i = 0; i < 10; ++i) l2[t * 10 + i] = make_float2(td[i], tv[i]);
    }
    __syncthreads();
    if (t == 0) {
        float td[10], tv[10];
        #pragma unroll
        for (int i = 0; i < 10; ++i) { td[i] = FINF; tv[i] = 0.f; }
        for (int j = 0; j < 160; ++j) {
            float nd = l2[j].x;
            if (nd < td[9]) {
                td[9] = nd; tv[9] = l2[j].y;
                #pragma unroll
                for (int x = 9; x > 0; --x)
                    if (td[x] < td[x - 1]) {
                        float a = td[x]; td[x] = td[x - 1]; td[x - 1] = a;
                        float b = tv[x]; tv[x] = tv[x - 1]; tv[x - 1] = b;
                    }
            }
        }
        float s = 0.f;
        #pragma unroll
        for (int i = 0; i < 10; ++i) s += tv[i];
        atomicAdd(&acc[0], s);
    }
}

// fast-path merge: u32 packed keys (dist-bits | 9-bit local col); val recovered by algebra
template <int NB>
__global__ __launch_bounds__(256) void k_knn_merge_keys(const u32* __restrict__ cand,
                                                        const float* __restrict__ cn_sq,
                                                        const float* __restrict__ en,
                                                        float* __restrict__ acc) {
    __shared__ float2 buf[NB];
    __shared__ float2 l2[160];
    int c = blockIdx.x, t = threadIdx.x;
    const float FINF = __builtin_inff();
    const float cnr = cn_sq[c];
    const u32* src = &cand[(size_t)c * NB];
    for (int i = t; i < NB; i += 256) {
        u32 k = src[i];
        int bx = i / 10;
        int gcol = bx * 512 + (int)(k & 511u);
        float dist = __builtin_bit_cast(float, k & 0xFFFFFE00u);
        float val = 0.5f * (cnr + en[gcol] - dist);
        buf[i] = make_float2(dist, val);
    }
    __syncthreads();
    if (t < 16) {
        float td[10], tv[10];
        #pragma unroll
        for (int i = 0; i < 10; ++i) { td[i] = FINF; tv[i] = 0.f; }
        const int per = NB / 16;
        for (int j = t * per; j < t * per + per; ++j) {
            float nd = buf[j].x;
            if (nd < td[9]) {
                td[9] = nd; tv[9] = buf[j].y;
                #pragma unroll
                for (int x = 9; x > 0; --x)
                    if (td[x] < td[x - 1]) {
                        float a = td[x]; td[x] = td[x - 1]; td[x - 1] = a;
                        float b = tv[x]; tv[x] = tv[x - 1]; tv[x - 1] = b;
                    }
            }
        }
        #pragma unroll
        for (int i = 0; i < 10; ++i) l2[t * 10 + i] = make_float2(td[i], tv[i]);
    }
    __syncthreads();
    if (t == 0) {
        float td[10], tv[10];
        #pragma unroll
        for (int i = 0; i < 10; ++i) { td[i] = FINF; tv[i] = 0.f; }
        for (int j = 0; j < 160; ++j) {
            float nd = l2[j].x;
            if (nd < td[9]) {
                td[9] = nd; tv[9] = l2[j].y;
                #pragma unroll
                for (int x = 9; x > 0; --x)
                    if (td[x] < td[x - 1]) {
                        float a = td[x]; td[x] = td[x - 1]; td[x - 1] = a;
                        float b = tv[x]; tv[x] = tv[x - 1]; tv[x - 1] = b;
                    }
            }
        }
        float s = 0.f;
        #pragma unroll
        for (int i = 0; i < 10; ++i) s += tv[i];
        atomicAdd(&acc[0], s);
    }
}
__global__ void k_finalize(const float* __restrict__ acc, float* __restrict__ out) {
    if (threadIdx.x == 0) {
        out[10485760] = acc[0] / 5120.0f;
        out[10485761] = (acc[1] - acc[2]) / 262144.0f;
    }
}

// ======================= FAST PATH =======================
template <int EN>
__global__ __launch_bounds__(256) void k_tc(const float* __restrict__ src,
                                            ushort* __restrict__ dst,
                                            float* __restrict__ en,
                                            int Ncols, int D) {
    __shared__ float tile[32][256];
    const int t = threadIdx.x;
    const int n0 = blockIdx.x * 256;
    const int d0 = blockIdx.y * 32;
    float s = 0.f;
    #pragma unroll 8
    for (int dd = 0; dd < 32; ++dd) {
        float v = src[(size_t)(d0 + dd) * Ncols + n0 + t];
        tile[dd][t] = v;
        if (EN) s += v * v;
    }
    if (EN) atomicAdd(&en[n0 + t], s);
    __syncthreads();
    ushort* drow = dst + (size_t)(n0 + t) * D + d0;
    #pragma unroll
    for (int q = 0; q < 4; ++q) {
        uint4 d4;
        d4.x = pack2(tile[q * 8 + 0][t], tile[q * 8 + 1][t]);
        d4.y = pack2(tile[q * 8 + 2][t], tile[q * 8 + 3][t]);
        d4.z = pack2(tile[q * 8 + 4][t], tile[q * 8 + 5][t]);
        d4.w = pack2(tile[q * 8 + 6][t], tile[q * 8 + 7][t]);
        *(uint4*)(drow + q * 8) = d4;
    }
}

// fp32 transpose: src [D][Ncols] -> dst [Ncols][D]
__global__ __launch_bounds__(256) void k_tcp(const float* __restrict__ src,
                                             float* __restrict__ dst,
                                             int Ncols, int D) {
    __shared__ float tile[32][257];
    const int t = threadIdx.x;
    const int n0 = blockIdx.x * 256;
    const int d0 = blockIdx.y * 32;
    #pragma unroll 8
    for (int dd = 0; dd < 32; ++dd)
        tile[dd][t] = src[(size_t)(d0 + dd) * Ncols + n0 + t];
    __syncthreads();
    float* drow = dst + (size_t)(n0 + t) * D + d0;
    #pragma unroll
    for (int q = 0; q < 8; ++q) {
        float4 d4 = make_float4(tile[q * 4 + 0][t], tile[q * 4 + 1][t],
                                tile[q * 4 + 2][t], tile[q * 4 + 3][t]);
        *(float4*)(drow + q * 4) = d4;
    }
}

__global__ void k_cvt_emb(const float* __restrict__ src, ushort* __restrict__ dst) {
    int i = (blockIdx.x * 256 + threadIdx.x) * 8;
    float4 a = *(const float4*)&src[i], b = *(const float4*)&src[i + 4];
    uint4 d4 = make_uint4(pack2(a.x, a.y), pack2(a.z, a.w), pack2(b.x, b.y), pack2(b.z, b.w));
    *(uint4*)&dst[i] = d4;
}

// C = A[MxK] @ B[NxK]^T, bf16 in, gload_lds staging, tile 64x128, BK=64.
template <int WF32, int WB16, int RELU>
__global__ __launch_bounds__(256, 4) void gemm_bt(const ushort* __restrict__ A,
                                                  const ushort* __restrict__ B,
                                                  float* __restrict__ C,
                                                  ushort* __restrict__ Cb,
                                                  int M, int N, int K) {
    __shared__ __align__(16) char smem[24576];
    char* Ab = smem;              // [64 rows][128 B]
    char* Bb = smem + 8192;       // [128 rows][128 B]
    const int t = threadIdx.x;
    const int l = t & 63, w = t >> 6;
    const int wr = w >> 1, wc = w & 1;
    const int lg = l >> 4, lc = l & 15;
    const int m0 = blockIdx.x * 64, n0 = blockIdx.y * 128;
    const int sr8 = l >> 3, oct = l & 7;
    const int arw0 = 16 * w + sr8, arw1 = arw0 + 8;
    const ushort* ga0 = A + (size_t)(m0 + arw0) * K + (oct ^ (arw0 & 7)) * 8;
    const ushort* ga1 = A + (size_t)(m0 + arw1) * K + (oct ^ (arw1 & 7)) * 8;
    char* la0 = Ab + w * 2048;
    char* la1 = Ab + w * 2048 + 1024;
    const int brw0 = 32 * w + sr8, brw1 = brw0 + 8, brw2 = brw0 + 16, brw3 = brw0 + 24;
    const ushort* gb0 = B + (size_t)(n0 + brw0) * K + (oct ^ (brw0 & 7)) * 8;
    const ushort* gb1 = B + (size_t)(n0 + brw1) * K + (oct ^ (brw1 & 7)) * 8;
    const ushort* gb2 = B + (size_t)(n0 + brw2) * K + (oct ^ (brw2 & 7)) * 8;
    const ushort* gb3 = B + (size_t)(n0 + brw3) * K + (oct ^ (brw3 & 7)) * 8;
    char* lb0 = Bb + w * 4096;
    char* lb1 = Bb + w * 4096 + 1024;
    char* lb2 = Bb + w * 4096 + 2048;
    char* lb3 = Bb + w * 4096 + 3072;
    const int ar0 = wr * 32 + lc, ar1 = ar0 + 16;
    int aoff[2][2], boff[2][4];
    #pragma unroll
    for (int kk = 0; kk < 2; ++kk) {
        aoff[kk][0] = ar0 * 128 + (((kk * 4 + lg) ^ (ar0 & 7)) * 16);
        aoff[kk][1] = ar1 * 128 + (((kk * 4 + lg) ^ (ar1 & 7)) * 16);
        #pragma unroll
        for (int f = 0; f < 4; ++f) {
            int bc = wc * 64 + f * 16 + lc;
            boff[kk][f] = bc * 128 + (((kk * 4 + lg) ^ (bc & 7)) * 16);
        }
    }
    f32x4 acc[2][4];
    #pragma unroll
    for (int m = 0; m < 2; ++m)
        #pragma unroll
        for (int f = 0; f < 4; ++f) acc[m][f] = (f32x4){0.f, 0.f, 0.f, 0.f};

    #pragma unroll 1
    for (int k0 = 0; k0 < K; k0 += 64) {
        __syncthreads();
        gll16(ga0 + k0, la0); gll16(ga1 + k0, la1);
        gll16(gb0 + k0, lb0); gll16(gb1 + k0, lb1);
        gll16(gb2 + k0, lb2); gll16(gb3 + k0, lb3);
        __syncthreads();
        #pragma unroll
        for (int kk = 0; kk < 2; ++kk) {
            short8 a0 = *(const short8*)(Ab + aoff[kk][0]);
            short8 a1 = *(const short8*)(Ab + aoff[kk][1]);
            short8 bfr[4];
            #pragma unroll
            for (int f = 0; f < 4; ++f) bfr[f] = *(const short8*)(Bb + boff[kk][f]);
            #pragma unroll
            for (int f = 0; f < 4; ++f) {
                acc[0][f] = __builtin_amdgcn_mfma_f32_16x16x32_bf16(a0, bfr[f], acc[0][f], 0, 0, 0);
                acc[1][f] = __builtin_amdgcn_mfma_f32_16x16x32_bf16(a1, bfr[f], acc[1][f], 0, 0, 0);
            }
        }
    }
    #pragma unroll
    for (int m = 0; m < 2; ++m)
        #pragma unroll
        for (int f = 0; f < 4; ++f)
            #pragma unroll
            for (int i = 0; i < 4; ++i) {
                int row = m0 + wr * 32 + m * 16 + lg * 4 + i;
                int col = n0 + wc * 64 + f * 16 + lc;
                float v = acc[m][f][i];
                if (RELU) v = fmaxf(v, 0.f);
                if (WF32) C[(size_t)row * N + col] = v;
                if (WB16) Cb[(size_t)row * N + col] = f2bf(v);
            }
}

// prob epilogue with exact fp32 fixup; cptT [512][768] gives coalesced dots
__global__ __launch_bounds__(256) void k_prob2(const float* __restrict__ emb,
                                               const float* __restrict__ cptT,
                                               const float* __restrict__ cn_sq,
                                               float* __restrict__ S,
                                               ushort* __restrict__ probb) {
    __shared__ float erow[768];
    __shared__ float sval[512];
    __shared__ int idxl[512];
    __shared__ int cnt;
    __shared__ float redw[4];
    const int b = blockIdx.x, t = threadIdx.x;
    const int l = t & 63, w = t >> 6;
    if (t == 0) cnt = 0;
    float s = 0.f;
    #pragma unroll
    for (int j = 0; j < 3; ++j) {
        float v = emb[(size_t)b * 768 + t + j * 256];
        erow[t + j * 256] = v; s += v * v;
    }
    #pragma unroll
    for (int o = 32; o > 0; o >>= 1) s += __shfl_down(s, o);
    if (l == 0) redw[w] = s;
    __syncthreads();
    const float rn = fmaxf(sqrtf(redw[0] + redw[1] + redw[2] + redw[3]), 1e-12f);
    #pragma unroll
    for (int j = 0; j < 2; ++j) {
        int c = t + j * 256;
        sval[c] = 0.f;
        float cn = fmaxf(sqrtf(cn_sq[c]), 1e-12f);
        float sn = S[(size_t)b * 512 + c] / (rn * cn);
        if (sn > 0.1f - 4e-3f) { int p = atomicAdd(&cnt, 1); idxl[p] = c; }
    }
    __syncthreads();
    const int nf = cnt;
    for (int q0 = 0; q0 < nf; q0 += 4) {
        int q = q0 + w;
        if (q < nf) {
            int c = idxl[q];
            const float* cr = cptT + (size_t)c * 768;
            float p = 0.f;
            #pragma unroll
            for (int ii = 0; ii < 3; ++ii) {
                int d = l * 4 + ii * 256;
                float4 e4 = *(const float4*)&erow[d];
                float4 x4 = *(const float4*)&cr[d];
                p += e4.x * x4.x + e4.y * x4.y + e4.z * x4.z + e4.w * x4.w;
            }
            #pragma unroll
            for (int o = 32; o > 0; o >>= 1) p += __shfl_down(p, o);
            if (l == 0) {
                float cn = fmaxf(sqrtf(cn_sq[c]), 1e-12f);
                sval[c] = (p / (rn * cn) > 0.1f) ? p : 0.f;
            }
        }
    }
    __syncthreads();
    float s2 = sval[t] + sval[t + 256];
    #pragma unroll
    for (int o = 32; o > 0; o >>= 1) s2 += __shfl_down(s2, o);
    if (l == 0) redw[w] = s2;
    __syncthreads();
    const float denom = redw[0] + redw[1] + redw[2] + redw[3] + 0.001f;
    #pragma unroll
    for (int j = 0; j < 2; ++j) {
        int c = t + j * 256;
        float pr = sval[c] / denom;
        S[(size_t)b * 512 + c] = pr;
        probb[(size_t)b * 512 + c] = f2bf(pr);
    }
}

// cx GEMM (bf16, gload_lds, BK=64) + fused per-block top-10 via packed u32 keys.
// key = (bits(dist) & ~0x1FF) | local_col(9b); dist>0 so uint order == float order.
__global__ __launch_bounds__(256, 4) void k_cx_topk2(const ushort* __restrict__ cptb, // [512][768]
                                                     const ushort* __restrict__ XbT,  // [65536][768]
                                                     const float* __restrict__ cn_sq,
                                                     const float* __restrict__ en,
                                                     u32* __restrict__ cand) {
    __shared__ __align__(16) char smem[34048];
    char* Ab = smem;              // [64][128B]
    char* Bb = smem + 8192;       // [128][128B]
    float* Ct = (float*)smem;     // [64][132] f32 (33792 B) aliased

    const int t = threadIdx.x;
    const int l = t & 63, w = t >> 6;
    const int wr = w >> 1, wc = w & 1;
    const int lg = l >> 4, lc = l & 15;
    const int c0 = blockIdx.y * 64;
    const int nbase = blockIdx.x * 512;

    const int sr8 = l >> 3, oct = l & 7;
    const int arw0 = 16 * w + sr8, arw1 = arw0 + 8;
    const ushort* ga0 = cptb + (size_t)(c0 + arw0) * 768 + (oct ^ (arw0 & 7)) * 8;
    const ushort* ga1 = cptb + (size_t)(c0 + arw1) * 768 + (oct ^ (arw1 & 7)) * 8;
    char* la0 = Ab + w * 2048;
    char* la1 = Ab + w * 2048 + 1024;
    const int brw0 = 32 * w + sr8, brw1 = brw0 + 8, brw2 = brw0 + 16, brw3 = brw0 + 24;
    const int bs0 = (oct ^ (brw0 & 7)) * 8, bs1 = (oct ^ (brw1 & 7)) * 8;
    const int bs2 = (oct ^ (brw2 & 7)) * 8, bs3 = (oct ^ (brw3 & 7)) * 8;
    char* lb0 = Bb + w * 4096;
    char* lb1 = Bb + w * 4096 + 1024;
    char* lb2 = Bb + w * 4096 + 2048;
    char* lb3 = Bb + w * 4096 + 3072;

    const int ar0 = wr * 32 + lc, ar1 = ar0 + 16;
    int aoff[2][2], boff[2][4];
    #pragma unroll
    for (int kk = 0; kk < 2; ++kk) {
        aoff[kk][0] = ar0 * 128 + (((kk * 4 + lg) ^ (ar0 & 7)) * 16);
        aoff[kk][1] = ar1 * 128 + (((kk * 4 + lg) ^ (ar1 & 7)) * 16);
        #pragma unroll
        for (int f = 0; f < 4; ++f) {
            int bc = wc * 64 + f * 16 + lc;
            boff[kk][f] = bc * 128 + (((kk * 4 + lg) ^ (bc & 7)) * 16);
        }
    }

    const int r = t >> 2, g = t & 3;
    u32 topk[10];
    #pragma unroll
    for (int i = 0; i < 10; ++i) topk[i] = 0xFFFFFFFFu;
    const float cnr = cn_sq[c0 + r];

    auto insk = [&](u32 k) {
        if (k < topk[9]) {
            topk[9] = k;
            #pragma unroll
            for (int x = 9; x > 0; --x) {
                u32 a = topk[x - 1], b = topk[x];
                u32 lo = a < b ? a : b;
                u32 hi = a < b ? b : a;
                topk[x - 1] = lo; topk[x] = hi;
            }
        }
    };

    #pragma unroll 1
    for (int s = 0; s < 4; ++s) {
        const int n0 = nbase + s * 128;
        const ushort* gb0 = XbT + (size_t)(n0 + brw0) * 768 + bs0;
        const ushort* gb1 = XbT + (size_t)(n0 + brw1) * 768 + bs1;
        const ushort* gb2 = XbT + (size_t)(n0 + brw2) * 768 + bs2;
        const ushort* gb3 = XbT + (size_t)(n0 + brw3) * 768 + bs3;
        f32x4 acc[2][4];
        #pragma unroll
        for (int m = 0; m < 2; ++m)
            #pragma unroll
            for (int f = 0; f < 4; ++f) acc[m][f] = (f32x4){0.f, 0.f, 0.f, 0.f};

        #pragma unroll 1
        for (int k0 = 0; k0 < 768; k0 += 64) {
            __syncthreads();
            gll16(ga0 + k0, la0); gll16(ga1 + k0, la1);
            gll16(gb0 + k0, lb0); gll16(gb1 + k0, lb1);
            gll16(gb2 + k0, lb2); gll16(gb3 + k0, lb3);
            __syncthreads();
            #pragma unroll
            for (int kk = 0; kk < 2; ++kk) {
                short8 a0 = *(const short8*)(Ab + aoff[kk][0]);
                short8 a1 = *(const short8*)(Ab + aoff[kk][1]);
                short8 bfr[4];
                #pragma unroll
                for (int f = 0; f < 4; ++f) bfr[f] = *(const short8*)(Bb + boff[kk][f]);
                #pragma unroll
                for (int f = 0; f < 4; ++f) {
                    acc[0][f] = __builtin_amdgcn_mfma_f32_16x16x32_bf16(a0, bfr[f], acc[0][f], 0, 0, 0);
                    acc[1][f] = __builtin_amdgcn_mfma_f32_16x16x32_bf16(a1, bfr[f], acc[1][f], 0, 0, 0);
                }
            }
        }
        __syncthreads();
        // ---- write C tile (C/D map: col = lane&15, row = (lane>>4)*4 + reg)
        #pragma unroll
        for (int m = 0; m < 2; ++m)
            #pragma unroll
            for (int f = 0; f < 4; ++f)
                #pragma unroll
                for (int i = 0; i < 4; ++i)
                    Ct[(wr * 32 + m * 16 + lg * 4 + i) * 132 + wc * 64 + f * 16 + lc] = acc[m][f][i];
        __syncthreads();
        // ---- scan: thread (r,g) covers cols c = g*4 + 16u; pack keys
        #pragma unroll
        for (int u = 0; u < 8; ++u) {
            int c = g * 4 + u * 16;
            float4 v4 = *(const float4*)&Ct[r * 132 + c];
            float4 e4 = *(const float4*)&en[n0 + c];
            u32 base = (u32)(s * 128 + c);
            float d0 = cnr + e4.x - 2.f * v4.x;
            float d1 = cnr + e4.y - 2.f * v4.y;
            float d2 = cnr + e4.z - 2.f * v4.z;
            float d3 = cnr + e4.w - 2.f * v4.w;
            insk((__builtin_bit_cast(u32, d0) & 0xFFFFFE00u) | (base + 0));
            insk((__builtin_bit_cast(u32, d1) & 0xFFFFFE00u) | (base + 1));
            insk((__builtin_bit_cast(u32, d2) & 0xFFFFFE00u) | (base + 2));
            insk((__builtin_bit_cast(u32, d3) & 0xFFFFFE00u) | (base + 3));
        }
        __syncthreads();
    }
    // ---- merge 4 per-thread lists per row via LDS (u32 keys)
    u32* ML = (u32*)smem;
    #pragma unroll
    for (int i = 0; i < 10; ++i) ML[t * 10 + i] = topk[i];
    __syncthreads();
    if (g == 0) {
        #pragma unroll 1
        for (int o = 1; o < 4; ++o) {
            const u32* L = &ML[(t + o) * 10];
            #pragma unroll 1
            for (int i = 0; i < 10; ++i) {
                u32 nk = L[i];
                if (nk >= topk[9]) break;          // lists sorted ascending
                topk[9] = nk;
                #pragma unroll
                for (int x = 9; x > 0; --x) {
                    u32 a = topk[x - 1], b = topk[x];
                    u32 lo = a < b ? a : b;
                    u32 hi = a < b ? b : a;
                    topk[x - 1] = lo; topk[x] = hi;
                }
            }
        }
        u32* dst = &cand[((size_t)(c0 + r) * 128 + blockIdx.x) * 10];
        #pragma unroll
        for (int i = 0; i < 10; ++i) dst[i] = topk[i];
    }
}

// ======================= FALLBACK PATH (round-3, proven) =======================
template <int RELU>
__global__ __launch_bounds__(256) void k_gemm(const float* __restrict__ A,
                                              const float* __restrict__ Bm,
                                              float* __restrict__ Cm,
                                              int M, int N, int K) {
    __shared__ float As[16][68];
    __shared__ float Bs[16][128];
    const int t = threadIdx.x;
    const int m0 = blockIdx.x * 64, n0 = blockIdx.y * 128;
    const int tm = t >> 4, tn = t & 15;
    float acc[4][8] = {};
    #pragma unroll 1
    for (int k0 = 0; k0 < K; k0 += 16) {
        {
            int i = t >> 2, kk4 = (t & 3) * 4;
            float4 av = *(const float4*)&A[(size_t)(m0 + i) * K + k0 + kk4];
            As[kk4 + 0][i] = av.x; As[kk4 + 1][i] = av.y;
            As[kk4 + 2][i] = av.z; As[kk4 + 3][i] = av.w;
        }
        {
            int kk = t >> 5, c4 = (t & 31) * 4;
            *(float4*)&Bs[kk][c4] = *(const float4*)&Bm[(size_t)(k0 + kk) * N + n0 + c4];
            *(float4*)&Bs[kk + 8][c4] = *(const float4*)&Bm[(size_t)(k0 + kk + 8) * N + n0 + c4];
        }
        __syncthreads();
        #pragma unroll
        for (int k = 0; k < 16; ++k) {
            float4 a4 = *(const float4*)&As[k][tm * 4];
            float4 b0 = *(const float4*)&Bs[k][tn * 4];
            float4 b1 = *(const float4*)&Bs[k][64 + tn * 4];
            float av[4] = {a4.x, a4.y, a4.z, a4.w};
            float bv[8] = {b0.x, b0.y, b0.z, b0.w, b1.x, b1.y, b1.z, b1.w};
            #pragma unroll
            for (int i = 0; i < 4; ++i)
                #pragma unroll
                for (int j = 0; j < 8; ++j) acc[i][j] += av[i] * bv[j];
        }
        __syncthreads();
    }
    #pragma unroll
    for (int i = 0; i < 4; ++i) {
        int row = m0 + tm * 4 + i;
        float4 o0 = make_float4(acc[i][0], acc[i][1], acc[i][2], acc[i][3]);
        float4 o1 = make_float4(acc[i][4], acc[i][5], acc[i][6], acc[i][7]);
        if (RELU) {
            o0.x = fmaxf(o0.x, 0.f); o0.y = fmaxf(o0.y, 0.f);
            o0.z = fmaxf(o0.z, 0.f); o0.w = fmaxf(o0.w, 0.f);
            o1.x = fmaxf(o1.x, 0.f); o1.y = fmaxf(o1.y, 0.f);
            o1.z = fmaxf(o1.z, 0.f); o1.w = fmaxf(o1.w, 0.f);
        }
        *(float4*)&Cm[(size_t)row * N + n0 + tn * 4] = o0;
        *(float4*)&Cm[(size_t)row * N + n0 + 64 + tn * 4] = o1;
    }
}

template <int RELU>
__global__ __launch_bounds__(256) void k_gemm_bf(const float* __restrict__ A,
                                                 const float* __restrict__ Bm,
                                                 float* __restrict__ Cm,
                                                 int M, int N, int K) {
    __shared__ __align__(16) char smem[15360];
    char* Ab = smem;
    char* Bb = smem + 5120;
    const int t = threadIdx.x;
    const int l = t & 63, w = t >> 6;
    const int wr = w >> 1, wc = w & 1;
    const int lg = l >> 4, lc = l & 15;
    const int m0 = blockIdx.x * 64, n0 = blockIdx.y * 128;
    const int ar = t >> 2, ak = (t & 3) * 8;
    const int bc = t & 63, bw = t >> 6;
    f32x4 acc[2][4];
    #pragma unroll
    for (int m = 0; m < 2; ++m)
        #pragma unroll
        for (int f = 0; f < 4; ++f) acc[m][f] = (f32x4){0.f, 0.f, 0.f, 0.f};
    #pragma unroll 1
    for (int k0 = 0; k0 < K; k0 += 32) {
        __syncthreads();
        {
            const float* p = &A[(size_t)(m0 + ar) * K + k0 + ak];
            float4 a0 = *(const float4*)p;
            float4 a1 = *(const float4*)(p + 4);
            uint4 da = make_uint4(pack2(a0.x, a0.y), pack2(a0.z, a0.w),
                                  pack2(a1.x, a1.y), pack2(a1.z, a1.w));
            *(uint4*)(Ab + ar * 80 + (t & 3) * 16) = da;
        }
        #pragma unroll
        for (int j = 0; j < 2; ++j) {
            float x[8];
            #pragma unroll
            for (int i = 0; i < 8; ++i)
                x[i] = Bm[(size_t)(k0 + 8 * bw + i) * N + n0 + bc + 64 * j];
            uint4 db = make_uint4(pack2(x[0], x[1]), pack2(x[2], x[3]),
                                  pack2(x[4], x[5]), pack2(x[6], x[7]));
            *(uint4*)(Bb + (bc + 64 * j) * 80 + bw * 16) = db;
        }
        __syncthreads();
        short8 af0 = *(const short8*)(Ab + (wr * 32 + lc) * 80 + lg * 16);
        short8 af1 = *(const short8*)(Ab + (wr * 32 + 16 + lc) * 80 + lg * 16);
        short8 bfr[4];
        #pragma unroll
        for (int f = 0; f < 4; ++f)
            bfr[f] = *(const short8*)(Bb + (wc * 64 + f * 16 + lc) * 80 + lg * 16);
        #pragma unroll
        for (int f = 0; f < 4; ++f) {
            acc[0][f] = __builtin_amdgcn_mfma_f32_16x16x32_bf16(af0, bfr[f], acc[0][f], 0, 0, 0);
            acc[1][f] = __builtin_amdgcn_mfma_f32_16x16x32_bf16(af1, bfr[f], acc[1][f], 0, 0, 0);
        }
    }
    #pragma unroll
    for (int m = 0; m < 2; ++m)
        #pragma unroll
        for (int f = 0; f < 4; ++f)
            #pragma unroll
            for (int i = 0; i < 4; ++i) {
                int row = m0 + wr * 32 + m * 16 + lg * 4 + i;
                int col = n0 + wc * 64 + f * 16 + lc;
                float v = acc[m][f][i];
                if (RELU) v = fmaxf(v, 0.f);
                Cm[(size_t)row * N + col] = v;
            }
}

__global__ __launch_bounds__(256) void k_prob(const float* __restrict__ emb,
                                              const float* __restrict__ cn_sq,
                                              float* __restrict__ S) {
    __shared__ float red[256];
    int b = blockIdx.x, t = threadIdx.x;
    float s = 0.f;
    #pragma unroll
    for (int j = 0; j < 3; ++j) { float v = emb[(size_t)b * 768 + t + j * 256]; s += v * v; }
    red[t] = s; __syncthreads();
    for (int st = 128; st > 0; st >>= 1) { if (t < st) red[t] += red[t + st]; __syncthreads(); }
    float rn = fmaxf(sqrtf(red[0]), 1e-12f);
    __syncthreads();
    float vals[2]; float sum = 0.f;
    #pragma unroll
    for (int j = 0; j < 2; ++j) {
        int cc = t + j * 256;
        float sc = S[(size_t)b * 512 + cc];
        float cn = fmaxf(sqrtf(cn_sq[cc]), 1e-12f);
        float v = (sc / (rn * cn) > 0.1f) ? sc : 0.f;
        vals[j] = v; sum += v;
    }
    red[t] = sum; __syncthreads();
    for (int st = 128; st > 0; st >>= 1) { if (t < st) red[t] += red[t + st]; __syncthreads(); }
    float denom = red[0] + 0.001f;
    #pragma unroll
    for (int j = 0; j < 2; ++j) S[(size_t)b * 512 + (t + j * 256)] = vals[j] / denom;
}

__global__ void k_en(const float* __restrict__ X, float* __restrict__ en) {
    int n4 = blockIdx.x * 256 + threadIdx.x;
    float4 s = make_float4(0.f, 0.f, 0.f, 0.f);
    #pragma unroll 4
    for (int d = 0; d < 768; ++d) {
        float4 v = *(const float4*)&X[(size_t)d * 65536 + n4 * 4];
        s.x += v.x * v.x; s.y += v.y * v.y; s.z += v.z * v.z; s.w += v.w * v.w;
    }
    *(float4*)&en[n4 * 4] = s;
}

__global__ __launch_bounds__(256, 4) void k_cx_topk(const float* __restrict__ cpt,
                                                    const float* __restrict__ X,
                                                    const float* __restrict__ cn_sq,
                                                    const float* __restrict__ en,
                                                    float2* __restrict__ cand) {
    __shared__ __align__(16) char smem_c[34048];
    float* Ct = (float*)smem_c;
    char* Ab = smem_c;
    char* Bb = smem_c + 5120;
    const int t = threadIdx.x;
    const int l = t & 63, w = t >> 6;
    const int wr = w >> 1, wc = w & 1;
    const int lg = l >> 4, lc = l & 15;
    const int c0 = blockIdx.y * 64;
    const int nbase = blockIdx.x * 512;
    const float FINF = __builtin_inff();
    const int sc_ = t & 63, sw = t >> 6;
    const int r = t >> 2, g = t & 3;
    float topd[10], topv[10];
    #pragma unroll
    for (int i = 0; i < 10; ++i) { topd[i] = FINF; topv[i] = 0.f; }
    const float cnr = cn_sq[c0 + r];
    #pragma unroll 1
    for (int s = 0; s < 4; ++s) {
        const int n0 = nbase + s * 128;
        f32x4 acc[2][4];
        #pragma unroll
        for (int m = 0; m < 2; ++m)
            #pragma unroll
            for (int f = 0; f < 4; ++f) acc[m][f] = (f32x4){0.f, 0.f, 0.f, 0.f};
        #pragma unroll 1
        for (int k0 = 0; k0 < 768; k0 += 32) {
            __syncthreads();
            {
                float x[8];
                #pragma unroll
                for (int i = 0; i < 8; ++i)
                    x[i] = cpt[(size_t)(k0 + 8 * sw + i) * 512 + c0 + sc_];
                uint4 da = make_uint4(pack2(x[0], x[1]), pack2(x[2], x[3]),
                                      pack2(x[4], x[5]), pack2(x[6], x[7]));
                *(uint4*)(Ab + sc_ * 80 + sw * 16) = da;
            }
            #pragma unroll
            for (int j = 0; j < 2; ++j) {
                float x[8];
                #pragma unroll
                for (int i = 0; i < 8; ++i)
                    x[i] = X[(size_t)(k0 + 8 * sw + i) * 65536 + n0 + sc_ + 64 * j];
                uint4 db = make_uint4(pack2(x[0], x[1]), pack2(x[2], x[3]),
                                      pack2(x[4], x[5]), pack2(x[6], x[7]));
                *(uint4*)(Bb + (sc_ + 64 * j) * 80 + sw * 16) = db;
            }
            __syncthreads();
            short8 af0 = *(const short8*)(Ab + (wr * 32 + lc) * 80 + lg * 16);
            short8 af1 = *(const short8*)(Ab + (wr * 32 + 16 + lc) * 80 + lg * 16);
            short8 bfr[4];
            #pragma unroll
            for (int f = 0; f < 4; ++f)
                bfr[f] = *(const short8*)(Bb + (wc * 64 + f * 16 + lc) * 80 + lg * 16);
            #pragma unroll
            for (int f = 0; f < 4; ++f) {
                acc[0][f] = __builtin_amdgcn_mfma_f32_16x16x32_bf16(af0, bfr[f], acc[0][f], 0, 0, 0);
                acc[1][f] = __builtin_amdgcn_mfma_f32_16x16x32_bf16(af1, bfr[f], acc[1][f], 0, 0, 0);
            }
        }
        __syncthreads();
        #pragma unroll
        for (int m = 0; m < 2; ++m)
            #pragma unroll
            for (int f = 0; f < 4; ++f)
                #pragma unroll
                for (int i = 0; i < 4; ++i)
                    Ct[(wr * 32 + m * 16 + lg * 4 + i) * 133 + wc * 64 + f * 16 + lc] = acc[m][f][i];
        __syncthreads();
        #pragma unroll 1
        for (int u = 0; u < 32; ++u) {
            int c = u * 4 + g;
            float val = Ct[r * 133 + c];
            float dist = cnr + en[n0 + c] - 2.f * val;
            if (dist < topd[9]) {
                topd[9] = dist; topv[9] = val;
                #pragma unroll
                for (int i = 9; i > 0; --i) {
                    if (topd[i] < topd[i - 1]) {
                        float td = topd[i]; topd[i] = topd[i - 1]; topd[i - 1] = td;
                        float tv = topv[i]; topv[i] = topv[i - 1]; topv[i - 1] = tv;
                    }
                }
            }
        }
        __syncthreads();
    }
    float* ML = (float*)smem_c;
    #pragma unroll
    for (int i = 0; i < 10; ++i) {
        ML[t * 20 + 2 * i] = topd[i];
        ML[t * 20 + 2 * i + 1] = topv[i];
    }
    __syncthreads();
    if (g == 0) {
        #pragma unroll 1
        for (int o = 1; o < 4; ++o) {
            const float* L = &ML[(t + o) * 20];
            #pragma unroll 1
            for (int i = 0; i < 10; ++i) {
                float nd = L[2 * i];
                if (nd >= topd[9]) break;
                float nv = L[2 * i + 1];
                topd[9] = nd; topv[9] = nv;
                #pragma unroll
                for (int x = 9; x > 0; --x) {
                    if (topd[x] < topd[x - 1]) {
                        float td = topd[x]; topd[x] = topd[x - 1]; topd[x - 1] = td;
                        float tv = topv[x]; topv[x] = topv[x - 1]; topv[x - 1] = tv;
                    }
                }
            }
        }
        float2* dst = &cand[((size_t)(c0 + r) * 128 + blockIdx.x) * 10];
        #pragma unroll
        for (int i = 0; i < 10; ++i) dst[i] = make_float2(topd[i], topv[i]);
    }
}

// ======================= launcher =======================
extern "C" void kernel_launch(void* const* d_in, const int* in_sizes, int n_in,
                              void* d_out, int out_size, void* d_ws, size_t ws_size,
                              hipStream_t stream) {
    const float* emb = (const float*)d_in[0];   // [8192 x 768]
    const float* X   = (const float*)d_in[1];   // [768 x 65536]
    const float* cpt = (const float*)d_in[2];   // [768 x 512]
    const float* r1  = (const float*)d_in[3];   // [512 x 256]
    const float* r2  = (const float*)d_in[4];   // [256 x 768]
    float* out = (float*)d_out;
    float* ws = (float*)d_ws;
    float* S = out + 6291456;                   // prob region doubles as score scratch

    const size_t OFF_CN = 0, OFF_EN = 512, OFF_ACC = 66048, OFF_XBT = 66560;
    const size_t OFF_EMBB = 25232384, OFF_CPTB = 28378112, OFF_R1T = 28574720;
    const size_t OFF_R2T = 28640256, OFF_PRBB = 28738560, OFF_RL1B = 30835712;
    const size_t OFF_CAND = 31884288, WS_NEED = 33195008ull * 4ull;

    if (ws_size >= WS_NEED) {
        float* cn_sq = ws + OFF_CN;
        float* en    = ws + OFF_EN;
        float* acc   = ws + OFF_ACC;
        ushort* XbT  = (ushort*)(ws + OFF_XBT);
        ushort* embb = (ushort*)(ws + OFF_EMBB);
        ushort* cptb = (ushort*)(ws + OFF_CPTB);
        ushort* r1T  = (ushort*)(ws + OFF_R1T);
        ushort* r2T  = (ushort*)(ws + OFF_R2T);
        ushort* prbb = (ushort*)(ws + OFF_PRBB);
        ushort* rl1b = (ushort*)(ws + OFF_RL1B);
        // cand region reuse: cptT (1.5 MB) first, then u32 keys (2.6 MB) after prob2
        float* cptT  = ws + OFF_CAND;
        u32* candk   = (u32*)(ws + OFF_CAND + 524288);   // disjoint from cptT? no need; sequential use — keep disjoint anyway

        k_zero<<<259, 256, 0, stream>>>(ws, 66056);
        k_col_sumsq<<<dim3(2, 8), 256, 0, stream>>>(cpt, cn_sq);
        k_row_stats<<<48, 256, 0, stream>>>(cpt, acc);
        k_tc<1><<<dim3(256, 24), 256, 0, stream>>>(X, XbT, en, 65536, 768);
        k_tc<0><<<dim3(2, 24), 256, 0, stream>>>(cpt, cptb, nullptr, 512, 768);
        k_tcp<<<dim3(2, 24), 256, 0, stream>>>(cpt, cptT, 512, 768);
        k_tc<0><<<dim3(1, 16), 256, 0, stream>>>(r1, r1T, nullptr, 256, 512);
        k_tc<0><<<dim3(3, 8), 256, 0, stream>>>(r2, r2T, nullptr, 768, 256);
        k_cvt_emb<<<3072, 256, 0, stream>>>(emb, embb);
        gemm_bt<1, 0, 0><<<dim3(128, 4), 256, 0, stream>>>(embb, cptb, S, nullptr, 8192, 512, 768);
        k_prob2<<<8192, 256, 0, stream>>>(emb, cptT, cn_sq, S, prbb);
        gemm_bt<0, 1, 1><<<dim3(128, 2), 256, 0, stream>>>(prbb, r1T, nullptr, rl1b, 8192, 256, 512);
        gemm_bt<1, 0, 0><<<dim3(128, 6), 256, 0, stream>>>(rl1b, r2T, out, nullptr, 8192, 768, 256);
        k_cx_topk2<<<dim3(128, 8), 256, 0, stream>>>(cptb, XbT, cn_sq, en, candk);
        k_knn_merge_keys<1280><<<512, 256, 0, stream>>>(candk, cn_sq, en, acc);
        k_finalize<<<1, 64, 0, stream>>>(acc, out);
    } else {
        float* cn_sq = ws;
        float* en    = ws + 512;
        float* acc   = ws + 66048;
        float* rl1   = ws + 66560;
        float2* cand = (float2*)(ws + 66560 + 8192 * 256);
        k_init<<<1, 256, 0, stream>>>(cn_sq, acc);
        k_col_sumsq<<<dim3(2, 8), 256, 0, stream>>>(cpt, cn_sq);
        k_row_stats<<<48, 256, 0, stream>>>(cpt, acc);
        k_gemm<0><<<dim3(128, 4), 256, 0, stream>>>(emb, cpt, S, 8192, 512, 768);
        k_prob<<<8192, 256, 0, stream>>>(emb, cn_sq, S);
        k_gemm_bf<1><<<dim3(128, 2), 256, 0, stream>>>(S, r1, rl1, 8192, 256, 512);
        k_gemm_bf<0><<<dim3(128, 6), 256, 0, stream>>>(rl1, r2, out, 8192, 768, 256);
        k_en<<<64, 256, 0, stream>>>(X, en);
        k_cx_topk<<<dim3(128, 8), 256, 0, stream>>>(cpt, X, cn_sq, en, cand);
        k_knn_merge<1280><<<512, 256, 0, stream>>>(cand, acc);
        k_finalize<<<1, 64, 0, stream>>>(acc, out);
    }
}

// Round 15
// 283.238 us; speedup vs baseline: 1.7363x; 1.0532x over previous
//
#include <hip/hip_runtime.h>

// Problem constants: B=8192, D=768, C=512, H=256, N=65536, k=10.
// Outputs (flat): rec_layer_2 [8192*768], prob [8192*512], L1, L2.

typedef __attribute__((ext_vector_type(8))) short short8;
typedef __attribute__((ext_vector_type(4))) float f32x4;
typedef unsigned int u32;

__device__ __forceinline__ ushort f2bf(float f) {
    unsigned u = __builtin_bit_cast(unsigned, f);
    u += 0x7FFFu + ((u >> 16) & 1u);          // round-to-nearest-even
    return (ushort)(u >> 16);
}
__device__ __forceinline__ unsigned pack2(float lo, float hi) {
    return (unsigned)f2bf(lo) | ((unsigned)f2bf(hi) << 16);
}
// async global->LDS, 16B per lane; lds dest = wave-uniform base + lane*16
__device__ __forceinline__ void gll16(const void* g, void* l) {
    __builtin_amdgcn_global_load_lds((const __attribute__((address_space(1))) u32*)g,
                                     (__attribute__((address_space(3))) u32*)l, 16, 0, 0);
}

// ======================= shared small kernels =======================
__global__ void k_zero(float* p, int n) {
    int i = blockIdx.x * 256 + threadIdx.x;
    if (i < n) p[i] = 0.f;
}
__global__ void k_init(float* cn_sq, float* acc) {
    int t = threadIdx.x;
    cn_sq[t] = 0.f; cn_sq[t + 256] = 0.f;
    if (t < 8) acc[t] = 0.f;
}
__global__ void k_col_sumsq(const float* __restrict__ cpt, float* __restrict__ cn_sq) {
    int c = blockIdx.x * 256 + threadIdx.x;
    int d0 = blockIdx.y * 96;
    float s = 0.f;
    #pragma unroll 4
    for (int d = d0; d < d0 + 96; ++d) { float v = cpt[d * 512 + c]; s += v * v; }
    atomicAdd(&cn_sq[c], s);
}
__global__ void k_row_stats(const float* __restrict__ cpt, float* __restrict__ acc) {
    __shared__ float red[256];
    int t = threadIdx.x;
    int d = blockIdx.x * 16;
    float rowsq = 0.f, tot = 0.f;
    for (int r = 0; r < 16; ++r, ++d) {
        float v1 = cpt[d * 512 + t], v2 = cpt[d * 512 + 256 + t];
        tot += v1 * v1 + v2 * v2;
        red[t] = v1 + v2;
        __syncthreads();
        for (int st = 128; st > 0; st >>= 1) {
            if (t < st) red[t] += red[t + st];
            __syncthreads();
        }
        if (t == 0) rowsq += red[0] * red[0];
        __syncthreads();
    }
    red[t] = tot; __syncthreads();
    for (int st = 128; st > 0; st >>= 1) {
        if (t < st) red[t] += red[t + st];
        __syncthreads();
    }
    if (t == 0) { atomicAdd(&acc[1], rowsq); atomicAdd(&acc[2], red[0]); }
}

// fallback-path merge: float2 candidates
template <int NB>
__global__ __launch_bounds__(256) void k_knn_merge(const float2* __restrict__ cand,
                                                   float* __restrict__ acc) {
    __shared__ float2 buf[NB];
    __shared__ float2 l2[160];
    int c = blockIdx.x, t = threadIdx.x;
    const float FINF = __builtin_inff();
    const float2* src = &cand[(size_t)c * NB];
    for (int i = t; i < NB; i += 256) buf[i] = src[i];
    __syncthreads();
    if (t < 16) {
        float td[10], tv[10];
        #pragma unroll
        for (int i = 0; i < 10; ++i) { td[i] = FINF; tv[i] = 0.f; }
        const int per = NB / 16;
        for (int j = t * per; j < t * per + per; ++j) {
            float nd = buf[j].x;
            if (nd < td[9]) {
                td[9] = nd; tv[9] = buf[j].y;
                #pragma unroll
                for (int x = 9; x > 0; --x)
                    if (td[x] < td[x - 1]) {
                        float a = td[x]; td[x] = td[x - 1]; td[x - 1] = a;
                        float b = tv[x]; tv[x] = tv[x - 1]; tv[x - 1] = b;
                    }
            }
        }
        #pragma unroll
        for (int i = 0; i < 10; ++i) l2[t * 10 + i] = make_float2(td[i], tv[i]);
    }
    __syncthreads();
    if (t == 0) {
        float td[10], tv[10];
        #pragma unroll
        for (int i = 0; i < 10; ++i) { td[i] = FINF; tv[i] = 0.f; }
        for (int j = 0; j < 160; ++j) {
            float nd = l2[j].x;
            if (nd < td[9]) {
                td[9] = nd; tv[9] = l2[j].y;
                #pragma unroll
                for (int x = 9; x > 0; --x)
                    if (td[x] < td[x - 1]) {
                        float a = td[x]; td[x] = td[x - 1]; td[x - 1] = a;
                        float b = tv[x]; tv[x] = tv[x - 1]; tv[x - 1] = b;
                    }
            }
        }
        float s = 0.f;
        #pragma unroll
        for (int i = 0; i < 10; ++i) s += tv[i];
        atomicAdd(&acc[0], s);
    }
}

// fast-path merge: u32 packed keys (dist-bits | 9-bit local col); val recovered by algebra
template <int NB>
__global__ __launch_bounds__(256) void k_knn_merge_keys(const u32* __restrict__ cand,
                                                        const float* __restrict__ cn_sq,
                                                        const float* __restrict__ en,
                                                        float* __restrict__ acc) {
    __shared__ float2 buf[NB];
    __shared__ float2 l2[160];
    int c = blockIdx.x, t = threadIdx.x;
    const float FINF = __builtin_inff();
    const float cnr = cn_sq[c];
    const u32* src = &cand[(size_t)c * NB];
    for (int i = t; i < NB; i += 256) {
        u32 k = src[i];
        int bx = i / 10;
        int gcol = bx * 512 + (int)(k & 511u);
        float dist = __builtin_bit_cast(float, k & 0xFFFFFE00u);
        float val = 0.5f * (cnr + en[gcol] - dist);
        buf[i] = make_float2(dist, val);
    }
    __syncthreads();
    if (t < 16) {
        float td[10], tv[10];
        #pragma unroll
        for (int i = 0; i < 10; ++i) { td[i] = FINF; tv[i] = 0.f; }
        const int per = NB / 16;
        for (int j = t * per; j < t * per + per; ++j) {
            float nd = buf[j].x;
            if (nd < td[9]) {
                td[9] = nd; tv[9] = buf[j].y;
                #pragma unroll
                for (int x = 9; x > 0; --x)
                    if (td[x] < td[x - 1]) {
                        float a = td[x]; td[x] = td[x - 1]; td[x - 1] = a;
                        float b = tv[x]; tv[x] = tv[x - 1]; tv[x - 1] = b;
                    }
            }
        }
        #pragma unroll
        for (int i = 0; i < 10; ++i) l2[t * 10 + i] = make_float2(td[i], tv[i]);
    }
    __syncthreads();
    if (t == 0) {
        float td[10], tv[10];
        #pragma unroll
        for (int i = 0; i < 10; ++i) { td[i] = FINF; tv[i] = 0.f; }
        for (int j = 0; j < 160; ++j) {
            float nd = l2[j].x;
            if (nd < td[9]) {
                td[9] = nd; tv[9] = l2[j].y;
                #pragma unroll
                for (int x = 9; x > 0; --x)
                    if (td[x] < td[x - 1]) {
                        float a = td[x]; td[x] = td[x - 1]; td[x - 1] = a;
                        float b = tv[x]; tv[x] = tv[x - 1]; tv[x - 1] = b;
                    }
            }
        }
        float s = 0.f;
        #pragma unroll
        for (int i = 0; i < 10; ++i) s += tv[i];
        atomicAdd(&acc[0], s);
    }
}
__global__ void k_finalize(const float* __restrict__ acc, float* __restrict__ out) {
    if (threadIdx.x == 0) {
        out[10485760] = acc[0] / 5120.0f;
        out[10485761] = (acc[1] - acc[2]) / 262144.0f;
    }
}

// ======================= FAST PATH =======================
// transpose+convert with 64B-coalesced writes: 4 lanes cooperate per output row.
template <int EN>
__global__ __launch_bounds__(256) void k_tc(const float* __restrict__ src,
                                            ushort* __restrict__ dst,
                                            float* __restrict__ en,
                                            int Ncols, int D) {
    __shared__ float tile[32][257];
    const int t = threadIdx.x;
    const int n0 = blockIdx.x * 256;
    const int d0 = blockIdx.y * 32;
    float s = 0.f;
    #pragma unroll 8
    for (int dd = 0; dd < 32; ++dd) {
        float v = src[(size_t)(d0 + dd) * Ncols + n0 + t];
        tile[dd][t] = v;
        if (EN) s += v * v;
    }
    if (EN) atomicAdd(&en[n0 + t], s);
    __syncthreads();
    const int rsub = t & 3;           // 8-ushort (16B) sub-chunk within row
    const int rloc = t >> 2;          // 0..63
    #pragma unroll
    for (int p = 0; p < 4; ++p) {
        int row = p * 64 + rloc;
        uint4 d4;
        d4.x = pack2(tile[rsub * 8 + 0][row], tile[rsub * 8 + 1][row]);
        d4.y = pack2(tile[rsub * 8 + 2][row], tile[rsub * 8 + 3][row]);
        d4.z = pack2(tile[rsub * 8 + 4][row], tile[rsub * 8 + 5][row]);
        d4.w = pack2(tile[rsub * 8 + 6][row], tile[rsub * 8 + 7][row]);
        *(uint4*)(dst + (size_t)(n0 + row) * D + d0 + rsub * 8) = d4;
    }
}

// fp32 transpose: src [D][Ncols] -> dst [Ncols][D]
__global__ __launch_bounds__(256) void k_tcp(const float* __restrict__ src,
                                             float* __restrict__ dst,
                                             int Ncols, int D) {
    __shared__ float tile[32][257];
    const int t = threadIdx.x;
    const int n0 = blockIdx.x * 256;
    const int d0 = blockIdx.y * 32;
    #pragma unroll 8
    for (int dd = 0; dd < 32; ++dd)
        tile[dd][t] = src[(size_t)(d0 + dd) * Ncols + n0 + t];
    __syncthreads();
    float* drow = dst + (size_t)(n0 + t) * D + d0;
    #pragma unroll
    for (int q = 0; q < 8; ++q) {
        float4 d4 = make_float4(tile[q * 4 + 0][t], tile[q * 4 + 1][t],
                                tile[q * 4 + 2][t], tile[q * 4 + 3][t]);
        *(float4*)(drow + q * 4) = d4;
    }
}

__global__ void k_cvt_emb(const float* __restrict__ src, ushort* __restrict__ dst) {
    int i = (blockIdx.x * 256 + threadIdx.x) * 8;
    float4 a = *(const float4*)&src[i], b = *(const float4*)&src[i + 4];
    uint4 d4 = make_uint4(pack2(a.x, a.y), pack2(a.z, a.w), pack2(b.x, b.y), pack2(b.z, b.w));
    *(uint4*)&dst[i] = d4;
}

// C = A[MxK] @ B[NxK]^T, bf16 in, gload_lds staging, tile 64x128, BK=64.
template <int WF32, int WB16, int RELU>
__global__ __launch_bounds__(256, 4) void gemm_bt(const ushort* __restrict__ A,
                                                  const ushort* __restrict__ B,
                                                  float* __restrict__ C,
                                                  ushort* __restrict__ Cb,
                                                  int M, int N, int K) {
    __shared__ __align__(16) char smem[24576];
    char* Ab = smem;              // [64 rows][128 B]
    char* Bb = smem + 8192;       // [128 rows][128 B]
    const int t = threadIdx.x;
    const int l = t & 63, w = t >> 6;
    const int wr = w >> 1, wc = w & 1;
    const int lg = l >> 4, lc = l & 15;
    const int m0 = blockIdx.x * 64, n0 = blockIdx.y * 128;
    const int sr8 = l >> 3, oct = l & 7;
    const int arw0 = 16 * w + sr8, arw1 = arw0 + 8;
    const ushort* ga0 = A + (size_t)(m0 + arw0) * K + (oct ^ (arw0 & 7)) * 8;
    const ushort* ga1 = A + (size_t)(m0 + arw1) * K + (oct ^ (arw1 & 7)) * 8;
    char* la0 = Ab + w * 2048;
    char* la1 = Ab + w * 2048 + 1024;
    const int brw0 = 32 * w + sr8, brw1 = brw0 + 8, brw2 = brw0 + 16, brw3 = brw0 + 24;
    const ushort* gb0 = B + (size_t)(n0 + brw0) * K + (oct ^ (brw0 & 7)) * 8;
    const ushort* gb1 = B + (size_t)(n0 + brw1) * K + (oct ^ (brw1 & 7)) * 8;
    const ushort* gb2 = B + (size_t)(n0 + brw2) * K + (oct ^ (brw2 & 7)) * 8;
    const ushort* gb3 = B + (size_t)(n0 + brw3) * K + (oct ^ (brw3 & 7)) * 8;
    char* lb0 = Bb + w * 4096;
    char* lb1 = Bb + w * 4096 + 1024;
    char* lb2 = Bb + w * 4096 + 2048;
    char* lb3 = Bb + w * 4096 + 3072;
    const int ar0 = wr * 32 + lc, ar1 = ar0 + 16;
    int aoff[2][2], boff[2][4];
    #pragma unroll
    for (int kk = 0; kk < 2; ++kk) {
        aoff[kk][0] = ar0 * 128 + (((kk * 4 + lg) ^ (ar0 & 7)) * 16);
        aoff[kk][1] = ar1 * 128 + (((kk * 4 + lg) ^ (ar1 & 7)) * 16);
        #pragma unroll
        for (int f = 0; f < 4; ++f) {
            int bc = wc * 64 + f * 16 + lc;
            boff[kk][f] = bc * 128 + (((kk * 4 + lg) ^ (bc & 7)) * 16);
        }
    }
    f32x4 acc[2][4];
    #pragma unroll
    for (int m = 0; m < 2; ++m)
        #pragma unroll
        for (int f = 0; f < 4; ++f) acc[m][f] = (f32x4){0.f, 0.f, 0.f, 0.f};

    #pragma unroll 1
    for (int k0 = 0; k0 < K; k0 += 64) {
        __syncthreads();
        gll16(ga0 + k0, la0); gll16(ga1 + k0, la1);
        gll16(gb0 + k0, lb0); gll16(gb1 + k0, lb1);
        gll16(gb2 + k0, lb2); gll16(gb3 + k0, lb3);
        __syncthreads();
        #pragma unroll
        for (int kk = 0; kk < 2; ++kk) {
            short8 a0 = *(const short8*)(Ab + aoff[kk][0]);
            short8 a1 = *(const short8*)(Ab + aoff[kk][1]);
            short8 bfr[4];
            #pragma unroll
            for (int f = 0; f < 4; ++f) bfr[f] = *(const short8*)(Bb + boff[kk][f]);
            #pragma unroll
            for (int f = 0; f < 4; ++f) {
                acc[0][f] = __builtin_amdgcn_mfma_f32_16x16x32_bf16(a0, bfr[f], acc[0][f], 0, 0, 0);
                acc[1][f] = __builtin_amdgcn_mfma_f32_16x16x32_bf16(a1, bfr[f], acc[1][f], 0, 0, 0);
            }
        }
    }
    #pragma unroll
    for (int m = 0; m < 2; ++m)
        #pragma unroll
        for (int f = 0; f < 4; ++f)
            #pragma unroll
            for (int i = 0; i < 4; ++i) {
                int row = m0 + wr * 32 + m * 16 + lg * 4 + i;
                int col = n0 + wc * 64 + f * 16 + lc;
                float v = acc[m][f][i];
                if (RELU) v = fmaxf(v, 0.f);
                if (WF32) C[(size_t)row * N + col] = v;
                if (WB16) Cb[(size_t)row * N + col] = f2bf(v);
            }
}

// prob epilogue with exact fp32 fixup; cptT [512][768] gives coalesced dots
__global__ __launch_bounds__(256) void k_prob2(const float* __restrict__ emb,
                                               const float* __restrict__ cptT,
                                               const float* __restrict__ cn_sq,
                                               float* __restrict__ S,
                                               ushort* __restrict__ probb) {
    __shared__ float erow[768];
    __shared__ float sval[512];
    __shared__ int idxl[512];
    __shared__ int cnt;
    __shared__ float redw[4];
    const int b = blockIdx.x, t = threadIdx.x;
    const int l = t & 63, w = t >> 6;
    if (t == 0) cnt = 0;
    float s = 0.f;
    #pragma unroll
    for (int j = 0; j < 3; ++j) {
        float v = emb[(size_t)b * 768 + t + j * 256];
        erow[t + j * 256] = v; s += v * v;
    }
    #pragma unroll
    for (int o = 32; o > 0; o >>= 1) s += __shfl_down(s, o);
    if (l == 0) redw[w] = s;
    __syncthreads();
    const float rn = fmaxf(sqrtf(redw[0] + redw[1] + redw[2] + redw[3]), 1e-12f);
    #pragma unroll
    for (int j = 0; j < 2; ++j) {
        int c = t + j * 256;
        sval[c] = 0.f;
        float cn = fmaxf(sqrtf(cn_sq[c]), 1e-12f);
        float sn = S[(size_t)b * 512 + c] / (rn * cn);
        if (sn > 0.1f - 4e-3f) { int p = atomicAdd(&cnt, 1); idxl[p] = c; }
    }
    __syncthreads();
    const int nf = cnt;
    for (int q0 = 0; q0 < nf; q0 += 4) {
        int q = q0 + w;
        if (q < nf) {
            int c = idxl[q];
            const float* cr = cptT + (size_t)c * 768;
            float p = 0.f;
            #pragma unroll
            for (int ii = 0; ii < 3; ++ii) {
                int d = l * 4 + ii * 256;
                float4 e4 = *(const float4*)&erow[d];
                float4 x4 = *(const float4*)&cr[d];
                p += e4.x * x4.x + e4.y * x4.y + e4.z * x4.z + e4.w * x4.w;
            }
            #pragma unroll
            for (int o = 32; o > 0; o >>= 1) p += __shfl_down(p, o);
            if (l == 0) {
                float cn = fmaxf(sqrtf(cn_sq[c]), 1e-12f);
                sval[c] = (p / (rn * cn) > 0.1f) ? p : 0.f;
            }
        }
    }
    __syncthreads();
    float s2 = sval[t] + sval[t + 256];
    #pragma unroll
    for (int o = 32; o > 0; o >>= 1) s2 += __shfl_down(s2, o);
    if (l == 0) redw[w] = s2;
    __syncthreads();
    const float denom = redw[0] + redw[1] + redw[2] + redw[3] + 0.001f;
    #pragma unroll
    for (int j = 0; j < 2; ++j) {
        int c = t + j * 256;
        float pr = sval[c] / denom;
        S[(size_t)b * 512 + c] = pr;
        probb[(size_t)b * 512 + c] = f2bf(pr);
    }
}

// cx GEMM (bf16, gload_lds, BK=64) + fused per-block top-10 via packed u32 keys.
// key = (bits(dist) & ~0x1FF) | local_col(9b); dist>0 so uint order == float order.
__global__ __launch_bounds__(256, 4) void k_cx_topk2(const ushort* __restrict__ cptb, // [512][768]
                                                     const ushort* __restrict__ XbT,  // [65536][768]
                                                     const float* __restrict__ cn_sq,
                                                     const float* __restrict__ en,
                                                     u32* __restrict__ cand) {
    __shared__ __align__(16) char smem[34048];
    char* Ab = smem;              // [64][128B]
    char* Bb = smem + 8192;       // [128][128B]
    float* Ct = (float*)smem;     // [64][132] f32 (33792 B) aliased

    const int t = threadIdx.x;
    const int l = t & 63, w = t >> 6;
    const int wr = w >> 1, wc = w & 1;
    const int lg = l >> 4, lc = l & 15;
    const int c0 = blockIdx.y * 64;
    const int nbase = blockIdx.x * 512;

    const int sr8 = l >> 3, oct = l & 7;
    const int arw0 = 16 * w + sr8, arw1 = arw0 + 8;
    const ushort* ga0 = cptb + (size_t)(c0 + arw0) * 768 + (oct ^ (arw0 & 7)) * 8;
    const ushort* ga1 = cptb + (size_t)(c0 + arw1) * 768 + (oct ^ (arw1 & 7)) * 8;
    char* la0 = Ab + w * 2048;
    char* la1 = Ab + w * 2048 + 1024;
    const int brw0 = 32 * w + sr8, brw1 = brw0 + 8, brw2 = brw0 + 16, brw3 = brw0 + 24;
    const int bs0 = (oct ^ (brw0 & 7)) * 8, bs1 = (oct ^ (brw1 & 7)) * 8;
    const int bs2 = (oct ^ (brw2 & 7)) * 8, bs3 = (oct ^ (brw3 & 7)) * 8;
    char* lb0 = Bb + w * 4096;
    char* lb1 = Bb + w * 4096 + 1024;
    char* lb2 = Bb + w * 4096 + 2048;
    char* lb3 = Bb + w * 4096 + 3072;

    const int ar0 = wr * 32 + lc, ar1 = ar0 + 16;
    int aoff[2][2], boff[2][4];
    #pragma unroll
    for (int kk = 0; kk < 2; ++kk) {
        aoff[kk][0] = ar0 * 128 + (((kk * 4 + lg) ^ (ar0 & 7)) * 16);
        aoff[kk][1] = ar1 * 128 + (((kk * 4 + lg) ^ (ar1 & 7)) * 16);
        #pragma unroll
        for (int f = 0; f < 4; ++f) {
            int bc = wc * 64 + f * 16 + lc;
            boff[kk][f] = bc * 128 + (((kk * 4 + lg) ^ (bc & 7)) * 16);
        }
    }

    const int r = t >> 2, g = t & 3;
    u32 topk[10];
    #pragma unroll
    for (int i = 0; i < 10; ++i) topk[i] = 0xFFFFFFFFu;
    const float cnr = cn_sq[c0 + r];

    auto insk = [&](u32 k) {
        if (k < topk[9]) {
            topk[9] = k;
            #pragma unroll
            for (int x = 9; x > 0; --x) {
                u32 a = topk[x - 1], b = topk[x];
                u32 lo = a < b ? a : b;
                u32 hi = a < b ? b : a;
                topk[x - 1] = lo; topk[x] = hi;
            }
        }
    };

    #pragma unroll 1
    for (int s = 0; s < 4; ++s) {
        const int n0 = nbase + s * 128;
        const ushort* gb0 = XbT + (size_t)(n0 + brw0) * 768 + bs0;
        const ushort* gb1 = XbT + (size_t)(n0 + brw1) * 768 + bs1;
        const ushort* gb2 = XbT + (size_t)(n0 + brw2) * 768 + bs2;
        const ushort* gb3 = XbT + (size_t)(n0 + brw3) * 768 + bs3;
        f32x4 acc[2][4];
        #pragma unroll
        for (int m = 0; m < 2; ++m)
            #pragma unroll
            for (int f = 0; f < 4; ++f) acc[m][f] = (f32x4){0.f, 0.f, 0.f, 0.f};

        #pragma unroll 1
        for (int k0 = 0; k0 < 768; k0 += 64) {
            __syncthreads();
            gll16(ga0 + k0, la0); gll16(ga1 + k0, la1);
            gll16(gb0 + k0, lb0); gll16(gb1 + k0, lb1);
            gll16(gb2 + k0, lb2); gll16(gb3 + k0, lb3);
            __syncthreads();
            #pragma unroll
            for (int kk = 0; kk < 2; ++kk) {
                short8 a0 = *(const short8*)(Ab + aoff[kk][0]);
                short8 a1 = *(const short8*)(Ab + aoff[kk][1]);
                short8 bfr[4];
                #pragma unroll
                for (int f = 0; f < 4; ++f) bfr[f] = *(const short8*)(Bb + boff[kk][f]);
                #pragma unroll
                for (int f = 0; f < 4; ++f) {
                    acc[0][f] = __builtin_amdgcn_mfma_f32_16x16x32_bf16(a0, bfr[f], acc[0][f], 0, 0, 0);
                    acc[1][f] = __builtin_amdgcn_mfma_f32_16x16x32_bf16(a1, bfr[f], acc[1][f], 0, 0, 0);
                }
            }
        }
        __syncthreads();
        // ---- write C tile (C/D map: col = lane&15, row = (lane>>4)*4 + reg)
        #pragma unroll
        for (int m = 0; m < 2; ++m)
            #pragma unroll
            for (int f = 0; f < 4; ++f)
                #pragma unroll
                for (int i = 0; i < 4; ++i)
                    Ct[(wr * 32 + m * 16 + lg * 4 + i) * 132 + wc * 64 + f * 16 + lc] = acc[m][f][i];
        __syncthreads();
        // ---- scan: thread (r,g) covers cols c = g*4 + 16u; pack keys
        #pragma unroll
        for (int u = 0; u < 8; ++u) {
            int c = g * 4 + u * 16;
            float4 v4 = *(const float4*)&Ct[r * 132 + c];
            float4 e4 = *(const float4*)&en[n0 + c];
            u32 base = (u32)(s * 128 + c);
            float d0 = cnr + e4.x - 2.f * v4.x;
            float d1 = cnr + e4.y - 2.f * v4.y;
            float d2 = cnr + e4.z - 2.f * v4.z;
            float d3 = cnr + e4.w - 2.f * v4.w;
            insk((__builtin_bit_cast(u32, d0) & 0xFFFFFE00u) | (base + 0));
            insk((__builtin_bit_cast(u32, d1) & 0xFFFFFE00u) | (base + 1));
            insk((__builtin_bit_cast(u32, d2) & 0xFFFFFE00u) | (base + 2));
            insk((__builtin_bit_cast(u32, d3) & 0xFFFFFE00u) | (base + 3));
        }
        __syncthreads();
    }
    // ---- merge 4 per-thread lists per row via LDS (u32 keys)
    u32* ML = (u32*)smem;
    #pragma unroll
    for (int i = 0; i < 10; ++i) ML[t * 10 + i] = topk[i];
    __syncthreads();
    if (g == 0) {
        #pragma unroll 1
        for (int o = 1; o < 4; ++o) {
            const u32* L = &ML[(t + o) * 10];
            #pragma unroll 1
            for (int i = 0; i < 10; ++i) {
                u32 nk = L[i];
                if (nk >= topk[9]) break;          // lists sorted ascending
                topk[9] = nk;
                #pragma unroll
                for (int x = 9; x > 0; --x) {
                    u32 a = topk[x - 1], b = topk[x];
                    u32 lo = a < b ? a : b;
                    u32 hi = a < b ? b : a;
                    topk[x - 1] = lo; topk[x] = hi;
                }
            }
        }
        u32* dst = &cand[((size_t)(c0 + r) * 128 + blockIdx.x) * 10];
        #pragma unroll
        for (int i = 0; i < 10; ++i) dst[i] = topk[i];
    }
}

// ======================= FALLBACK PATH (round-3, proven) =======================
template <int RELU>
__global__ __launch_bounds__(256) void k_gemm(const float* __restrict__ A,
                                              const float* __restrict__ Bm,
                                              float* __restrict__ Cm,
                                              int M, int N, int K) {
    __shared__ float As[16][68];
    __shared__ float Bs[16][128];
    const int t = threadIdx.x;
    const int m0 = blockIdx.x * 64, n0 = blockIdx.y * 128;
    const int tm = t >> 4, tn = t & 15;
    float acc[4][8] = {};
    #pragma unroll 1
    for (int k0 = 0; k0 < K; k0 += 16) {
        {
            int i = t >> 2, kk4 = (t & 3) * 4;
            float4 av = *(const float4*)&A[(size_t)(m0 + i) * K + k0 + kk4];
            As[kk4 + 0][i] = av.x; As[kk4 + 1][i] = av.y;
            As[kk4 + 2][i] = av.z; As[kk4 + 3][i] = av.w;
        }
        {
            int kk = t >> 5, c4 = (t & 31) * 4;
            *(float4*)&Bs[kk][c4] = *(const float4*)&Bm[(size_t)(k0 + kk) * N + n0 + c4];
            *(float4*)&Bs[kk + 8][c4] = *(const float4*)&Bm[(size_t)(k0 + kk + 8) * N + n0 + c4];
        }
        __syncthreads();
        #pragma unroll
        for (int k = 0; k < 16; ++k) {
            float4 a4 = *(const float4*)&As[k][tm * 4];
            float4 b0 = *(const float4*)&Bs[k][tn * 4];
            float4 b1 = *(const float4*)&Bs[k][64 + tn * 4];
            float av[4] = {a4.x, a4.y, a4.z, a4.w};
            float bv[8] = {b0.x, b0.y, b0.z, b0.w, b1.x, b1.y, b1.z, b1.w};
            #pragma unroll
            for (int i = 0; i < 4; ++i)
                #pragma unroll
                for (int j = 0; j < 8; ++j) acc[i][j] += av[i] * bv[j];
        }
        __syncthreads();
    }
    #pragma unroll
    for (int i = 0; i < 4; ++i) {
        int row = m0 + tm * 4 + i;
        float4 o0 = make_float4(acc[i][0], acc[i][1], acc[i][2], acc[i][3]);
        float4 o1 = make_float4(acc[i][4], acc[i][5], acc[i][6], acc[i][7]);
        if (RELU) {
            o0.x = fmaxf(o0.x, 0.f); o0.y = fmaxf(o0.y, 0.f);
            o0.z = fmaxf(o0.z, 0.f); o0.w = fmaxf(o0.w, 0.f);
            o1.x = fmaxf(o1.x, 0.f); o1.y = fmaxf(o1.y, 0.f);
            o1.z = fmaxf(o1.z, 0.f); o1.w = fmaxf(o1.w, 0.f);
        }
        *(float4*)&Cm[(size_t)row * N + n0 + tn * 4] = o0;
        *(float4*)&Cm[(size_t)row * N + n0 + 64 + tn * 4] = o1;
    }
}

template <int RELU>
__global__ __launch_bounds__(256) void k_gemm_bf(const float* __restrict__ A,
                                                 const float* __restrict__ Bm,
                                                 float* __restrict__ Cm,
                                                 int M, int N, int K) {
    __shared__ __align__(16) char smem[15360];
    char* Ab = smem;
    char* Bb = smem + 5120;
    const int t = threadIdx.x;
    const int l = t & 63, w = t >> 6;
    const int wr = w >> 1, wc = w & 1;
    const int lg = l >> 4, lc = l & 15;
    const int m0 = blockIdx.x * 64, n0 = blockIdx.y * 128;
    const int ar = t >> 2, ak = (t & 3) * 8;
    const int bc = t & 63, bw = t >> 6;
    f32x4 acc[2][4];
    #pragma unroll
    for (int m = 0; m < 2; ++m)
        #pragma unroll
        for (int f = 0; f < 4; ++f) acc[m][f] = (f32x4){0.f, 0.f, 0.f, 0.f};
    #pragma unroll 1
    for (int k0 = 0; k0 < K; k0 += 32) {
        __syncthreads();
        {
            const float* p = &A[(size_t)(m0 + ar) * K + k0 + ak];
            float4 a0 = *(const float4*)p;
            float4 a1 = *(const float4*)(p + 4);
            uint4 da = make_uint4(pack2(a0.x, a0.y), pack2(a0.z, a0.w),
                                  pack2(a1.x, a1.y), pack2(a1.z, a1.w));
            *(uint4*)(Ab + ar * 80 + (t & 3) * 16) = da;
        }
        #pragma unroll
        for (int j = 0; j < 2; ++j) {
            float x[8];
            #pragma unroll
            for (int i = 0; i < 8; ++i)
                x[i] = Bm[(size_t)(k0 + 8 * bw + i) * N + n0 + bc + 64 * j];
            uint4 db = make_uint4(pack2(x[0], x[1]), pack2(x[2], x[3]),
                                  pack2(x[4], x[5]), pack2(x[6], x[7]));
            *(uint4*)(Bb + (bc + 64 * j) * 80 + bw * 16) = db;
        }
        __syncthreads();
        short8 af0 = *(const short8*)(Ab + (wr * 32 + lc) * 80 + lg * 16);
        short8 af1 = *(const short8*)(Ab + (wr * 32 + 16 + lc) * 80 + lg * 16);
        short8 bfr[4];
        #pragma unroll
        for (int f = 0; f < 4; ++f)
            bfr[f] = *(const short8*)(Bb + (wc * 64 + f * 16 + lc) * 80 + lg * 16);
        #pragma unroll
        for (int f = 0; f < 4; ++f) {
            acc[0][f] = __builtin_amdgcn_mfma_f32_16x16x32_bf16(af0, bfr[f], acc[0][f], 0, 0, 0);
            acc[1][f] = __builtin_amdgcn_mfma_f32_16x16x32_bf16(af1, bfr[f], acc[1][f], 0, 0, 0);
        }
    }
    #pragma unroll
    for (int m = 0; m < 2; ++m)
        #pragma unroll
        for (int f = 0; f < 4; ++f)
            #pragma unroll
            for (int i = 0; i < 4; ++i) {
                int row = m0 + wr * 32 + m * 16 + lg * 4 + i;
                int col = n0 + wc * 64 + f * 16 + lc;
                float v = acc[m][f][i];
                if (RELU) v = fmaxf(v, 0.f);
                Cm[(size_t)row * N + col] = v;
            }
}

__global__ __launch_bounds__(256) void k_prob(const float* __restrict__ emb,
                                              const float* __restrict__ cn_sq,
                                              float* __restrict__ S) {
    __shared__ float red[256];
    int b = blockIdx.x, t = threadIdx.x;
    float s = 0.f;
    #pragma unroll
    for (int j = 0; j < 3; ++j) { float v = emb[(size_t)b * 768 + t + j * 256]; s += v * v; }
    red[t] = s; __syncthreads();
    for (int st = 128; st > 0; st >>= 1) { if (t < st) red[t] += red[t + st]; __syncthreads(); }
    float rn = fmaxf(sqrtf(red[0]), 1e-12f);
    __syncthreads();
    float vals[2]; float sum = 0.f;
    #pragma unroll
    for (int j = 0; j < 2; ++j) {
        int cc = t + j * 256;
        float sc = S[(size_t)b * 512 + cc];
        float cn = fmaxf(sqrtf(cn_sq[cc]), 1e-12f);
        float v = (sc / (rn * cn) > 0.1f) ? sc : 0.f;
        vals[j] = v; sum += v;
    }
    red[t] = sum; __syncthreads();
    for (int st = 128; st > 0; st >>= 1) { if (t < st) red[t] += red[t + st]; __syncthreads(); }
    float denom = red[0] + 0.001f;
    #pragma unroll
    for (int j = 0; j < 2; ++j) S[(size_t)b * 512 + (t + j * 256)] = vals[j] / denom;
}

__global__ void k_en(const float* __restrict__ X, float* __restrict__ en) {
    int n4 = blockIdx.x * 256 + threadIdx.x;
    float4 s = make_float4(0.f, 0.f, 0.f, 0.f);
    #pragma unroll 4
    for (int d = 0; d < 768; ++d) {
        float4 v = *(const float4*)&X[(size_t)d * 65536 + n4 * 4];
        s.x += v.x * v.x; s.y += v.y * v.y; s.z += v.z * v.z; s.w += v.w * v.w;
    }
    *(float4*)&en[n4 * 4] = s;
}

__global__ __launch_bounds__(256, 4) void k_cx_topk(const float* __restrict__ cpt,
                                                    const float* __restrict__ X,
                                                    const float* __restrict__ cn_sq,
                                                    const float* __restrict__ en,
                                                    float2* __restrict__ cand) {
    __shared__ __align__(16) char smem_c[34048];
    float* Ct = (float*)smem_c;
    char* Ab = smem_c;
    char* Bb = smem_c + 5120;
    const int t = threadIdx.x;
    const int l = t & 63, w = t >> 6;
    const int wr = w >> 1, wc = w & 1;
    const int lg = l >> 4, lc = l & 15;
    const int c0 = blockIdx.y * 64;
    const int nbase = blockIdx.x * 512;
    const float FINF = __builtin_inff();
    const int sc_ = t & 63, sw = t >> 6;
    const int r = t >> 2, g = t & 3;
    float topd[10], topv[10];
    #pragma unroll
    for (int i = 0; i < 10; ++i) { topd[i] = FINF; topv[i] = 0.f; }
    const float cnr = cn_sq[c0 + r];
    #pragma unroll 1
    for (int s = 0; s < 4; ++s) {
        const int n0 = nbase + s * 128;
        f32x4 acc[2][4];
        #pragma unroll
        for (int m = 0; m < 2; ++m)
            #pragma unroll
            for (int f = 0; f < 4; ++f) acc[m][f] = (f32x4){0.f, 0.f, 0.f, 0.f};
        #pragma unroll 1
        for (int k0 = 0; k0 < 768; k0 += 32) {
            __syncthreads();
            {
                float x[8];
                #pragma unroll
                for (int i = 0; i < 8; ++i)
                    x[i] = cpt[(size_t)(k0 + 8 * sw + i) * 512 + c0 + sc_];
                uint4 da = make_uint4(pack2(x[0], x[1]), pack2(x[2], x[3]),
                                      pack2(x[4], x[5]), pack2(x[6], x[7]));
                *(uint4*)(Ab + sc_ * 80 + sw * 16) = da;
            }
            #pragma unroll
            for (int j = 0; j < 2; ++j) {
                float x[8];
                #pragma unroll
                for (int i = 0; i < 8; ++i)
                    x[i] = X[(size_t)(k0 + 8 * sw + i) * 65536 + n0 + sc_ + 64 * j];
                uint4 db = make_uint4(pack2(x[0], x[1]), pack2(x[2], x[3]),
                                      pack2(x[4], x[5]), pack2(x[6], x[7]));
                *(uint4*)(Bb + (sc_ + 64 * j) * 80 + sw * 16) = db;
            }
            __syncthreads();
            short8 af0 = *(const short8*)(Ab + (wr * 32 + lc) * 80 + lg * 16);
            short8 af1 = *(const short8*)(Ab + (wr * 32 + 16 + lc) * 80 + lg * 16);
            short8 bfr[4];
            #pragma unroll
            for (int f = 0; f < 4; ++f)
                bfr[f] = *(const short8*)(Bb + (wc * 64 + f * 16 + lc) * 80 + lg * 16);
            #pragma unroll
            for (int f = 0; f < 4; ++f) {
                acc[0][f] = __builtin_amdgcn_mfma_f32_16x16x32_bf16(af0, bfr[f], acc[0][f], 0, 0, 0);
                acc[1][f] = __builtin_amdgcn_mfma_f32_16x16x32_bf16(af1, bfr[f], acc[1][f], 0, 0, 0);
            }
        }
        __syncthreads();
        #pragma unroll
        for (int m = 0; m < 2; ++m)
            #pragma unroll
            for (int f = 0; f < 4; ++f)
                #pragma unroll
                for (int i = 0; i < 4; ++i)
                    Ct[(wr * 32 + m * 16 + lg * 4 + i) * 133 + wc * 64 + f * 16 + lc] = acc[m][f][i];
        __syncthreads();
        #pragma unroll 1
        for (int u = 0; u < 32; ++u) {
            int c = u * 4 + g;
            float val = Ct[r * 133 + c];
            float dist = cnr + en[n0 + c] - 2.f * val;
            if (dist < topd[9]) {
                topd[9] = dist; topv[9] = val;
                #pragma unroll
                for (int i = 9; i > 0; --i) {
                    if (topd[i] < topd[i - 1]) {
                        float td = topd[i]; topd[i] = topd[i - 1]; topd[i - 1] = td;
                        float tv = topv[i]; topv[i] = topv[i - 1]; topv[i - 1] = tv;
                    }
                }
            }
        }
        __syncthreads();
    }
    float* ML = (float*)smem_c;
    #pragma unroll
    for (int i = 0; i < 10; ++i) {
        ML[t * 20 + 2 * i] = topd[i];
        ML[t * 20 + 2 * i + 1] = topv[i];
    }
    __syncthreads();
    if (g == 0) {
        #pragma unroll 1
        for (int o = 1; o < 4; ++o) {
            const float* L = &ML[(t + o) * 20];
            #pragma unroll 1
            for (int i = 0; i < 10; ++i) {
                float nd = L[2 * i];
                if (nd >= topd[9]) break;
                float nv = L[2 * i + 1];
                topd[9] = nd; topv[9] = nv;
                #pragma unroll
                for (int x = 9; x > 0; --x) {
                    if (topd[x] < topd[x - 1]) {
                        float td = topd[x]; topd[x] = topd[x - 1]; topd[x - 1] = td;
                        float tv = topv[x]; topv[x] = topv[x - 1]; topv[x - 1] = tv;
                    }
                }
            }
        }
        float2* dst = &cand[((size_t)(c0 + r) * 128 + blockIdx.x) * 10];
        #pragma unroll
        for (int i = 0; i < 10; ++i) dst[i] = make_float2(topd[i], topv[i]);
    }
}

// ======================= launcher =======================
extern "C" void kernel_launch(void* const* d_in, const int* in_sizes, int n_in,
                              void* d_out, int out_size, void* d_ws, size_t ws_size,
                              hipStream_t stream) {
    const float* emb = (const float*)d_in[0];   // [8192 x 768]
    const float* X   = (const float*)d_in[1];   // [768 x 65536]
    const float* cpt = (const float*)d_in[2];   // [768 x 512]
    const float* r1  = (const float*)d_in[3];   // [512 x 256]
    const float* r2  = (const float*)d_in[4];   // [256 x 768]
    float* out = (float*)d_out;
    float* ws = (float*)d_ws;
    float* S = out + 6291456;                   // prob region doubles as score scratch

    const size_t OFF_CN = 0, OFF_EN = 512, OFF_ACC = 66048, OFF_XBT = 66560;
    const size_t OFF_EMBB = 25232384, OFF_CPTB = 28378112, OFF_R1T = 28574720;
    const size_t OFF_R2T = 28640256, OFF_PRBB = 28738560, OFF_RL1B = 30835712;
    const size_t OFF_CAND = 31884288, WS_NEED = 33195008ull * 4ull;

    if (ws_size >= WS_NEED) {
        float* cn_sq = ws + OFF_CN;
        float* en    = ws + OFF_EN;
        float* acc   = ws + OFF_ACC;
        ushort* XbT  = (ushort*)(ws + OFF_XBT);
        ushort* embb = (ushort*)(ws + OFF_EMBB);
        ushort* cptb = (ushort*)(ws + OFF_CPTB);
        ushort* r1T  = (ushort*)(ws + OFF_R1T);
        ushort* r2T  = (ushort*)(ws + OFF_R2T);
        ushort* prbb = (ushort*)(ws + OFF_PRBB);
        ushort* rl1b = (ushort*)(ws + OFF_RL1B);
        float* cptT  = ws + OFF_CAND;
        u32* candk   = (u32*)(ws + OFF_CAND + 524288);

        k_zero<<<259, 256, 0, stream>>>(ws, 66056);
        k_col_sumsq<<<dim3(2, 8), 256, 0, stream>>>(cpt, cn_sq);
        k_row_stats<<<48, 256, 0, stream>>>(cpt, acc);
        k_tc<1><<<dim3(256, 24), 256, 0, stream>>>(X, XbT, en, 65536, 768);
        k_tc<0><<<dim3(2, 24), 256, 0, stream>>>(cpt, cptb, nullptr, 512, 768);
        k_tcp<<<dim3(2, 24), 256, 0, stream>>>(cpt, cptT, 512, 768);
        k_tc<0><<<dim3(1, 16), 256, 0, stream>>>(r1, r1T, nullptr, 256, 512);
        k_tc<0><<<dim3(3, 8), 256, 0, stream>>>(r2, r2T, nullptr, 768, 256);
        k_cvt_emb<<<3072, 256, 0, stream>>>(emb, embb);
        gemm_bt<1, 0, 0><<<dim3(128, 4), 256, 0, stream>>>(embb, cptb, S, nullptr, 8192, 512, 768);
        k_prob2<<<8192, 256, 0, stream>>>(emb, cptT, cn_sq, S, prbb);
        gemm_bt<0, 1, 1><<<dim3(128, 2), 256, 0, stream>>>(prbb, r1T, nullptr, rl1b, 8192, 256, 512);
        gemm_bt<1, 0, 0><<<dim3(128, 6), 256, 0, stream>>>(rl1b, r2T, out, nullptr, 8192, 768, 256);
        k_cx_topk2<<<dim3(128, 8), 256, 0, stream>>>(cptb, XbT, cn_sq, en, candk);
        k_knn_merge_keys<1280><<<512, 256, 0, stream>>>(candk, cn_sq, en, acc);
        k_finalize<<<1, 64, 0, stream>>>(acc, out);
    } else {
        float* cn_sq = ws;
        float* en    = ws + 512;
        float* acc   = ws + 66048;
        float* rl1   = ws + 66560;
        float2* cand = (float2*)(ws + 66560 + 8192 * 256);
        k_init<<<1, 256, 0, stream>>>(cn_sq, acc);
        k_col_sumsq<<<dim3(2, 8), 256, 0, stream>>>(cpt, cn_sq);
        k_row_stats<<<48, 256, 0, stream>>>(cpt, acc);
        k_gemm<0><<<dim3(128, 4), 256, 0, stream>>>(emb, cpt, S, 8192, 512, 768);
        k_prob<<<8192, 256, 0, stream>>>(emb, cn_sq, S);
        k_gemm_bf<1><<<dim3(128, 2), 256, 0, stream>>>(S, r1, rl1, 8192, 256, 512);
        k_gemm_bf<0><<<dim3(128, 6), 256, 0, stream>>>(rl1, r2, out, 8192, 768, 256);
        k_en<<<64, 256, 0, stream>>>(X, en);
        k_cx_topk<<<dim3(128, 8), 256, 0, stream>>>(cpt, X, cn_sq, en, cand);
        k_knn_merge<1280><<<512, 256, 0, stream>>>(cand, acc);
        k_finalize<<<1, 64, 0, stream>>>(acc, out);
    }
}